// Round 10
// baseline (288.520 us; speedup 1.0000x reference)
//
#include <hip/hip_runtime.h>
#include <hip/hip_bf16.h>
#include <math.h>

#define B_   8
#define NH_  8
#define D_   96
#define C_   768
#define N_   1569          // 8*14*14 + 1
#define NKV_ 393           // 8*7*7 + 1
#define M_   (B_*N_)       // 12552
#define QKV1 ((size_t)B_*NH_*N_*D_)    // 9,639,936 elems per tensor
#define QPAD 1664          // padded q rows per slab (13 tiles of 128)
#define KPAD 416           // padded kv rows per slab (13 tiles of 32)
#define SCALE_ 0.10206207261596575f    // 96^-0.5

using short8v = __attribute__((ext_vector_type(8))) short;
using f32x4   = __attribute__((ext_vector_type(4))) float;
typedef unsigned short u16;

#define GLOAD_LDS16(g, l) __builtin_amdgcn_global_load_lds( \
    (const __attribute__((address_space(1))) void*)(g),     \
    (__attribute__((address_space(3))) void*)(l), 16, 0, 0)

static __device__ __forceinline__ u16 f2bf(float f) {
    __hip_bfloat16 b = __float2bfloat16(f);
    return *(u16*)&b;
}
static __device__ __forceinline__ float bf2f(u16 v) {
    return __bfloat162float(*(const __hip_bfloat16*)&v);
}

// bijective XCD swizzle (m204): consecutive swizzled ids land on one XCD
static __device__ __forceinline__ unsigned xcd_swizzle(unsigned orig, unsigned nwg) {
    const unsigned qq = nwg >> 3, rr = nwg & 7;
    const unsigned xcd = orig & 7, loc = orig >> 3;
    return (xcd < rr ? xcd * (qq + 1) : rr * (qq + 1) + (xcd - rr) * qq) + loc;
}

// ---------------------------------------------------------------------------
// fp32 -> bf16 flat convert (n4 float4 chunks)
// ---------------------------------------------------------------------------
__global__ __launch_bounds__(256)
void cvt_f32_to_bf16(const float* __restrict__ in, u16* __restrict__ out, int n4)
{
    const int i = blockIdx.x * 256 + threadIdx.x;
    if (i < n4) {
        const float4 v = ((const float4*)in)[i];
        ushort4 o;
        o.x = f2bf(v.x); o.y = f2bf(v.y); o.z = f2bf(v.z); o.w = f2bf(v.w);
        ((ushort4*)out)[i] = o;
    }
}

// ---------------------------------------------------------------------------
// W [768][ncols] fp32  ->  Wt [ncols][768] bf16   (32x32 LDS tiles)
// ---------------------------------------------------------------------------
__global__ __launch_bounds__(256)
void transpose_cvt(const float* __restrict__ W, u16* __restrict__ Wt, int ncols)
{
    __shared__ float tile[32][33];
    const int tx = threadIdx.x & 31, ty = threadIdx.x >> 5;   // 32 x 8
    const int n0 = blockIdx.x * 32, k0 = blockIdx.y * 32;
    #pragma unroll
    for (int i = 0; i < 4; ++i)
        tile[ty + i * 8][tx] = W[(size_t)(k0 + ty + i * 8) * ncols + n0 + tx];
    __syncthreads();
    #pragma unroll
    for (int i = 0; i < 4; ++i)
        Wt[(size_t)(n0 + ty + i * 8) * 768 + k0 + tx] = f2bf(tile[tx][ty + i * 8]);
}

// ---------------------------------------------------------------------------
// zero V^T pad columns (j in [NKV_, KPAD)) — required finite for PV MFMA
// ---------------------------------------------------------------------------
__global__ __launch_bounds__(256)
void zero_pad_vt(u16* __restrict__ vt)
{
    const int i = blockIdx.x * 256 + threadIdx.x;
    const int total = 64 * 96 * (KPAD - NKV_);
    if (i < total) {
        const int j = i % (KPAD - NKV_);
        const int rest = i / (KPAD - NKV_);     // slab*96 + d
        vt[(size_t)rest * KPAD + NKV_ + j] = 0;
    }
}

// ---------------------------------------------------------------------------
// bf16 MFMA GEMM, counted-vmcnt pipeline (T3+T4) + LDS XOR swizzle (T2).
// 512 threads / 8 waves (2x4), 64x32 per wave. T5 setprio around MFMA.
// ---------------------------------------------------------------------------
template<int NC, bool SCATTER>
__global__ __launch_bounds__(512)
void gemm_bf16_kernel(const u16* __restrict__ A, const u16* __restrict__ Bt,
                      const float* __restrict__ bias, void* __restrict__ outp)
{
    constexpr int NXT = NC / 128;
    __shared__ alignas(16) u16 As[2][128 * 64];
    __shared__ alignas(16) u16 Bs[2][128 * 64];

    const int tid  = threadIdx.x;
    const int w    = tid >> 6, lane = tid & 63;
    const int c    = lane & 15, g = lane >> 4;
    const int wm   = w >> 2, wn = w & 3;      // 2 x 4 wave grid
    const int lrow = lane >> 3, lcol = lane & 7;

    const unsigned wg = xcd_swizzle(blockIdx.x, gridDim.x);
    const int m0 = (int)(wg / NXT) * 128;
    const int n0 = (int)(wg % NXT) * 128;

    f32x4 acc[4][2];
    #pragma unroll
    for (int i = 0; i < 4; ++i)
        #pragma unroll
        for (int j = 0; j < 2; ++j) acc[i][j] = (f32x4){0.f, 0.f, 0.f, 0.f};

#define STAGE(BUF, K0) do {                                                      \
    _Pragma("unroll")                                                            \
    for (int t = 0; t < 2; ++t) {                                                \
        const int r = t * 64 + w * 8;                                            \
        const int row = r + lrow;                                                \
        const int scol = (lcol ^ (row & 7)) * 8;                                 \
        int m = m0 + row; if (m >= M_) m = M_ - 1;                               \
        GLOAD_LDS16(&A[(size_t)m * 768 + (K0) + scol], &As[BUF][r * 64]);        \
        GLOAD_LDS16(&Bt[(size_t)(n0 + row) * 768 + (K0) + scol],                 \
                    &Bs[BUF][r * 64]);                                           \
    } } while (0)

    const int xora = (g ^ (c & 7)) * 8;          // kk=0: logical col16 = g
    const int xorb = ((4 + g) ^ (c & 7)) * 8;    // kk=1: logical col16 = 4+g

#define KSTEP(BUF, LAST, PREF, KNEXT) do {                                       \
    if (LAST) asm volatile("s_waitcnt vmcnt(0)" ::: "memory");                   \
    else      asm volatile("s_waitcnt vmcnt(4)" ::: "memory");                   \
    __builtin_amdgcn_s_barrier();                                                \
    short8v a0[4], a1[4], b0[2], b1[2];                                          \
    _Pragma("unroll")                                                            \
    for (int i = 0; i < 4; ++i) {                                                \
        const int ra = (wm * 64 + i * 16 + c) * 64;                              \
        a0[i] = *(const short8v*)&As[BUF][ra + xora];                            \
        a1[i] = *(const short8v*)&As[BUF][ra + xorb];                            \
    }                                                                            \
    _Pragma("unroll")                                                            \
    for (int j = 0; j < 2; ++j) {                                                \
        const int rb = (wn * 32 + j * 16 + c) * 64;                              \
        b0[j] = *(const short8v*)&Bs[BUF][rb + xora];                            \
        b1[j] = *(const short8v*)&Bs[BUF][rb + xorb];                            \
    }                                                                            \
    asm volatile("s_waitcnt lgkmcnt(0)" ::: "memory");                           \
    __builtin_amdgcn_sched_barrier(0);                                           \
    __builtin_amdgcn_s_barrier();                                                \
    if (PREF) STAGE(BUF, KNEXT);                                                 \
    __builtin_amdgcn_s_setprio(1);                                               \
    _Pragma("unroll")                                                            \
    for (int i = 0; i < 4; ++i)                                                  \
        _Pragma("unroll")                                                        \
        for (int j = 0; j < 2; ++j)                                              \
            acc[i][j] = __builtin_amdgcn_mfma_f32_16x16x32_bf16(                 \
                a0[i], b0[j], acc[i][j], 0, 0, 0);                               \
    _Pragma("unroll")                                                            \
    for (int i = 0; i < 4; ++i)                                                  \
        _Pragma("unroll")                                                        \
        for (int j = 0; j < 2; ++j)                                              \
            acc[i][j] = __builtin_amdgcn_mfma_f32_16x16x32_bf16(                 \
                a1[i], b1[j], acc[i][j], 0, 0, 0);                               \
    __builtin_amdgcn_s_setprio(0);                                               \
    } while (0)

    STAGE(0, 0);
    STAGE(1, 64);
    #pragma unroll
    for (int tt = 0; tt < 5; ++tt) {
        KSTEP(0, false, true, (2 * tt + 2) * 64);
        KSTEP(1, false, true, (2 * tt + 3) * 64);
    }
    KSTEP(0, false, false, 0);
    KSTEP(1, true,  false, 0);
#undef STAGE
#undef KSTEP

    #pragma unroll
    for (int i = 0; i < 4; ++i) {
        const int mrow = m0 + wm * 64 + i * 16 + g * 4;
        #pragma unroll
        for (int j = 0; j < 2; ++j) {
            const int ncol = n0 + wn * 32 + j * 16 + c;
            const float bv = bias[ncol];
            if constexpr (SCATTER) {
                u16* out = (u16*)outp;
                const int s   = ncol / C_;          // 0=q,1=k,2=v
                const int rem = ncol - s * C_;
                const int hh  = rem / D_;
                const int dd  = rem - hh * D_;
                #pragma unroll
                for (int r = 0; r < 4; ++r) {
                    const int m = mrow + r;
                    if (m < M_) {
                        const int bb2 = m / N_;
                        const int n = m - bb2 * N_;
                        out[(size_t)s * QKV1 +
                            ((size_t)(bb2 * NH_ + hh) * N_ + n) * D_ + dd] = f2bf(acc[i][j][r] + bv);
                    }
                }
            } else {
                float* out = (float*)outp;
                #pragma unroll
                for (int r = 0; r < 4; ++r) {
                    const int m = mrow + r;
                    if (m < M_) out[(size_t)m * NC + ncol] = acc[i][j][r] + bv;
                }
            }
        }
    }
}

// ---------------------------------------------------------------------------
// Fused pool+LN, 512 threads (8 waves), one block per (tensor, bh, to).
// Stage 3 input t-planes (112.9KB) via global_load_lds, compute from LDS.
// MODE: 0=q ([tok][96], scaled), 1=k ([tok][96]), 2=v^T ([96][KPAD]).
// ---------------------------------------------------------------------------
#define PLANE_B 37632              // 196*192 bytes per t-plane
#define POOL_LDS_B (114688 + 96*27*4)

template<int STRIDE, int OH, int OW, int MODE>
static __device__ __forceinline__
void pool_block_body(const u16* __restrict__ smem, const float* __restrict__ wsm2,
                     const float* __restrict__ g, const float* __restrict__ bta,
                     const u16* __restrict__ in, size_t inbase,
                     u16* __restrict__ out, int tokstride, int bh, int to,
                     float oscale)
{
    const int tid = threadIdx.x;
    const int wv = tid >> 6, lane = tid & 63;
    const int l = lane < 48 ? lane : 47;
    const bool act = lane < 48;

    float wg0[27], wg1[27];
    #pragma unroll
    for (int tap = 0; tap < 27; ++tap) {
        const float2 wp = *(const float2*)&wsm2[tap * 96 + 2 * l];
        wg0[tap] = wp.x; wg1[tap] = wp.y;
    }
    const float gam0 = g[2 * l],     bet0 = bta[2 * l];
    const float gam1 = g[2 * l + 1], bet1 = bta[2 * l + 1];

    for (int ho = wv; ho < OH; ho += 8) {
        float a0[OW], a1[OW];
        #pragma unroll
        for (int wo = 0; wo < OW; ++wo) { a0[wo] = 0.f; a1[wo] = 0.f; }

        #pragma unroll
        for (int dt = 0; dt < 3; ++dt) {
            const int t = to - 1 + dt;
            if (t < 0 || t > 7) continue;
            #pragma unroll
            for (int dh = 0; dh < 3; ++dh) {
                const int h = ho * STRIDE - 1 + dh;
                if (h < 0 || h >= 14) continue;
                float xl[14], xh[14];
                #pragma unroll
                for (int iw = 0; iw < 14; ++iw) {
                    const unsigned u = *(const unsigned*)
                        &smem[(dt * 196 + h * 14 + iw) * 96 + 2 * l];
                    xl[iw] = __uint_as_float(u << 16);
                    xh[iw] = __uint_as_float(u & 0xffff0000u);
                }
                const int tapb = dt * 9 + dh * 3;
                #pragma unroll
                for (int wo = 0; wo < OW; ++wo)
                    #pragma unroll
                    for (int dw = 0; dw < 3; ++dw) {
                        const int iw = wo * STRIDE - 1 + dw;
                        if (iw < 0 || iw >= 14) continue;   // compile-time
                        a0[wo] += wg0[tapb + dw] * xl[iw];
                        a1[wo] += wg1[tapb + dw] * xh[iw];
                    }
            }
        }

        #pragma unroll
        for (int wo = 0; wo < OW; ++wo) {
            const float va = act ? a0[wo] : 0.f, vb = act ? a1[wo] : 0.f;
            float s = va + vb;
            #pragma unroll
            for (int off = 32; off; off >>= 1) s += __shfl_xor(s, off, 64);
            float sq = va * va + vb * vb;
            #pragma unroll
            for (int off = 32; off; off >>= 1) sq += __shfl_xor(sq, off, 64);
            const float mu = s * (1.f / 96.f);
            const float rstd = rsqrtf(sq * (1.f / 96.f) - mu * mu + 1e-5f);
            const float y0 = ((va - mu) * rstd * gam0 + bet0) * oscale;
            const float y1 = ((vb - mu) * rstd * gam1 + bet1) * oscale;
            const int tok = 1 + (to * OH + ho) * OW + wo;
            if (act) {
                if constexpr (MODE == 2) {
                    out[((size_t)bh * 96 + 2 * l) * KPAD + tok] = f2bf(y0);
                    out[((size_t)bh * 96 + 2 * l + 1) * KPAD + tok] = f2bf(y1);
                } else {
                    const unsigned pk = (unsigned)f2bf(y0) | ((unsigned)f2bf(y1) << 16);
                    *(unsigned*)&out[((size_t)bh * tokstride + tok) * 96 + 2 * l] = pk;
                }
            }
        }
    }

    if (to == 0 && wv == 7) {        // cls token: LN only
        const unsigned u = *(const unsigned*)&in[inbase + 2 * l];
        const float va = act ? __uint_as_float(u << 16) : 0.f;
        const float vb = act ? __uint_as_float(u & 0xffff0000u) : 0.f;
        float s = va + vb;
        #pragma unroll
        for (int off = 32; off; off >>= 1) s += __shfl_xor(s, off, 64);
        float sq = va * va + vb * vb;
        #pragma unroll
        for (int off = 32; off; off >>= 1) sq += __shfl_xor(sq, off, 64);
        const float mu = s * (1.f / 96.f);
        const float rstd = rsqrtf(sq * (1.f / 96.f) - mu * mu + 1e-5f);
        const float y0 = ((va - mu) * rstd * gam0 + bet0) * oscale;
        const float y1 = ((vb - mu) * rstd * gam1 + bet1) * oscale;
        if (act) {
            if constexpr (MODE == 2) {
                out[((size_t)bh * 96 + 2 * l) * KPAD] = f2bf(y0);
                out[((size_t)bh * 96 + 2 * l + 1) * KPAD] = f2bf(y1);
            } else {
                const unsigned pk = (unsigned)f2bf(y0) | ((unsigned)f2bf(y1) << 16);
                *(unsigned*)&out[(size_t)bh * tokstride * 96 + 2 * l] = pk;
            }
        }
    }
}

__global__ __launch_bounds__(512, 1)
void pool_ln_fused_kernel(const u16* __restrict__ qin, const u16* __restrict__ kin,
                          const u16* __restrict__ vin,
                          const float* __restrict__ cwq, const float* __restrict__ cwk,
                          const float* __restrict__ cwv,
                          const float* __restrict__ gq, const float* __restrict__ bq,
                          const float* __restrict__ gk, const float* __restrict__ bk,
                          const float* __restrict__ gv, const float* __restrict__ bv,
                          u16* __restrict__ qout, u16* __restrict__ kout,
                          u16* __restrict__ vtout)
{
    extern __shared__ u16 smem[];              // [3][196][96] + pad
    float* wsm2 = (float*)(smem + 57344);      // [27][96] transposed weights

    const int tid = threadIdx.x;
    const unsigned wg = xcd_swizzle(blockIdx.x, gridDim.x);
    const int tensor = (int)(wg / 512);
    const int rem = (int)(wg - tensor * 512);
    const int bh = rem >> 3, to = rem & 7;

    const u16* in = tensor == 0 ? qin : (tensor == 1 ? kin : vin);
    const float* cw = tensor == 0 ? cwq : (tensor == 1 ? cwk : cwv);

    for (int i = tid; i < 96 * 27; i += 512) {
        const int tap = i / 96, ch = i - tap * 96;
        wsm2[i] = cw[ch * 27 + tap];
    }

    const size_t inbase = (size_t)bh * N_ * 96;
    #pragma unroll
    for (int it = 0; it < 14; ++it) {
        const int byte = (it * 512 + tid) * 16;
        int plane = byte / PLANE_B; if (plane > 2) plane = 2;
        const int remb = byte - plane * PLANE_B;
        const int tok = remb / 192;
        const int chb = remb - tok * 192;
        int t = to - 1 + plane; if (t < 0) t = 0; if (t > 7) t = 7;
        const u16* gsrc = in + inbase + (size_t)(1 + t * 196 + tok) * 96 + (chb >> 1);
        GLOAD_LDS16(gsrc, smem + (size_t)(it * 512 + (tid >> 6) * 64) * 8);
    }
    __syncthreads();

    if (tensor == 0)
        pool_block_body<1, 14, 14, 0>(smem, wsm2, gq, bq, in, inbase, qout, QPAD, bh, to, SCALE_);
    else if (tensor == 1)
        pool_block_body<2, 7, 7, 1>(smem, wsm2, gk, bk, in, inbase, kout, KPAD, bh, to, 1.f);
    else
        pool_block_body<2, 7, 7, 2>(smem, wsm2, gv, bv, in, inbase, vtout, KPAD, bh, to, 1.f);
}

// ---------------------------------------------------------------------------
// MFMA attention v2 -> bf16 [M_][768]. 32 q-rows/wave (2 subtiles), K reg
// double-buffer prefetch, VT loads hoisted before softmax. Q pre-scaled.
// ---------------------------------------------------------------------------
__global__ __launch_bounds__(256)
void attn_mfma_kernel(const u16* __restrict__ Q, const u16* __restrict__ K,
                      const u16* __restrict__ VT, u16* __restrict__ Out)
{
    __shared__ alignas(16) u16 plds[4][2][512];   // per-wave, per-subtile P tile
    const int tid  = threadIdx.x;
    const int w    = tid >> 6, lane = tid & 63;
    const int c    = lane & 15, g = lane >> 4;

    const unsigned wg = xcd_swizzle(blockIdx.x, gridDim.x);
    const int bh = (int)(wg / 13);
    const int b  = bh >> 3, hh = bh & 7;
    const int q0 = (int)(wg % 13) * 128 + w * 32;

    const size_t qbase = (size_t)bh * QPAD * 96;
    const size_t kbase = (size_t)bh * KPAD * 96;

    short8v qa[2][3];
    #pragma unroll
    for (int s2 = 0; s2 < 2; ++s2)
        #pragma unroll
        for (int kf = 0; kf < 3; ++kf)
            qa[s2][kf] = *(const short8v*)
                &Q[qbase + (size_t)(q0 + s2 * 16 + c) * 96 + kf * 32 + g * 8];

    f32x4 oacc[2][6];
    #pragma unroll
    for (int s2 = 0; s2 < 2; ++s2)
        #pragma unroll
        for (int t = 0; t < 6; ++t) oacc[s2][t] = (f32x4){0.f, 0.f, 0.f, 0.f};
    float lsum[2][4] = {{0.f,0.f,0.f,0.f},{0.f,0.f,0.f,0.f}};

    short8v kb[2][6];
#define LOADK(IDX, PR) do {                                                     \
    _Pragma("unroll")                                                           \
    for (int h = 0; h < 2; ++h)                                                 \
        _Pragma("unroll")                                                       \
        for (int kf = 0; kf < 3; ++kf)                                          \
            kb[IDX][h * 3 + kf] = *(const short8v*)                             \
                &K[kbase + (size_t)((PR) * 32 + h * 16 + c) * 96 + kf * 32 + g * 8]; \
    } while (0)

    LOADK(0, 0);

    #pragma unroll
    for (int pr = 0; pr < 13; ++pr) {
        const int cur = pr & 1, nxt = cur ^ 1;

        short8v vt[6];
        #pragma unroll
        for (int t = 0; t < 6; ++t)
            vt[t] = *(const short8v*)
                &VT[kbase + (size_t)(t * 16 + c) * KPAD + pr * 32 + g * 8];

        f32x4 sacc[2][2];
        __builtin_amdgcn_s_setprio(1);
        #pragma unroll
        for (int s2 = 0; s2 < 2; ++s2)
            #pragma unroll
            for (int h = 0; h < 2; ++h) {
                f32x4 sa = (f32x4){0.f, 0.f, 0.f, 0.f};
                sa = __builtin_amdgcn_mfma_f32_16x16x32_bf16(qa[s2][0], kb[cur][h*3+0], sa, 0, 0, 0);
                sa = __builtin_amdgcn_mfma_f32_16x16x32_bf16(qa[s2][1], kb[cur][h*3+1], sa, 0, 0, 0);
                sa = __builtin_amdgcn_mfma_f32_16x16x32_bf16(qa[s2][2], kb[cur][h*3+2], sa, 0, 0, 0);
                sacc[s2][h] = sa;
            }
        __builtin_amdgcn_s_setprio(0);

        if (pr < 12) LOADK(nxt, pr + 1);

        #pragma unroll
        for (int s2 = 0; s2 < 2; ++s2)
            #pragma unroll
            for (int h = 0; h < 2; ++h) {
                const int jcol = pr * 32 + h * 16 + c;
                #pragma unroll
                for (int r = 0; r < 4; ++r) {
                    float s = sacc[s2][h][r];
                    if (jcol >= NKV_) s = -1e30f;
                    const float p = __expf(s);
                    lsum[s2][r] += p;
                    const int q    = g * 4 + r;
                    const int j    = h * 16 + c;
                    const int dstL = q | ((j >> 3) << 4);
                    plds[w][s2][dstL * 8 + (j & 7)] = f2bf(p);
                }
            }
        asm volatile("s_waitcnt lgkmcnt(0)" ::: "memory");
        __builtin_amdgcn_sched_barrier(0);
        const short8v pa0 = *(const short8v*)&plds[w][0][lane * 8];
        const short8v pa1 = *(const short8v*)&plds[w][1][lane * 8];

        __builtin_amdgcn_s_setprio(1);
        #pragma unroll
        for (int t = 0; t < 6; ++t)
            oacc[0][t] = __builtin_amdgcn_mfma_f32_16x16x32_bf16(pa0, vt[t], oacc[0][t], 0, 0, 0);
        #pragma unroll
        for (int t = 0; t < 6; ++t)
            oacc[1][t] = __builtin_amdgcn_mfma_f32_16x16x32_bf16(pa1, vt[t], oacc[1][t], 0, 0, 0);
        __builtin_amdgcn_s_setprio(0);
    }
#undef LOADK

    float linv[2][4];
    #pragma unroll
    for (int s2 = 0; s2 < 2; ++s2)
        #pragma unroll
        for (int r = 0; r < 4; ++r) {
            float s = lsum[s2][r];
            s += __shfl_xor(s, 1, 64);
            s += __shfl_xor(s, 2, 64);
            s += __shfl_xor(s, 4, 64);
            s += __shfl_xor(s, 8, 64);
            linv[s2][r] = 1.f / s;
        }

    #pragma unroll
    for (int s2 = 0; s2 < 2; ++s2)
        #pragma unroll
        for (int t = 0; t < 6; ++t)
            #pragma unroll
            for (int r = 0; r < 4; ++r) {
                const int row = q0 + s2 * 16 + g * 4 + r;
                if (row < N_)
                    Out[((size_t)(b * N_ + row)) * 768 + hh * 96 + t * 16 + c] =
                        f2bf(oacc[s2][t][r] * linv[s2][r]);
            }
}

// ---------------------------------------------------------------------------
extern "C" void kernel_launch(void* const* d_in, const int* in_sizes, int n_in,
                              void* d_out, int out_size, void* d_ws, size_t ws_size,
                              hipStream_t stream)
{
    const float* x     = (const float*)d_in[0];
    const float* Wqkv  = (const float*)d_in[1];
    const float* bqkv  = (const float*)d_in[2];
    const float* Wproj = (const float*)d_in[3];
    const float* bproj = (const float*)d_in[4];
    const float* cwq   = (const float*)d_in[5];
    const float* cwk   = (const float*)d_in[6];
    const float* cwv   = (const float*)d_in[7];
    const float* lnqg  = (const float*)d_in[8];
    const float* lnqb  = (const float*)d_in[9];
    const float* lnkg  = (const float*)d_in[10];
    const float* lnkb  = (const float*)d_in[11];
    const float* lnvg  = (const float*)d_in[12];
    const float* lnvb  = (const float*)d_in[13];

    u16* ws = (u16*)d_ws;
    u16* qkv_raw = ws;                       // 3 x [B][NH][N][D] bf16
    u16* q16 = qkv_raw + 3 * QKV1;           // [64][QPAD][96]
    u16* k16 = q16 + (size_t)64 * QPAD * 96; // [64][KPAD][96]
    u16* vt16 = k16 + (size_t)64 * KPAD * 96;// [64][96][KPAD] (transposed)
    u16* x16    = vt16 + (size_t)64 * KPAD * 96;  // [12552][768]
    u16* Wqkvt  = x16 + (size_t)M_ * 768;         // [2304][768]
    u16* Wprojt = Wqkvt + (size_t)2304 * 768;     // [768][768]
    u16* attn16 = qkv_raw;                   // alias: raw dead after pooling
    float* out = (float*)d_out;

    // 0) converts / transposes / VT pad zero
    cvt_f32_to_bf16<<<(M_ * 768 / 4 + 255) / 256, 256, 0, stream>>>(x, x16, M_ * 768 / 4);
    transpose_cvt<<<dim3(2304 / 32, 768 / 32), 256, 0, stream>>>(Wqkv, Wqkvt, 2304);
    transpose_cvt<<<dim3(768 / 32, 768 / 32), 256, 0, stream>>>(Wproj, Wprojt, 768);
    zero_pad_vt<<<(64 * 96 * (KPAD - NKV_) + 255) / 256, 256, 0, stream>>>(vt16);

    // 1) qkv GEMM (8-wave pipelined MFMA) with bf16 scatter into q/k/v
    gemm_bf16_kernel<2304, true><<<18 * 99, 512, 0, stream>>>(x16, Wqkvt, bqkv, qkv_raw);

    // 2) fused pool + LN: one dispatch, block per (tensor, bh, to)
    pool_ln_fused_kernel<<<1536, 512, POOL_LDS_B, stream>>>(
        qkv_raw, qkv_raw + QKV1, qkv_raw + 2 * QKV1,
        cwq, cwk, cwv, lnqg, lnqb, lnkg, lnkb, lnvg, lnvb,
        q16, k16, vt16);

    // 3) MFMA attention v2 -> bf16 [M_][768]
    attn_mfma_kernel<<<13 * 64, 256, 0, stream>>>(q16, k16, vt16, attn16);

    // 4) output projection (8-wave pipelined MFMA) -> fp32 d_out
    gemm_bf16_kernel<768, false><<<6 * 99, 512, 0, stream>>>(attn16, Wprojt, bproj, out);
}

// Round 11
// 238.406 us; speedup vs baseline: 1.2102x; 1.2102x over previous
//
#include <hip/hip_runtime.h>
#include <hip/hip_bf16.h>
#include <math.h>

#define B_   8
#define NH_  8
#define D_   96
#define C_   768
#define N_   1569          // 8*14*14 + 1
#define NKV_ 393           // 8*7*7 + 1
#define M_   (B_*N_)       // 12552
#define QKV1 ((size_t)B_*NH_*N_*D_)    // 9,639,936 elems per tensor
#define QPAD 1664          // padded q rows per slab (13 tiles of 128)
#define KPAD 416           // padded kv rows per slab (13 tiles of 32)
#define SCALE_ 0.10206207261596575f    // 96^-0.5

using short8v = __attribute__((ext_vector_type(8))) short;
using f32x4   = __attribute__((ext_vector_type(4))) float;
typedef unsigned short u16;

#define GLOAD_LDS16(g, l) __builtin_amdgcn_global_load_lds( \
    (const __attribute__((address_space(1))) void*)(g),     \
    (__attribute__((address_space(3))) void*)(l), 16, 0, 0)

static __device__ __forceinline__ u16 f2bf(float f) {
    __hip_bfloat16 b = __float2bfloat16(f);
    return *(u16*)&b;
}
static __device__ __forceinline__ float bf2f(u16 v) {
    return __bfloat162float(*(const __hip_bfloat16*)&v);
}

// bijective XCD swizzle (m204): consecutive swizzled ids land on one XCD
static __device__ __forceinline__ unsigned xcd_swizzle(unsigned orig, unsigned nwg) {
    const unsigned qq = nwg >> 3, rr = nwg & 7;
    const unsigned xcd = orig & 7, loc = orig >> 3;
    return (xcd < rr ? xcd * (qq + 1) : rr * (qq + 1) + (xcd - rr) * qq) + loc;
}

// ---------------------------------------------------------------------------
// fp32 -> bf16 flat convert (n4 float4 chunks)
// ---------------------------------------------------------------------------
__global__ __launch_bounds__(256)
void cvt_f32_to_bf16(const float* __restrict__ in, u16* __restrict__ out, int n4)
{
    const int i = blockIdx.x * 256 + threadIdx.x;
    if (i < n4) {
        const float4 v = ((const float4*)in)[i];
        ushort4 o;
        o.x = f2bf(v.x); o.y = f2bf(v.y); o.z = f2bf(v.z); o.w = f2bf(v.w);
        ((ushort4*)out)[i] = o;
    }
}

// ---------------------------------------------------------------------------
// W [768][ncols] fp32  ->  Wt [ncols][768] bf16   (32x32 LDS tiles)
// ---------------------------------------------------------------------------
__global__ __launch_bounds__(256)
void transpose_cvt(const float* __restrict__ W, u16* __restrict__ Wt, int ncols)
{
    __shared__ float tile[32][33];
    const int tx = threadIdx.x & 31, ty = threadIdx.x >> 5;   // 32 x 8
    const int n0 = blockIdx.x * 32, k0 = blockIdx.y * 32;
    #pragma unroll
    for (int i = 0; i < 4; ++i)
        tile[ty + i * 8][tx] = W[(size_t)(k0 + ty + i * 8) * ncols + n0 + tx];
    __syncthreads();
    #pragma unroll
    for (int i = 0; i < 4; ++i)
        Wt[(size_t)(n0 + ty + i * 8) * 768 + k0 + tx] = f2bf(tile[tx][ty + i * 8]);
}

// ---------------------------------------------------------------------------
// zero V^T pad columns (j in [NKV_, KPAD)) — required finite for PV MFMA
// ---------------------------------------------------------------------------
__global__ __launch_bounds__(256)
void zero_pad_vt(u16* __restrict__ vt)
{
    const int i = blockIdx.x * 256 + threadIdx.x;
    const int total = 64 * 96 * (KPAD - NKV_);
    if (i < total) {
        const int j = i % (KPAD - NKV_);
        const int rest = i / (KPAD - NKV_);     // slab*96 + d
        vt[(size_t)rest * KPAD + NKV_ + j] = 0;
    }
}

// ---------------------------------------------------------------------------
// bf16 MFMA GEMM, counted-vmcnt pipeline (T3+T4) + LDS XOR swizzle (T2).
// 512 threads / 8 waves (2x4), 64x32 per wave. T5 setprio around MFMA.
// ---------------------------------------------------------------------------
template<int NC, bool SCATTER>
__global__ __launch_bounds__(512)
void gemm_bf16_kernel(const u16* __restrict__ A, const u16* __restrict__ Bt,
                      const float* __restrict__ bias, void* __restrict__ outp)
{
    constexpr int NXT = NC / 128;
    __shared__ alignas(16) u16 As[2][128 * 64];
    __shared__ alignas(16) u16 Bs[2][128 * 64];

    const int tid  = threadIdx.x;
    const int w    = tid >> 6, lane = tid & 63;
    const int c    = lane & 15, g = lane >> 4;
    const int wm   = w >> 2, wn = w & 3;      // 2 x 4 wave grid
    const int lrow = lane >> 3, lcol = lane & 7;

    const unsigned wg = xcd_swizzle(blockIdx.x, gridDim.x);
    const int m0 = (int)(wg / NXT) * 128;
    const int n0 = (int)(wg % NXT) * 128;

    f32x4 acc[4][2];
    #pragma unroll
    for (int i = 0; i < 4; ++i)
        #pragma unroll
        for (int j = 0; j < 2; ++j) acc[i][j] = (f32x4){0.f, 0.f, 0.f, 0.f};

#define STAGE(BUF, K0) do {                                                      \
    _Pragma("unroll")                                                            \
    for (int t = 0; t < 2; ++t) {                                                \
        const int r = t * 64 + w * 8;                                            \
        const int row = r + lrow;                                                \
        const int scol = (lcol ^ (row & 7)) * 8;                                 \
        int m = m0 + row; if (m >= M_) m = M_ - 1;                               \
        GLOAD_LDS16(&A[(size_t)m * 768 + (K0) + scol], &As[BUF][r * 64]);        \
        GLOAD_LDS16(&Bt[(size_t)(n0 + row) * 768 + (K0) + scol],                 \
                    &Bs[BUF][r * 64]);                                           \
    } } while (0)

    const int xora = (g ^ (c & 7)) * 8;          // kk=0: logical col16 = g
    const int xorb = ((4 + g) ^ (c & 7)) * 8;    // kk=1: logical col16 = 4+g

#define KSTEP(BUF, LAST, PREF, KNEXT) do {                                       \
    if (LAST) asm volatile("s_waitcnt vmcnt(0)" ::: "memory");                   \
    else      asm volatile("s_waitcnt vmcnt(4)" ::: "memory");                   \
    __builtin_amdgcn_s_barrier();                                                \
    short8v a0[4], a1[4], b0[2], b1[2];                                          \
    _Pragma("unroll")                                                            \
    for (int i = 0; i < 4; ++i) {                                                \
        const int ra = (wm * 64 + i * 16 + c) * 64;                              \
        a0[i] = *(const short8v*)&As[BUF][ra + xora];                            \
        a1[i] = *(const short8v*)&As[BUF][ra + xorb];                            \
    }                                                                            \
    _Pragma("unroll")                                                            \
    for (int j = 0; j < 2; ++j) {                                                \
        const int rb = (wn * 32 + j * 16 + c) * 64;                              \
        b0[j] = *(const short8v*)&Bs[BUF][rb + xora];                            \
        b1[j] = *(const short8v*)&Bs[BUF][rb + xorb];                            \
    }                                                                            \
    asm volatile("s_waitcnt lgkmcnt(0)" ::: "memory");                           \
    __builtin_amdgcn_sched_barrier(0);                                           \
    __builtin_amdgcn_s_barrier();                                                \
    if (PREF) STAGE(BUF, KNEXT);                                                 \
    __builtin_amdgcn_s_setprio(1);                                               \
    _Pragma("unroll")                                                            \
    for (int i = 0; i < 4; ++i)                                                  \
        _Pragma("unroll")                                                        \
        for (int j = 0; j < 2; ++j)                                              \
            acc[i][j] = __builtin_amdgcn_mfma_f32_16x16x32_bf16(                 \
                a0[i], b0[j], acc[i][j], 0, 0, 0);                               \
    _Pragma("unroll")                                                            \
    for (int i = 0; i < 4; ++i)                                                  \
        _Pragma("unroll")                                                        \
        for (int j = 0; j < 2; ++j)                                              \
            acc[i][j] = __builtin_amdgcn_mfma_f32_16x16x32_bf16(                 \
                a1[i], b1[j], acc[i][j], 0, 0, 0);                               \
    __builtin_amdgcn_s_setprio(0);                                               \
    } while (0)

    STAGE(0, 0);
    STAGE(1, 64);
    #pragma unroll
    for (int tt = 0; tt < 5; ++tt) {
        KSTEP(0, false, true, (2 * tt + 2) * 64);
        KSTEP(1, false, true, (2 * tt + 3) * 64);
    }
    KSTEP(0, false, false, 0);
    KSTEP(1, true,  false, 0);
#undef STAGE
#undef KSTEP

    #pragma unroll
    for (int i = 0; i < 4; ++i) {
        const int mrow = m0 + wm * 64 + i * 16 + g * 4;
        #pragma unroll
        for (int j = 0; j < 2; ++j) {
            const int ncol = n0 + wn * 32 + j * 16 + c;
            const float bv = bias[ncol];
            if constexpr (SCATTER) {
                u16* out = (u16*)outp;
                const int s   = ncol / C_;          // 0=q,1=k,2=v
                const int rem = ncol - s * C_;
                const int hh  = rem / D_;
                const int dd  = rem - hh * D_;
                #pragma unroll
                for (int r = 0; r < 4; ++r) {
                    const int m = mrow + r;
                    if (m < M_) {
                        const int bb2 = m / N_;
                        const int n = m - bb2 * N_;
                        out[(size_t)s * QKV1 +
                            ((size_t)(bb2 * NH_ + hh) * N_ + n) * D_ + dd] = f2bf(acc[i][j][r] + bv);
                    }
                }
            } else {
                float* out = (float*)outp;
                #pragma unroll
                for (int r = 0; r < 4; ++r) {
                    const int m = mrow + r;
                    if (m < M_) out[(size_t)m * NC + ncol] = acc[i][j][r] + bv;
                }
            }
        }
    }
}

// ---------------------------------------------------------------------------
// Fused pool+LN v2: one block per (tensor, bh, to, h-half). Stages only the
// 8 h-rows this half needs (3 planes x 8 x 14 x 96 bf16 = 64.5KB) ->
// 2 blocks/CU (4 waves/SIMD) for latency hiding. 512 threads.
// MODE: 0=q ([tok][96], scaled), 1=k ([tok][96]), 2=v^T ([96][KPAD]).
// ---------------------------------------------------------------------------
#define PSLAB_U16 (8 * 14 * 96)            // u16 per plane slab (8 h-rows)
#define POOL2_LDS_B (3 * PSLAB_U16 * 2 + 96 * 27 * 4)   // 64512 + 10368

template<int STRIDE, int OH, int OW, int MODE>
static __device__ __forceinline__
void pool_half_body(const u16* __restrict__ smem, const float* __restrict__ wsm2,
                    const float* __restrict__ g, const float* __restrict__ bta,
                    const u16* __restrict__ in, size_t inbase,
                    u16* __restrict__ out, int tokstride, int bh, int to,
                    int half, float oscale)
{
    const int tid = threadIdx.x;
    const int wv = tid >> 6, lane = tid & 63;
    const int l = lane < 48 ? lane : 47;
    const bool act = lane < 48;
    constexpr int H0CNT = (OH + 1) / 2;        // q:7, kv:4
    const int h0 = half ? 6 : 0;
    const int nho = half ? (OH - H0CNT) : H0CNT;

    const float gam0 = g[2 * l],     bet0 = bta[2 * l];
    const float gam1 = g[2 * l + 1], bet1 = bta[2 * l + 1];

    if (wv < nho) {
        const int ho = half * H0CNT + wv;
        float a0[OW], a1[OW];
        #pragma unroll
        for (int wo = 0; wo < OW; ++wo) { a0[wo] = 0.f; a1[wo] = 0.f; }

        #pragma unroll
        for (int dt = 0; dt < 3; ++dt) {
            const int t = to - 1 + dt;
            if (t < 0 || t > 7) continue;
            #pragma unroll
            for (int dh = 0; dh < 3; ++dh) {
                const int h = ho * STRIDE - 1 + dh;
                if (h < h0 || h >= h0 + 8 || h >= 14) continue;  // wave-uniform
                const int hl = h - h0;
                float xl[14], xh[14];
                #pragma unroll
                for (int iw = 0; iw < 14; ++iw) {
                    const unsigned u = *(const unsigned*)
                        &smem[(dt * 8 + hl) * 1344 + iw * 96 + 2 * l];
                    xl[iw] = __uint_as_float(u << 16);
                    xh[iw] = __uint_as_float(u & 0xffff0000u);
                }
                const int tapb = dt * 9 + dh * 3;
                float wt0[3], wt1[3];
                #pragma unroll
                for (int dw = 0; dw < 3; ++dw) {
                    const float2 wp = *(const float2*)&wsm2[(tapb + dw) * 96 + 2 * l];
                    wt0[dw] = wp.x; wt1[dw] = wp.y;
                }
                #pragma unroll
                for (int wo = 0; wo < OW; ++wo)
                    #pragma unroll
                    for (int dw = 0; dw < 3; ++dw) {
                        const int iw = wo * STRIDE - 1 + dw;
                        if (iw < 0 || iw >= 14) continue;   // compile-time
                        a0[wo] += wt0[dw] * xl[iw];
                        a1[wo] += wt1[dw] * xh[iw];
                    }
            }
        }

        #pragma unroll
        for (int wo = 0; wo < OW; ++wo) {
            const float va = act ? a0[wo] : 0.f, vb = act ? a1[wo] : 0.f;
            float s = va + vb;
            #pragma unroll
            for (int off = 32; off; off >>= 1) s += __shfl_xor(s, off, 64);
            float sq = va * va + vb * vb;
            #pragma unroll
            for (int off = 32; off; off >>= 1) sq += __shfl_xor(sq, off, 64);
            const float mu = s * (1.f / 96.f);
            const float rstd = rsqrtf(sq * (1.f / 96.f) - mu * mu + 1e-5f);
            const float y0 = ((va - mu) * rstd * gam0 + bet0) * oscale;
            const float y1 = ((vb - mu) * rstd * gam1 + bet1) * oscale;
            const int tok = 1 + (to * OH + ho) * OW + wo;
            if (act) {
                if constexpr (MODE == 2) {
                    out[((size_t)bh * 96 + 2 * l) * KPAD + tok] = f2bf(y0);
                    out[((size_t)bh * 96 + 2 * l + 1) * KPAD + tok] = f2bf(y1);
                } else {
                    const unsigned pk = (unsigned)f2bf(y0) | ((unsigned)f2bf(y1) << 16);
                    *(unsigned*)&out[((size_t)bh * tokstride + tok) * 96 + 2 * l] = pk;
                }
            }
        }
    }

    if (to == 0 && half == 0 && wv == 7) {      // cls token: LN only
        const unsigned u = *(const unsigned*)&in[inbase + 2 * l];
        const float va = act ? __uint_as_float(u << 16) : 0.f;
        const float vb = act ? __uint_as_float(u & 0xffff0000u) : 0.f;
        float s = va + vb;
        #pragma unroll
        for (int off = 32; off; off >>= 1) s += __shfl_xor(s, off, 64);
        float sq = va * va + vb * vb;
        #pragma unroll
        for (int off = 32; off; off >>= 1) sq += __shfl_xor(sq, off, 64);
        const float mu = s * (1.f / 96.f);
        const float rstd = rsqrtf(sq * (1.f / 96.f) - mu * mu + 1e-5f);
        const float y0 = ((va - mu) * rstd * gam0 + bet0) * oscale;
        const float y1 = ((vb - mu) * rstd * gam1 + bet1) * oscale;
        if (act) {
            if constexpr (MODE == 2) {
                out[((size_t)bh * 96 + 2 * l) * KPAD] = f2bf(y0);
                out[((size_t)bh * 96 + 2 * l + 1) * KPAD] = f2bf(y1);
            } else {
                const unsigned pk = (unsigned)f2bf(y0) | ((unsigned)f2bf(y1) << 16);
                *(unsigned*)&out[(size_t)bh * tokstride * 96 + 2 * l] = pk;
            }
        }
    }
}

__global__ __launch_bounds__(512, 4)
void pool_ln_fused_kernel(const u16* __restrict__ qin, const u16* __restrict__ kin,
                          const u16* __restrict__ vin,
                          const float* __restrict__ cwq, const float* __restrict__ cwk,
                          const float* __restrict__ cwv,
                          const float* __restrict__ gq, const float* __restrict__ bq,
                          const float* __restrict__ gk, const float* __restrict__ bk,
                          const float* __restrict__ gv, const float* __restrict__ bv,
                          u16* __restrict__ qout, u16* __restrict__ kout,
                          u16* __restrict__ vtout)
{
    extern __shared__ u16 smem[];              // [3][8][14][96] bf16
    float* wsm2 = (float*)(smem + 3 * PSLAB_U16);   // [27][96] transposed weights

    const int tid = threadIdx.x;
    const int wv = tid >> 6;
    const unsigned wg = xcd_swizzle(blockIdx.x, gridDim.x);
    const int tensor = (int)(wg >> 10);            // /1024
    const int rem = (int)(wg & 1023);
    const int bh = rem >> 4, to = (rem >> 1) & 7, half = rem & 1;
    const int h0 = half ? 6 : 0;

    const u16* in = tensor == 0 ? qin : (tensor == 1 ? kin : vin);
    const float* cw = tensor == 0 ? cwq : (tensor == 1 ? cwk : cwv);
    const size_t inbase = (size_t)bh * N_ * 96;

    // stage 3 planes x 8 h-rows x 14 tokens x 96ch: 4032 16B chunks
    #pragma unroll
    for (int it = 0; it < 8; ++it) {
        if (it == 7 && wv >= 7) break;             // wave-uniform tail guard
        const int chunk = it * 512 + tid;
        const int plane = chunk / 1344;            // 1344 chunks per plane
        const int remc  = chunk - plane * 1344;
        const int hrow  = remc / 168;              // 168 chunks per h-row
        const int rem2  = remc - hrow * 168;
        const int tokw  = (rem2 * 16) / 192;
        const int choff = ((rem2 * 16) - tokw * 192) >> 1;
        int t = to - 1 + plane; if (t < 0) t = 0; if (t > 7) t = 7;
        const int token = 1 + t * 196 + (h0 + hrow) * 14 + tokw;
        GLOAD_LDS16(in + inbase + (size_t)token * 96 + choff,
                    smem + (size_t)(it * 512 + wv * 64) * 8);
    }
    // weights load overlaps staging (drained by syncthreads)
    for (int i = tid; i < 96 * 27; i += 512) {
        const int tap = i / 96, ch = i - tap * 96;
        wsm2[i] = cw[ch * 27 + tap];
    }
    __syncthreads();

    if (tensor == 0)
        pool_half_body<1, 14, 14, 0>(smem, wsm2, gq, bq, in, inbase, qout, QPAD, bh, to, half, SCALE_);
    else if (tensor == 1)
        pool_half_body<2, 7, 7, 1>(smem, wsm2, gk, bk, in, inbase, kout, KPAD, bh, to, half, 1.f);
    else
        pool_half_body<2, 7, 7, 2>(smem, wsm2, gv, bv, in, inbase, vtout, KPAD, bh, to, half, 1.f);
}

// ---------------------------------------------------------------------------
// MFMA attention v2 -> bf16 [M_][768]. 32 q-rows/wave (2 subtiles), K reg
// double-buffer prefetch, VT loads hoisted before softmax. Q pre-scaled.
// ---------------------------------------------------------------------------
__global__ __launch_bounds__(256)
void attn_mfma_kernel(const u16* __restrict__ Q, const u16* __restrict__ K,
                      const u16* __restrict__ VT, u16* __restrict__ Out)
{
    __shared__ alignas(16) u16 plds[4][2][512];   // per-wave, per-subtile P tile
    const int tid  = threadIdx.x;
    const int w    = tid >> 6, lane = tid & 63;
    const int c    = lane & 15, g = lane >> 4;

    const unsigned wg = xcd_swizzle(blockIdx.x, gridDim.x);
    const int bh = (int)(wg / 13);
    const int b  = bh >> 3, hh = bh & 7;
    const int q0 = (int)(wg % 13) * 128 + w * 32;

    const size_t qbase = (size_t)bh * QPAD * 96;
    const size_t kbase = (size_t)bh * KPAD * 96;

    short8v qa[2][3];
    #pragma unroll
    for (int s2 = 0; s2 < 2; ++s2)
        #pragma unroll
        for (int kf = 0; kf < 3; ++kf)
            qa[s2][kf] = *(const short8v*)
                &Q[qbase + (size_t)(q0 + s2 * 16 + c) * 96 + kf * 32 + g * 8];

    f32x4 oacc[2][6];
    #pragma unroll
    for (int s2 = 0; s2 < 2; ++s2)
        #pragma unroll
        for (int t = 0; t < 6; ++t) oacc[s2][t] = (f32x4){0.f, 0.f, 0.f, 0.f};
    float lsum[2][4] = {{0.f,0.f,0.f,0.f},{0.f,0.f,0.f,0.f}};

    short8v kb[2][6];
#define LOADK(IDX, PR) do {                                                     \
    _Pragma("unroll")                                                           \
    for (int h = 0; h < 2; ++h)                                                 \
        _Pragma("unroll")                                                       \
        for (int kf = 0; kf < 3; ++kf)                                          \
            kb[IDX][h * 3 + kf] = *(const short8v*)                             \
                &K[kbase + (size_t)((PR) * 32 + h * 16 + c) * 96 + kf * 32 + g * 8]; \
    } while (0)

    LOADK(0, 0);

    #pragma unroll
    for (int pr = 0; pr < 13; ++pr) {
        const int cur = pr & 1, nxt = cur ^ 1;

        short8v vt[6];
        #pragma unroll
        for (int t = 0; t < 6; ++t)
            vt[t] = *(const short8v*)
                &VT[kbase + (size_t)(t * 16 + c) * KPAD + pr * 32 + g * 8];

        f32x4 sacc[2][2];
        __builtin_amdgcn_s_setprio(1);
        #pragma unroll
        for (int s2 = 0; s2 < 2; ++s2)
            #pragma unroll
            for (int h = 0; h < 2; ++h) {
                f32x4 sa = (f32x4){0.f, 0.f, 0.f, 0.f};
                sa = __builtin_amdgcn_mfma_f32_16x16x32_bf16(qa[s2][0], kb[cur][h*3+0], sa, 0, 0, 0);
                sa = __builtin_amdgcn_mfma_f32_16x16x32_bf16(qa[s2][1], kb[cur][h*3+1], sa, 0, 0, 0);
                sa = __builtin_amdgcn_mfma_f32_16x16x32_bf16(qa[s2][2], kb[cur][h*3+2], sa, 0, 0, 0);
                sacc[s2][h] = sa;
            }
        __builtin_amdgcn_s_setprio(0);

        if (pr < 12) LOADK(nxt, pr + 1);

        #pragma unroll
        for (int s2 = 0; s2 < 2; ++s2)
            #pragma unroll
            for (int h = 0; h < 2; ++h) {
                const int jcol = pr * 32 + h * 16 + c;
                #pragma unroll
                for (int r = 0; r < 4; ++r) {
                    float s = sacc[s2][h][r];
                    if (jcol >= NKV_) s = -1e30f;
                    const float p = __expf(s);
                    lsum[s2][r] += p;
                    const int q    = g * 4 + r;
                    const int j    = h * 16 + c;
                    const int dstL = q | ((j >> 3) << 4);
                    plds[w][s2][dstL * 8 + (j & 7)] = f2bf(p);
                }
            }
        asm volatile("s_waitcnt lgkmcnt(0)" ::: "memory");
        __builtin_amdgcn_sched_barrier(0);
        const short8v pa0 = *(const short8v*)&plds[w][0][lane * 8];
        const short8v pa1 = *(const short8v*)&plds[w][1][lane * 8];

        __builtin_amdgcn_s_setprio(1);
        #pragma unroll
        for (int t = 0; t < 6; ++t)
            oacc[0][t] = __builtin_amdgcn_mfma_f32_16x16x32_bf16(pa0, vt[t], oacc[0][t], 0, 0, 0);
        #pragma unroll
        for (int t = 0; t < 6; ++t)
            oacc[1][t] = __builtin_amdgcn_mfma_f32_16x16x32_bf16(pa1, vt[t], oacc[1][t], 0, 0, 0);
        __builtin_amdgcn_s_setprio(0);
    }
#undef LOADK

    float linv[2][4];
    #pragma unroll
    for (int s2 = 0; s2 < 2; ++s2)
        #pragma unroll
        for (int r = 0; r < 4; ++r) {
            float s = lsum[s2][r];
            s += __shfl_xor(s, 1, 64);
            s += __shfl_xor(s, 2, 64);
            s += __shfl_xor(s, 4, 64);
            s += __shfl_xor(s, 8, 64);
            linv[s2][r] = 1.f / s;
        }

    #pragma unroll
    for (int s2 = 0; s2 < 2; ++s2)
        #pragma unroll
        for (int t = 0; t < 6; ++t)
            #pragma unroll
            for (int r = 0; r < 4; ++r) {
                const int row = q0 + s2 * 16 + g * 4 + r;
                if (row < N_)
                    Out[((size_t)(b * N_ + row)) * 768 + hh * 96 + t * 16 + c] =
                        f2bf(oacc[s2][t][r] * linv[s2][r]);
            }
}

// ---------------------------------------------------------------------------
extern "C" void kernel_launch(void* const* d_in, const int* in_sizes, int n_in,
                              void* d_out, int out_size, void* d_ws, size_t ws_size,
                              hipStream_t stream)
{
    const float* x     = (const float*)d_in[0];
    const float* Wqkv  = (const float*)d_in[1];
    const float* bqkv  = (const float*)d_in[2];
    const float* Wproj = (const float*)d_in[3];
    const float* bproj = (const float*)d_in[4];
    const float* cwq   = (const float*)d_in[5];
    const float* cwk   = (const float*)d_in[6];
    const float* cwv   = (const float*)d_in[7];
    const float* lnqg  = (const float*)d_in[8];
    const float* lnqb  = (const float*)d_in[9];
    const float* lnkg  = (const float*)d_in[10];
    const float* lnkb  = (const float*)d_in[11];
    const float* lnvg  = (const float*)d_in[12];
    const float* lnvb  = (const float*)d_in[13];

    u16* ws = (u16*)d_ws;
    u16* qkv_raw = ws;                       // 3 x [B][NH][N][D] bf16
    u16* q16 = qkv_raw + 3 * QKV1;           // [64][QPAD][96]
    u16* k16 = q16 + (size_t)64 * QPAD * 96; // [64][KPAD][96]
    u16* vt16 = k16 + (size_t)64 * KPAD * 96;// [64][96][KPAD] (transposed)
    u16* x16    = vt16 + (size_t)64 * KPAD * 96;  // [12552][768]
    u16* Wqkvt  = x16 + (size_t)M_ * 768;         // [2304][768]
    u16* Wprojt = Wqkvt + (size_t)2304 * 768;     // [768][768]
    u16* attn16 = qkv_raw;                   // alias: raw dead after pooling
    float* out = (float*)d_out;

    // 0) converts / transposes / VT pad zero
    cvt_f32_to_bf16<<<(M_ * 768 / 4 + 255) / 256, 256, 0, stream>>>(x, x16, M_ * 768 / 4);
    transpose_cvt<<<dim3(2304 / 32, 768 / 32), 256, 0, stream>>>(Wqkv, Wqkvt, 2304);
    transpose_cvt<<<dim3(768 / 32, 768 / 32), 256, 0, stream>>>(Wproj, Wprojt, 768);
    zero_pad_vt<<<(64 * 96 * (KPAD - NKV_) + 255) / 256, 256, 0, stream>>>(vt16);

    // 1) qkv GEMM (8-wave pipelined MFMA) with bf16 scatter into q/k/v
    gemm_bf16_kernel<2304, true><<<18 * 99, 512, 0, stream>>>(x16, Wqkvt, bqkv, qkv_raw);

    // 2) fused pool + LN v2: block per (tensor, bh, to, h-half), 2 blocks/CU
    pool_ln_fused_kernel<<<3072, 512, POOL2_LDS_B, stream>>>(
        qkv_raw, qkv_raw + QKV1, qkv_raw + 2 * QKV1,
        cwq, cwk, cwv, lnqg, lnqb, lnkg, lnkb, lnvg, lnvb,
        q16, k16, vt16);

    // 3) MFMA attention v2 -> bf16 [M_][768]
    attn_mfma_kernel<<<13 * 64, 256, 0, stream>>>(q16, k16, vt16, attn16);

    // 4) output projection (8-wave pipelined MFMA) -> fp32 d_out
    gemm_bf16_kernel<768, false><<<6 * 99, 512, 0, stream>>>(attn16, Wprojt, bproj, out);
}

// Round 12
// 233.417 us; speedup vs baseline: 1.2361x; 1.0214x over previous
//
#include <hip/hip_runtime.h>
#include <hip/hip_bf16.h>
#include <math.h>

#define B_   8
#define NH_  8
#define D_   96
#define C_   768
#define N_   1569          // 8*14*14 + 1
#define NKV_ 393           // 8*7*7 + 1
#define M_   (B_*N_)       // 12552
#define QKV1 ((size_t)B_*NH_*N_*D_)    // 9,639,936 elems per tensor
#define QPAD 1664          // padded q rows per slab (13 tiles of 128)
#define KPAD 416           // padded kv rows per slab (13 tiles of 32)
#define SCALE_ 0.10206207261596575f    // 96^-0.5

using short8v = __attribute__((ext_vector_type(8))) short;
using f32x4   = __attribute__((ext_vector_type(4))) float;
using f32x2   = __attribute__((ext_vector_type(2))) float;
typedef unsigned short u16;

#define GLOAD_LDS16(g, l) __builtin_amdgcn_global_load_lds( \
    (const __attribute__((address_space(1))) void*)(g),     \
    (__attribute__((address_space(3))) void*)(l), 16, 0, 0)

static __device__ __forceinline__ u16 f2bf(float f) {
    __hip_bfloat16 b = __float2bfloat16(f);
    return *(u16*)&b;
}
static __device__ __forceinline__ float bf2f(u16 v) {
    return __bfloat162float(*(const __hip_bfloat16*)&v);
}

// bijective XCD swizzle (m204): consecutive swizzled ids land on one XCD
static __device__ __forceinline__ unsigned xcd_swizzle(unsigned orig, unsigned nwg) {
    const unsigned qq = nwg >> 3, rr = nwg & 7;
    const unsigned xcd = orig & 7, loc = orig >> 3;
    return (xcd < rr ? xcd * (qq + 1) : rr * (qq + 1) + (xcd - rr) * qq) + loc;
}

// ---------------------------------------------------------------------------
// fp32 -> bf16 flat convert (n4 float4 chunks)
// ---------------------------------------------------------------------------
__global__ __launch_bounds__(256)
void cvt_f32_to_bf16(const float* __restrict__ in, u16* __restrict__ out, int n4)
{
    const int i = blockIdx.x * 256 + threadIdx.x;
    if (i < n4) {
        const float4 v = ((const float4*)in)[i];
        ushort4 o;
        o.x = f2bf(v.x); o.y = f2bf(v.y); o.z = f2bf(v.z); o.w = f2bf(v.w);
        ((ushort4*)out)[i] = o;
    }
}

// ---------------------------------------------------------------------------
// W [768][ncols] fp32  ->  Wt [ncols][768] bf16   (32x32 LDS tiles)
// ---------------------------------------------------------------------------
__global__ __launch_bounds__(256)
void transpose_cvt(const float* __restrict__ W, u16* __restrict__ Wt, int ncols)
{
    __shared__ float tile[32][33];
    const int tx = threadIdx.x & 31, ty = threadIdx.x >> 5;   // 32 x 8
    const int n0 = blockIdx.x * 32, k0 = blockIdx.y * 32;
    #pragma unroll
    for (int i = 0; i < 4; ++i)
        tile[ty + i * 8][tx] = W[(size_t)(k0 + ty + i * 8) * ncols + n0 + tx];
    __syncthreads();
    #pragma unroll
    for (int i = 0; i < 4; ++i)
        Wt[(size_t)(n0 + ty + i * 8) * 768 + k0 + tx] = f2bf(tile[tx][ty + i * 8]);
}

// ---------------------------------------------------------------------------
// zero V^T pad columns (j in [NKV_, KPAD)) — required finite for PV MFMA
// ---------------------------------------------------------------------------
__global__ __launch_bounds__(256)
void zero_pad_vt(u16* __restrict__ vt)
{
    const int i = blockIdx.x * 256 + threadIdx.x;
    const int total = 64 * 96 * (KPAD - NKV_);
    if (i < total) {
        const int j = i % (KPAD - NKV_);
        const int rest = i / (KPAD - NKV_);     // slab*96 + d
        vt[(size_t)rest * KPAD + NKV_ + j] = 0;
    }
}

// ---------------------------------------------------------------------------
// bf16 MFMA GEMM, counted-vmcnt pipeline (T3+T4) + LDS XOR swizzle (T2).
// 512 threads / 8 waves (2x4), 64x32 per wave. T5 setprio around MFMA.
// ---------------------------------------------------------------------------
template<int NC, bool SCATTER>
__global__ __launch_bounds__(512)
void gemm_bf16_kernel(const u16* __restrict__ A, const u16* __restrict__ Bt,
                      const float* __restrict__ bias, void* __restrict__ outp)
{
    constexpr int NXT = NC / 128;
    __shared__ alignas(16) u16 As[2][128 * 64];
    __shared__ alignas(16) u16 Bs[2][128 * 64];

    const int tid  = threadIdx.x;
    const int w    = tid >> 6, lane = tid & 63;
    const int c    = lane & 15, g = lane >> 4;
    const int wm   = w >> 2, wn = w & 3;      // 2 x 4 wave grid
    const int lrow = lane >> 3, lcol = lane & 7;

    const unsigned wg = xcd_swizzle(blockIdx.x, gridDim.x);
    const int m0 = (int)(wg / NXT) * 128;
    const int n0 = (int)(wg % NXT) * 128;

    f32x4 acc[4][2];
    #pragma unroll
    for (int i = 0; i < 4; ++i)
        #pragma unroll
        for (int j = 0; j < 2; ++j) acc[i][j] = (f32x4){0.f, 0.f, 0.f, 0.f};

#define STAGE(BUF, K0) do {                                                      \
    _Pragma("unroll")                                                            \
    for (int t = 0; t < 2; ++t) {                                                \
        const int r = t * 64 + w * 8;                                            \
        const int row = r + lrow;                                                \
        const int scol = (lcol ^ (row & 7)) * 8;                                 \
        int m = m0 + row; if (m >= M_) m = M_ - 1;                               \
        GLOAD_LDS16(&A[(size_t)m * 768 + (K0) + scol], &As[BUF][r * 64]);        \
        GLOAD_LDS16(&Bt[(size_t)(n0 + row) * 768 + (K0) + scol],                 \
                    &Bs[BUF][r * 64]);                                           \
    } } while (0)

    const int xora = (g ^ (c & 7)) * 8;          // kk=0: logical col16 = g
    const int xorb = ((4 + g) ^ (c & 7)) * 8;    // kk=1: logical col16 = 4+g

#define KSTEP(BUF, LAST, PREF, KNEXT) do {                                       \
    if (LAST) asm volatile("s_waitcnt vmcnt(0)" ::: "memory");                   \
    else      asm volatile("s_waitcnt vmcnt(4)" ::: "memory");                   \
    __builtin_amdgcn_s_barrier();                                                \
    short8v a0[4], a1[4], b0[2], b1[2];                                          \
    _Pragma("unroll")                                                            \
    for (int i = 0; i < 4; ++i) {                                                \
        const int ra = (wm * 64 + i * 16 + c) * 64;                              \
        a0[i] = *(const short8v*)&As[BUF][ra + xora];                            \
        a1[i] = *(const short8v*)&As[BUF][ra + xorb];                            \
    }                                                                            \
    _Pragma("unroll")                                                            \
    for (int j = 0; j < 2; ++j) {                                                \
        const int rb = (wn * 32 + j * 16 + c) * 64;                              \
        b0[j] = *(const short8v*)&Bs[BUF][rb + xora];                            \
        b1[j] = *(const short8v*)&Bs[BUF][rb + xorb];                            \
    }                                                                            \
    asm volatile("s_waitcnt lgkmcnt(0)" ::: "memory");                           \
    __builtin_amdgcn_sched_barrier(0);                                           \
    __builtin_amdgcn_s_barrier();                                                \
    if (PREF) STAGE(BUF, KNEXT);                                                 \
    __builtin_amdgcn_s_setprio(1);                                               \
    _Pragma("unroll")                                                            \
    for (int i = 0; i < 4; ++i)                                                  \
        _Pragma("unroll")                                                        \
        for (int j = 0; j < 2; ++j)                                              \
            acc[i][j] = __builtin_amdgcn_mfma_f32_16x16x32_bf16(                 \
                a0[i], b0[j], acc[i][j], 0, 0, 0);                               \
    _Pragma("unroll")                                                            \
    for (int i = 0; i < 4; ++i)                                                  \
        _Pragma("unroll")                                                        \
        for (int j = 0; j < 2; ++j)                                              \
            acc[i][j] = __builtin_amdgcn_mfma_f32_16x16x32_bf16(                 \
                a1[i], b1[j], acc[i][j], 0, 0, 0);                               \
    __builtin_amdgcn_s_setprio(0);                                               \
    } while (0)

    STAGE(0, 0);
    STAGE(1, 64);
    #pragma unroll
    for (int tt = 0; tt < 5; ++tt) {
        KSTEP(0, false, true, (2 * tt + 2) * 64);
        KSTEP(1, false, true, (2 * tt + 3) * 64);
    }
    KSTEP(0, false, false, 0);
    KSTEP(1, true,  false, 0);
#undef STAGE
#undef KSTEP

    #pragma unroll
    for (int i = 0; i < 4; ++i) {
        const int mrow = m0 + wm * 64 + i * 16 + g * 4;
        #pragma unroll
        for (int j = 0; j < 2; ++j) {
            const int ncol = n0 + wn * 32 + j * 16 + c;
            const float bv = bias[ncol];
            if constexpr (SCATTER) {
                u16* out = (u16*)outp;
                const int s   = ncol / C_;          // 0=q,1=k,2=v
                const int rem = ncol - s * C_;
                const int hh  = rem / D_;
                const int dd  = rem - hh * D_;
                #pragma unroll
                for (int r = 0; r < 4; ++r) {
                    const int m = mrow + r;
                    if (m < M_) {
                        const int bb2 = m / N_;
                        const int n = m - bb2 * N_;
                        out[(size_t)s * QKV1 +
                            ((size_t)(bb2 * NH_ + hh) * N_ + n) * D_ + dd] = f2bf(acc[i][j][r] + bv);
                    }
                }
            } else {
                float* out = (float*)outp;
                #pragma unroll
                for (int r = 0; r < 4; ++r) {
                    const int m = mrow + r;
                    if (m < M_) out[(size_t)m * NC + ncol] = acc[i][j][r] + bv;
                }
            }
        }
    }
}

// ---------------------------------------------------------------------------
// Fused pool+LN v3: block per (tensor, bh, to, h-half); 512 threads, 2/CU.
// All waves busy: q = row per wave; k/v = (row, w-half) per wave.
// Packed f32x2 channel-pair math (v_pk_fma_f32).
// MODE: 0=q ([tok][96], scaled), 1=k ([tok][96]), 2=v^T ([96][KPAD]).
// ---------------------------------------------------------------------------
#define PSLAB_U16 (8 * 14 * 96)            // u16 per plane slab (8 h-rows)
#define POOL2_LDS_B (3 * PSLAB_U16 * 2 + 96 * 27 * 4)   // 64512 + 10368

template<int MODE>
static __device__ __forceinline__
void pool_write(u16* __restrict__ out, int tokstride, int bh, int tok, int l,
                bool act, float y0, float y1)
{
    if (!act) return;
    if constexpr (MODE == 2) {
        out[((size_t)bh * 96 + 2 * l) * KPAD + tok] = f2bf(y0);
        out[((size_t)bh * 96 + 2 * l + 1) * KPAD + tok] = f2bf(y1);
    } else {
        const unsigned pk = (unsigned)f2bf(y0) | ((unsigned)f2bf(y1) << 16);
        *(unsigned*)&out[((size_t)bh * tokstride + tok) * 96 + 2 * l] = pk;
    }
}

template<int STRIDE, int MODE, int WO0, int WOCNT>
static __device__ __forceinline__
void pool_row(const u16* __restrict__ smem, const float* __restrict__ wsm2,
              f32x2 gamv, f32x2 betv, u16* __restrict__ out, int tokstride,
              int bh, int to, int ho, int h0, float oscale)
{
    constexpr int OHW = (MODE == 0) ? 14 : 7;
    constexpr int IWLO = (WO0 * STRIDE - 1) < 0 ? 0 : (WO0 * STRIDE - 1);
    constexpr int IWHI = ((WO0 + WOCNT - 1) * STRIDE + 1) > 13 ? 13
                       : ((WO0 + WOCNT - 1) * STRIDE + 1);
    const int lane = threadIdx.x & 63;
    const int l = lane < 48 ? lane : 47;
    const bool act = lane < 48;

    f32x2 a[WOCNT];
    #pragma unroll
    for (int i = 0; i < WOCNT; ++i) a[i] = (f32x2){0.f, 0.f};

    #pragma unroll
    for (int dt = 0; dt < 3; ++dt) {
        const int t = to - 1 + dt;
        if (t < 0 || t > 7) continue;
        #pragma unroll
        for (int dh = 0; dh < 3; ++dh) {
            const int h = ho * STRIDE - 1 + dh;
            if (h < h0 || h >= h0 + 8 || h >= 14) continue;   // wave-uniform
            const int hl = h - h0;
            f32x2 xv[14];
            #pragma unroll
            for (int iw = IWLO; iw <= IWHI; ++iw) {
                const unsigned u = *(const unsigned*)
                    &smem[(dt * 8 + hl) * 1344 + iw * 96 + 2 * l];
                xv[iw][0] = __uint_as_float(u << 16);
                xv[iw][1] = __uint_as_float(u & 0xffff0000u);
            }
            const int tapb = dt * 9 + dh * 3;
            f32x2 wt[3];
            #pragma unroll
            for (int dw = 0; dw < 3; ++dw)
                wt[dw] = *(const f32x2*)&wsm2[(tapb + dw) * 96 + 2 * l];
            #pragma unroll
            for (int i = 0; i < WOCNT; ++i)
                #pragma unroll
                for (int dw = 0; dw < 3; ++dw) {
                    const int iw = (WO0 + i) * STRIDE - 1 + dw;
                    if (iw < IWLO || iw > IWHI) continue;     // compile-time
                    a[i] = __builtin_elementwise_fma(wt[dw], xv[iw], a[i]);
                }
        }
    }

    #pragma unroll
    for (int i = 0; i < WOCNT; ++i) {
        const float va = act ? a[i][0] : 0.f, vb = act ? a[i][1] : 0.f;
        float s = va + vb;
        #pragma unroll
        for (int off = 32; off; off >>= 1) s += __shfl_xor(s, off, 64);
        float sq = va * va + vb * vb;
        #pragma unroll
        for (int off = 32; off; off >>= 1) sq += __shfl_xor(sq, off, 64);
        const float mu = s * (1.f / 96.f);
        const float rstd = rsqrtf(sq * (1.f / 96.f) - mu * mu + 1e-5f);
        const float y0 = ((va - mu) * rstd * gamv[0] + betv[0]) * oscale;
        const float y1 = ((vb - mu) * rstd * gamv[1] + betv[1]) * oscale;
        const int tok = 1 + (to * OHW + ho) * OHW + WO0 + i;
        pool_write<MODE>(out, tokstride, bh, tok, l, act, y0, y1);
    }
}

template<int MODE>
static __device__ __forceinline__
void pool_cls(const u16* __restrict__ in, size_t inbase, f32x2 gamv, f32x2 betv,
              u16* __restrict__ out, int tokstride, int bh, float oscale)
{
    const int lane = threadIdx.x & 63;
    const int l = lane < 48 ? lane : 47;
    const bool act = lane < 48;
    const unsigned u = *(const unsigned*)&in[inbase + 2 * l];
    const float va = act ? __uint_as_float(u << 16) : 0.f;
    const float vb = act ? __uint_as_float(u & 0xffff0000u) : 0.f;
    float s = va + vb;
    #pragma unroll
    for (int off = 32; off; off >>= 1) s += __shfl_xor(s, off, 64);
    float sq = va * va + vb * vb;
    #pragma unroll
    for (int off = 32; off; off >>= 1) sq += __shfl_xor(sq, off, 64);
    const float mu = s * (1.f / 96.f);
    const float rstd = rsqrtf(sq * (1.f / 96.f) - mu * mu + 1e-5f);
    const float y0 = ((va - mu) * rstd * gamv[0] + betv[0]) * oscale;
    const float y1 = ((vb - mu) * rstd * gamv[1] + betv[1]) * oscale;
    pool_write<MODE>(out, tokstride, bh, 0, l, act, y0, y1);
}

__global__ __launch_bounds__(512, 4)
void pool_ln_fused_kernel(const u16* __restrict__ qin, const u16* __restrict__ kin,
                          const u16* __restrict__ vin,
                          const float* __restrict__ cwq, const float* __restrict__ cwk,
                          const float* __restrict__ cwv,
                          const float* __restrict__ gq, const float* __restrict__ bq,
                          const float* __restrict__ gk, const float* __restrict__ bk,
                          const float* __restrict__ gv, const float* __restrict__ bv,
                          u16* __restrict__ qout, u16* __restrict__ kout,
                          u16* __restrict__ vtout)
{
    extern __shared__ u16 smem[];              // [3][8][14][96] bf16
    float* wsm2 = (float*)(smem + 3 * PSLAB_U16);   // [27][96] transposed weights

    const int tid = threadIdx.x;
    const int wv = tid >> 6, lane = tid & 63;
    const unsigned wg = xcd_swizzle(blockIdx.x, gridDim.x);
    const int tensor = (int)(wg >> 10);            // /1024
    const int rem = (int)(wg & 1023);
    const int bh = rem >> 4, to = (rem >> 1) & 7, half = rem & 1;
    const int h0 = half ? 6 : 0;

    const u16* in = tensor == 0 ? qin : (tensor == 1 ? kin : vin);
    const float* cw = tensor == 0 ? cwq : (tensor == 1 ? cwk : cwv);
    const size_t inbase = (size_t)bh * N_ * 96;

    // stage 3 planes x 8 h-rows x 14 tokens x 96ch: 4032 16B chunks
    #pragma unroll
    for (int it = 0; it < 8; ++it) {
        if (it == 7 && wv >= 7) break;             // wave-uniform tail guard
        const int chunk = it * 512 + tid;
        const int plane = chunk / 1344;            // 1344 chunks per plane
        const int remc  = chunk - plane * 1344;
        const int hrow  = remc / 168;              // 168 chunks per h-row
        const int rem2  = remc - hrow * 168;
        const int tokw  = (rem2 * 16) / 192;
        const int choff = ((rem2 * 16) - tokw * 192) >> 1;
        int t = to - 1 + plane; if (t < 0) t = 0; if (t > 7) t = 7;
        const int token = 1 + t * 196 + (h0 + hrow) * 14 + tokw;
        GLOAD_LDS16(in + inbase + (size_t)token * 96 + choff,
                    smem + (size_t)(it * 512 + wv * 64) * 8);
    }
    for (int i = tid; i < 96 * 27; i += 512) {
        const int tap = i / 96, ch = i - tap * 96;
        wsm2[i] = cw[ch * 27 + tap];
    }
    __syncthreads();

    const int l = lane < 48 ? lane : 47;

    if (tensor == 0) {
        const f32x2 gamv = *(const f32x2*)&gq[2 * l];
        const f32x2 betv = *(const f32x2*)&bq[2 * l];
        if (wv < 7)
            pool_row<1, 0, 0, 14>(smem, wsm2, gamv, betv, qout, QPAD,
                                  bh, to, half * 7 + wv, h0, SCALE_);
        else if (to == 0 && half == 0)
            pool_cls<0>(in, inbase, gamv, betv, qout, QPAD, bh, SCALE_);
    } else if (tensor == 1) {
        const f32x2 gamv = *(const f32x2*)&gk[2 * l];
        const f32x2 betv = *(const f32x2*)&bk[2 * l];
        const int ho = half * 4 + (wv >> 1);
        if (ho < 7) {
            if ((wv & 1) == 0)
                pool_row<2, 1, 0, 4>(smem, wsm2, gamv, betv, kout, KPAD, bh, to, ho, h0, 1.f);
            else
                pool_row<2, 1, 4, 3>(smem, wsm2, gamv, betv, kout, KPAD, bh, to, ho, h0, 1.f);
        } else if (to == 0 && half == 1 && wv == 7)
            pool_cls<1>(in, inbase, gamv, betv, kout, KPAD, bh, 1.f);
    } else {
        const f32x2 gamv = *(const f32x2*)&gv[2 * l];
        const f32x2 betv = *(const f32x2*)&bv[2 * l];
        const int ho = half * 4 + (wv >> 1);
        if (ho < 7) {
            if ((wv & 1) == 0)
                pool_row<2, 2, 0, 4>(smem, wsm2, gamv, betv, vtout, KPAD, bh, to, ho, h0, 1.f);
            else
                pool_row<2, 2, 4, 3>(smem, wsm2, gamv, betv, vtout, KPAD, bh, to, ho, h0, 1.f);
        } else if (to == 0 && half == 1 && wv == 7)
            pool_cls<2>(in, inbase, gamv, betv, vtout, KPAD, bh, 1.f);
    }
}

// ---------------------------------------------------------------------------
// MFMA attention v2 -> bf16 [M_][768]. 32 q-rows/wave (2 subtiles), K reg
// double-buffer prefetch, VT loads hoisted before softmax. Q pre-scaled.
// ---------------------------------------------------------------------------
__global__ __launch_bounds__(256)
void attn_mfma_kernel(const u16* __restrict__ Q, const u16* __restrict__ K,
                      const u16* __restrict__ VT, u16* __restrict__ Out)
{
    __shared__ alignas(16) u16 plds[4][2][512];   // per-wave, per-subtile P tile
    const int tid  = threadIdx.x;
    const int w    = tid >> 6, lane = tid & 63;
    const int c    = lane & 15, g = lane >> 4;

    const unsigned wg = xcd_swizzle(blockIdx.x, gridDim.x);
    const int bh = (int)(wg / 13);
    const int b  = bh >> 3, hh = bh & 7;
    const int q0 = (int)(wg % 13) * 128 + w * 32;

    const size_t qbase = (size_t)bh * QPAD * 96;
    const size_t kbase = (size_t)bh * KPAD * 96;

    short8v qa[2][3];
    #pragma unroll
    for (int s2 = 0; s2 < 2; ++s2)
        #pragma unroll
        for (int kf = 0; kf < 3; ++kf)
            qa[s2][kf] = *(const short8v*)
                &Q[qbase + (size_t)(q0 + s2 * 16 + c) * 96 + kf * 32 + g * 8];

    f32x4 oacc[2][6];
    #pragma unroll
    for (int s2 = 0; s2 < 2; ++s2)
        #pragma unroll
        for (int t = 0; t < 6; ++t) oacc[s2][t] = (f32x4){0.f, 0.f, 0.f, 0.f};
    float lsum[2][4] = {{0.f,0.f,0.f,0.f},{0.f,0.f,0.f,0.f}};

    short8v kb[2][6];
#define LOADK(IDX, PR) do {                                                     \
    _Pragma("unroll")                                                           \
    for (int h = 0; h < 2; ++h)                                                 \
        _Pragma("unroll")                                                       \
        for (int kf = 0; kf < 3; ++kf)                                          \
            kb[IDX][h * 3 + kf] = *(const short8v*)                             \
                &K[kbase + (size_t)((PR) * 32 + h * 16 + c) * 96 + kf * 32 + g * 8]; \
    } while (0)

    LOADK(0, 0);

    #pragma unroll
    for (int pr = 0; pr < 13; ++pr) {
        const int cur = pr & 1, nxt = cur ^ 1;

        short8v vt[6];
        #pragma unroll
        for (int t = 0; t < 6; ++t)
            vt[t] = *(const short8v*)
                &VT[kbase + (size_t)(t * 16 + c) * KPAD + pr * 32 + g * 8];

        f32x4 sacc[2][2];
        __builtin_amdgcn_s_setprio(1);
        #pragma unroll
        for (int s2 = 0; s2 < 2; ++s2)
            #pragma unroll
            for (int h = 0; h < 2; ++h) {
                f32x4 sa = (f32x4){0.f, 0.f, 0.f, 0.f};
                sa = __builtin_amdgcn_mfma_f32_16x16x32_bf16(qa[s2][0], kb[cur][h*3+0], sa, 0, 0, 0);
                sa = __builtin_amdgcn_mfma_f32_16x16x32_bf16(qa[s2][1], kb[cur][h*3+1], sa, 0, 0, 0);
                sa = __builtin_amdgcn_mfma_f32_16x16x32_bf16(qa[s2][2], kb[cur][h*3+2], sa, 0, 0, 0);
                sacc[s2][h] = sa;
            }
        __builtin_amdgcn_s_setprio(0);

        if (pr < 12) LOADK(nxt, pr + 1);

        #pragma unroll
        for (int s2 = 0; s2 < 2; ++s2)
            #pragma unroll
            for (int h = 0; h < 2; ++h) {
                const int jcol = pr * 32 + h * 16 + c;
                #pragma unroll
                for (int r = 0; r < 4; ++r) {
                    float s = sacc[s2][h][r];
                    if (jcol >= NKV_) s = -1e30f;
                    const float p = __expf(s);
                    lsum[s2][r] += p;
                    const int q    = g * 4 + r;
                    const int j    = h * 16 + c;
                    const int dstL = q | ((j >> 3) << 4);
                    plds[w][s2][dstL * 8 + (j & 7)] = f2bf(p);
                }
            }
        asm volatile("s_waitcnt lgkmcnt(0)" ::: "memory");
        __builtin_amdgcn_sched_barrier(0);
        const short8v pa0 = *(const short8v*)&plds[w][0][lane * 8];
        const short8v pa1 = *(const short8v*)&plds[w][1][lane * 8];

        __builtin_amdgcn_s_setprio(1);
        #pragma unroll
        for (int t = 0; t < 6; ++t)
            oacc[0][t] = __builtin_amdgcn_mfma_f32_16x16x32_bf16(pa0, vt[t], oacc[0][t], 0, 0, 0);
        #pragma unroll
        for (int t = 0; t < 6; ++t)
            oacc[1][t] = __builtin_amdgcn_mfma_f32_16x16x32_bf16(pa1, vt[t], oacc[1][t], 0, 0, 0);
        __builtin_amdgcn_s_setprio(0);
    }
#undef LOADK

    float linv[2][4];
    #pragma unroll
    for (int s2 = 0; s2 < 2; ++s2)
        #pragma unroll
        for (int r = 0; r < 4; ++r) {
            float s = lsum[s2][r];
            s += __shfl_xor(s, 1, 64);
            s += __shfl_xor(s, 2, 64);
            s += __shfl_xor(s, 4, 64);
            s += __shfl_xor(s, 8, 64);
            linv[s2][r] = 1.f / s;
        }

    #pragma unroll
    for (int s2 = 0; s2 < 2; ++s2)
        #pragma unroll
        for (int t = 0; t < 6; ++t)
            #pragma unroll
            for (int r = 0; r < 4; ++r) {
                const int row = q0 + s2 * 16 + g * 4 + r;
                if (row < N_)
                    Out[((size_t)(b * N_ + row)) * 768 + hh * 96 + t * 16 + c] =
                        f2bf(oacc[s2][t][r] * linv[s2][r]);
            }
}

// ---------------------------------------------------------------------------
extern "C" void kernel_launch(void* const* d_in, const int* in_sizes, int n_in,
                              void* d_out, int out_size, void* d_ws, size_t ws_size,
                              hipStream_t stream)
{
    const float* x     = (const float*)d_in[0];
    const float* Wqkv  = (const float*)d_in[1];
    const float* bqkv  = (const float*)d_in[2];
    const float* Wproj = (const float*)d_in[3];
    const float* bproj = (const float*)d_in[4];
    const float* cwq   = (const float*)d_in[5];
    const float* cwk   = (const float*)d_in[6];
    const float* cwv   = (const float*)d_in[7];
    const float* lnqg  = (const float*)d_in[8];
    const float* lnqb  = (const float*)d_in[9];
    const float* lnkg  = (const float*)d_in[10];
    const float* lnkb  = (const float*)d_in[11];
    const float* lnvg  = (const float*)d_in[12];
    const float* lnvb  = (const float*)d_in[13];

    u16* ws = (u16*)d_ws;
    u16* qkv_raw = ws;                       // 3 x [B][NH][N][D] bf16
    u16* q16 = qkv_raw + 3 * QKV1;           // [64][QPAD][96]
    u16* k16 = q16 + (size_t)64 * QPAD * 96; // [64][KPAD][96]
    u16* vt16 = k16 + (size_t)64 * KPAD * 96;// [64][96][KPAD] (transposed)
    u16* x16    = vt16 + (size_t)64 * KPAD * 96;  // [12552][768]
    u16* Wqkvt  = x16 + (size_t)M_ * 768;         // [2304][768]
    u16* Wprojt = Wqkvt + (size_t)2304 * 768;     // [768][768]
    u16* attn16 = qkv_raw;                   // alias: raw dead after pooling
    float* out = (float*)d_out;

    // 0) converts / transposes / VT pad zero
    cvt_f32_to_bf16<<<(M_ * 768 / 4 + 255) / 256, 256, 0, stream>>>(x, x16, M_ * 768 / 4);
    transpose_cvt<<<dim3(2304 / 32, 768 / 32), 256, 0, stream>>>(Wqkv, Wqkvt, 2304);
    transpose_cvt<<<dim3(768 / 32, 768 / 32), 256, 0, stream>>>(Wproj, Wprojt, 768);
    zero_pad_vt<<<(64 * 96 * (KPAD - NKV_) + 255) / 256, 256, 0, stream>>>(vt16);

    // 1) qkv GEMM (8-wave pipelined MFMA) with bf16 scatter into q/k/v
    gemm_bf16_kernel<2304, true><<<18 * 99, 512, 0, stream>>>(x16, Wqkvt, bqkv, qkv_raw);

    // 2) fused pool + LN v3: block per (tensor, bh, to, h-half), all waves busy
    pool_ln_fused_kernel<<<3072, 512, POOL2_LDS_B, stream>>>(
        qkv_raw, qkv_raw + QKV1, qkv_raw + 2 * QKV1,
        cwq, cwk, cwv, lnqg, lnqb, lnkg, lnkb, lnvg, lnvb,
        q16, k16, vt16);

    // 3) MFMA attention v2 -> bf16 [M_][768]
    attn_mfma_kernel<<<13 * 64, 256, 0, stream>>>(q16, k16, vt16, attn16);

    // 4) output projection (8-wave pipelined MFMA) -> fp32 d_out
    gemm_bf16_kernel<768, false><<<6 * 99, 512, 0, stream>>>(attn16, Wprojt, bproj, out);
}

// Round 13
// 223.784 us; speedup vs baseline: 1.2893x; 1.0430x over previous
//
#include <hip/hip_runtime.h>
#include <hip/hip_bf16.h>
#include <math.h>

#define B_   8
#define NH_  8
#define D_   96
#define C_   768
#define N_   1569          // 8*14*14 + 1
#define NKV_ 393           // 8*7*7 + 1
#define M_   (B_*N_)       // 12552
#define QKV1 ((size_t)B_*NH_*N_*D_)    // 9,639,936 elems per tensor
#define QPAD 1664          // padded q rows per slab (13 tiles of 128)
#define KPAD 416           // padded kv rows per slab (13 tiles of 32)
#define SCALE_ 0.10206207261596575f    // 96^-0.5

using short8v = __attribute__((ext_vector_type(8))) short;
using f32x4   = __attribute__((ext_vector_type(4))) float;
using f32x2   = __attribute__((ext_vector_type(2))) float;
typedef unsigned short u16;

#define GLOAD_LDS16(g, l) __builtin_amdgcn_global_load_lds( \
    (const __attribute__((address_space(1))) void*)(g),     \
    (__attribute__((address_space(3))) void*)(l), 16, 0, 0)

static __device__ __forceinline__ u16 f2bf(float f) {
    __hip_bfloat16 b = __float2bfloat16(f);
    return *(u16*)&b;
}
static __device__ __forceinline__ float bf2f(u16 v) {
    return __bfloat162float(*(const __hip_bfloat16*)&v);
}

// bijective XCD swizzle (m204): consecutive swizzled ids land on one XCD
static __device__ __forceinline__ unsigned xcd_swizzle(unsigned orig, unsigned nwg) {
    const unsigned qq = nwg >> 3, rr = nwg & 7;
    const unsigned xcd = orig & 7, loc = orig >> 3;
    return (xcd < rr ? xcd * (qq + 1) : rr * (qq + 1) + (xcd - rr) * qq) + loc;
}

// ---------------------------------------------------------------------------
// fp32 -> bf16 flat convert (n4 float4 chunks)
// ---------------------------------------------------------------------------
__global__ __launch_bounds__(256)
void cvt_f32_to_bf16(const float* __restrict__ in, u16* __restrict__ out, int n4)
{
    const int i = blockIdx.x * 256 + threadIdx.x;
    if (i < n4) {
        const float4 v = ((const float4*)in)[i];
        ushort4 o;
        o.x = f2bf(v.x); o.y = f2bf(v.y); o.z = f2bf(v.z); o.w = f2bf(v.w);
        ((ushort4*)out)[i] = o;
    }
}

// ---------------------------------------------------------------------------
// W [768][ncols] fp32  ->  Wt [ncols][768] bf16   (32x32 LDS tiles)
// ---------------------------------------------------------------------------
__global__ __launch_bounds__(256)
void transpose_cvt(const float* __restrict__ W, u16* __restrict__ Wt, int ncols)
{
    __shared__ float tile[32][33];
    const int tx = threadIdx.x & 31, ty = threadIdx.x >> 5;   // 32 x 8
    const int n0 = blockIdx.x * 32, k0 = blockIdx.y * 32;
    #pragma unroll
    for (int i = 0; i < 4; ++i)
        tile[ty + i * 8][tx] = W[(size_t)(k0 + ty + i * 8) * ncols + n0 + tx];
    __syncthreads();
    #pragma unroll
    for (int i = 0; i < 4; ++i)
        Wt[(size_t)(n0 + ty + i * 8) * 768 + k0 + tx] = f2bf(tile[tx][ty + i * 8]);
}

// ---------------------------------------------------------------------------
// zero V^T pad columns (j in [NKV_, KPAD)) — required finite for PV MFMA
// ---------------------------------------------------------------------------
__global__ __launch_bounds__(256)
void zero_pad_vt(u16* __restrict__ vt)
{
    const int i = blockIdx.x * 256 + threadIdx.x;
    const int total = 64 * 96 * (KPAD - NKV_);
    if (i < total) {
        const int j = i % (KPAD - NKV_);
        const int rest = i / (KPAD - NKV_);     // slab*96 + d
        vt[(size_t)rest * KPAD + NKV_ + j] = 0;
    }
}

// ---------------------------------------------------------------------------
// bf16 MFMA GEMM, counted-vmcnt pipeline (T3+T4) + LDS XOR swizzle (T2).
// 512 threads / 8 waves (2x4), 64x32 per wave. T5 setprio around MFMA.
// ---------------------------------------------------------------------------
template<int NC, bool SCATTER>
__global__ __launch_bounds__(512)
void gemm_bf16_kernel(const u16* __restrict__ A, const u16* __restrict__ Bt,
                      const float* __restrict__ bias, void* __restrict__ outp)
{
    constexpr int NXT = NC / 128;
    __shared__ alignas(16) u16 As[2][128 * 64];
    __shared__ alignas(16) u16 Bs[2][128 * 64];

    const int tid  = threadIdx.x;
    const int w    = tid >> 6, lane = tid & 63;
    const int c    = lane & 15, g = lane >> 4;
    const int wm   = w >> 2, wn = w & 3;      // 2 x 4 wave grid
    const int lrow = lane >> 3, lcol = lane & 7;

    const unsigned wg = xcd_swizzle(blockIdx.x, gridDim.x);
    const int m0 = (int)(wg / NXT) * 128;
    const int n0 = (int)(wg % NXT) * 128;

    f32x4 acc[4][2];
    #pragma unroll
    for (int i = 0; i < 4; ++i)
        #pragma unroll
        for (int j = 0; j < 2; ++j) acc[i][j] = (f32x4){0.f, 0.f, 0.f, 0.f};

#define STAGE(BUF, K0) do {                                                      \
    _Pragma("unroll")                                                            \
    for (int t = 0; t < 2; ++t) {                                                \
        const int r = t * 64 + w * 8;                                            \
        const int row = r + lrow;                                                \
        const int scol = (lcol ^ (row & 7)) * 8;                                 \
        int m = m0 + row; if (m >= M_) m = M_ - 1;                               \
        GLOAD_LDS16(&A[(size_t)m * 768 + (K0) + scol], &As[BUF][r * 64]);        \
        GLOAD_LDS16(&Bt[(size_t)(n0 + row) * 768 + (K0) + scol],                 \
                    &Bs[BUF][r * 64]);                                           \
    } } while (0)

    const int xora = (g ^ (c & 7)) * 8;          // kk=0: logical col16 = g
    const int xorb = ((4 + g) ^ (c & 7)) * 8;    // kk=1: logical col16 = 4+g

#define KSTEP(BUF, LAST, PREF, KNEXT) do {                                       \
    if (LAST) asm volatile("s_waitcnt vmcnt(0)" ::: "memory");                   \
    else      asm volatile("s_waitcnt vmcnt(4)" ::: "memory");                   \
    __builtin_amdgcn_s_barrier();                                                \
    short8v a0[4], a1[4], b0[2], b1[2];                                          \
    _Pragma("unroll")                                                            \
    for (int i = 0; i < 4; ++i) {                                                \
        const int ra = (wm * 64 + i * 16 + c) * 64;                              \
        a0[i] = *(const short8v*)&As[BUF][ra + xora];                            \
        a1[i] = *(const short8v*)&As[BUF][ra + xorb];                            \
    }                                                                            \
    _Pragma("unroll")                                                            \
    for (int j = 0; j < 2; ++j) {                                                \
        const int rb = (wn * 32 + j * 16 + c) * 64;                              \
        b0[j] = *(const short8v*)&Bs[BUF][rb + xora];                            \
        b1[j] = *(const short8v*)&Bs[BUF][rb + xorb];                            \
    }                                                                            \
    asm volatile("s_waitcnt lgkmcnt(0)" ::: "memory");                           \
    __builtin_amdgcn_sched_barrier(0);                                           \
    __builtin_amdgcn_s_barrier();                                                \
    if (PREF) STAGE(BUF, KNEXT);                                                 \
    __builtin_amdgcn_s_setprio(1);                                               \
    _Pragma("unroll")                                                            \
    for (int i = 0; i < 4; ++i)                                                  \
        _Pragma("unroll")                                                        \
        for (int j = 0; j < 2; ++j)                                              \
            acc[i][j] = __builtin_amdgcn_mfma_f32_16x16x32_bf16(                 \
                a0[i], b0[j], acc[i][j], 0, 0, 0);                               \
    _Pragma("unroll")                                                            \
    for (int i = 0; i < 4; ++i)                                                  \
        _Pragma("unroll")                                                        \
        for (int j = 0; j < 2; ++j)                                              \
            acc[i][j] = __builtin_amdgcn_mfma_f32_16x16x32_bf16(                 \
                a1[i], b1[j], acc[i][j], 0, 0, 0);                               \
    __builtin_amdgcn_s_setprio(0);                                               \
    } while (0)

    STAGE(0, 0);
    STAGE(1, 64);
    #pragma unroll
    for (int tt = 0; tt < 5; ++tt) {
        KSTEP(0, false, true, (2 * tt + 2) * 64);
        KSTEP(1, false, true, (2 * tt + 3) * 64);
    }
    KSTEP(0, false, false, 0);
    KSTEP(1, true,  false, 0);
#undef STAGE
#undef KSTEP

    #pragma unroll
    for (int i = 0; i < 4; ++i) {
        const int mrow = m0 + wm * 64 + i * 16 + g * 4;
        #pragma unroll
        for (int j = 0; j < 2; ++j) {
            const int ncol = n0 + wn * 32 + j * 16 + c;
            const float bv = bias[ncol];
            if constexpr (SCATTER) {
                u16* out = (u16*)outp;
                const int s   = ncol / C_;          // 0=q,1=k,2=v
                const int rem = ncol - s * C_;
                const int hh  = rem / D_;
                const int dd  = rem - hh * D_;
                #pragma unroll
                for (int r = 0; r < 4; ++r) {
                    const int m = mrow + r;
                    if (m < M_) {
                        const int bb2 = m / N_;
                        const int n = m - bb2 * N_;
                        out[(size_t)s * QKV1 +
                            ((size_t)(bb2 * NH_ + hh) * N_ + n) * D_ + dd] = f2bf(acc[i][j][r] + bv);
                    }
                }
            } else {
                float* out = (float*)outp;
                #pragma unroll
                for (int r = 0; r < 4; ++r) {
                    const int m = mrow + r;
                    if (m < M_) out[(size_t)m * NC + ncol] = acc[i][j][r] + bv;
                }
            }
        }
    }
}

// ---------------------------------------------------------------------------
// Fused pool+LN v4: block per (tensor, bh, to, h-half); tensor = wg % 3 so
// consecutive same-XCD blocks alternate q/k/v (work balance across XCDs).
// 512 threads, 2 blocks/CU. Packed f32x2 channel-pair math.
// MODE: 0=q ([tok][96], scaled), 1=k ([tok][96]), 2=v^T ([96][KPAD]).
// ---------------------------------------------------------------------------
#define PSLAB_U16 (8 * 14 * 96)            // u16 per plane slab (8 h-rows)
#define POOL2_LDS_B (3 * PSLAB_U16 * 2 + 96 * 27 * 4)   // 64512 + 10368

template<int MODE>
static __device__ __forceinline__
void pool_write(u16* __restrict__ out, int tokstride, int bh, int tok, int l,
                bool act, float y0, float y1)
{
    if (!act) return;
    if constexpr (MODE == 2) {
        out[((size_t)bh * 96 + 2 * l) * KPAD + tok] = f2bf(y0);
        out[((size_t)bh * 96 + 2 * l + 1) * KPAD + tok] = f2bf(y1);
    } else {
        const unsigned pk = (unsigned)f2bf(y0) | ((unsigned)f2bf(y1) << 16);
        *(unsigned*)&out[((size_t)bh * tokstride + tok) * 96 + 2 * l] = pk;
    }
}

template<int STRIDE, int MODE, int WO0, int WOCNT>
static __device__ __forceinline__
void pool_row(const u16* __restrict__ smem, const float* __restrict__ wsm2,
              f32x2 gamv, f32x2 betv, u16* __restrict__ out, int tokstride,
              int bh, int to, int ho, int h0, float oscale)
{
    constexpr int OHW = (MODE == 0) ? 14 : 7;
    constexpr int IWLO = (WO0 * STRIDE - 1) < 0 ? 0 : (WO0 * STRIDE - 1);
    constexpr int IWHI = ((WO0 + WOCNT - 1) * STRIDE + 1) > 13 ? 13
                       : ((WO0 + WOCNT - 1) * STRIDE + 1);
    const int lane = threadIdx.x & 63;
    const int l = lane < 48 ? lane : 47;
    const bool act = lane < 48;

    f32x2 a[WOCNT];
    #pragma unroll
    for (int i = 0; i < WOCNT; ++i) a[i] = (f32x2){0.f, 0.f};

    #pragma unroll
    for (int dt = 0; dt < 3; ++dt) {
        const int t = to - 1 + dt;
        if (t < 0 || t > 7) continue;
        #pragma unroll
        for (int dh = 0; dh < 3; ++dh) {
            const int h = ho * STRIDE - 1 + dh;
            if (h < h0 || h >= h0 + 8 || h >= 14) continue;   // wave-uniform
            const int hl = h - h0;
            f32x2 xv[14];
            #pragma unroll
            for (int iw = IWLO; iw <= IWHI; ++iw) {
                const unsigned u = *(const unsigned*)
                    &smem[(dt * 8 + hl) * 1344 + iw * 96 + 2 * l];
                xv[iw][0] = __uint_as_float(u << 16);
                xv[iw][1] = __uint_as_float(u & 0xffff0000u);
            }
            const int tapb = dt * 9 + dh * 3;
            f32x2 wt[3];
            #pragma unroll
            for (int dw = 0; dw < 3; ++dw)
                wt[dw] = *(const f32x2*)&wsm2[(tapb + dw) * 96 + 2 * l];
            #pragma unroll
            for (int i = 0; i < WOCNT; ++i)
                #pragma unroll
                for (int dw = 0; dw < 3; ++dw) {
                    const int iw = (WO0 + i) * STRIDE - 1 + dw;
                    if (iw < IWLO || iw > IWHI) continue;     // compile-time
                    a[i] = __builtin_elementwise_fma(wt[dw], xv[iw], a[i]);
                }
        }
    }

    #pragma unroll
    for (int i = 0; i < WOCNT; ++i) {
        const float va = act ? a[i][0] : 0.f, vb = act ? a[i][1] : 0.f;
        float s = va + vb;
        #pragma unroll
        for (int off = 32; off; off >>= 1) s += __shfl_xor(s, off, 64);
        float sq = va * va + vb * vb;
        #pragma unroll
        for (int off = 32; off; off >>= 1) sq += __shfl_xor(sq, off, 64);
        const float mu = s * (1.f / 96.f);
        const float rstd = rsqrtf(sq * (1.f / 96.f) - mu * mu + 1e-5f);
        const float y0 = ((va - mu) * rstd * gamv[0] + betv[0]) * oscale;
        const float y1 = ((vb - mu) * rstd * gamv[1] + betv[1]) * oscale;
        const int tok = 1 + (to * OHW + ho) * OHW + WO0 + i;
        pool_write<MODE>(out, tokstride, bh, tok, l, act, y0, y1);
    }
}

template<int MODE>
static __device__ __forceinline__
void pool_cls(const u16* __restrict__ in, size_t inbase, f32x2 gamv, f32x2 betv,
              u16* __restrict__ out, int tokstride, int bh, float oscale)
{
    const int lane = threadIdx.x & 63;
    const int l = lane < 48 ? lane : 47;
    const bool act = lane < 48;
    const unsigned u = *(const unsigned*)&in[inbase + 2 * l];
    const float va = act ? __uint_as_float(u << 16) : 0.f;
    const float vb = act ? __uint_as_float(u & 0xffff0000u) : 0.f;
    float s = va + vb;
    #pragma unroll
    for (int off = 32; off; off >>= 1) s += __shfl_xor(s, off, 64);
    float sq = va * va + vb * vb;
    #pragma unroll
    for (int off = 32; off; off >>= 1) sq += __shfl_xor(sq, off, 64);
    const float mu = s * (1.f / 96.f);
    const float rstd = rsqrtf(sq * (1.f / 96.f) - mu * mu + 1e-5f);
    const float y0 = ((va - mu) * rstd * gamv[0] + betv[0]) * oscale;
    const float y1 = ((vb - mu) * rstd * gamv[1] + betv[1]) * oscale;
    pool_write<MODE>(out, tokstride, bh, 0, l, act, y0, y1);
}

__global__ __launch_bounds__(512, 4)
void pool_ln_fused_kernel(const u16* __restrict__ qin, const u16* __restrict__ kin,
                          const u16* __restrict__ vin,
                          const float* __restrict__ cwq, const float* __restrict__ cwk,
                          const float* __restrict__ cwv,
                          const float* __restrict__ gq, const float* __restrict__ bq,
                          const float* __restrict__ gk, const float* __restrict__ bk,
                          const float* __restrict__ gv, const float* __restrict__ bv,
                          u16* __restrict__ qout, u16* __restrict__ kout,
                          u16* __restrict__ vtout)
{
    extern __shared__ u16 smem[];              // [3][8][14][96] bf16
    float* wsm2 = (float*)(smem + 3 * PSLAB_U16);   // [27][96] transposed weights

    const int tid = threadIdx.x;
    const int wv = tid >> 6, lane = tid & 63;
    const unsigned wg = xcd_swizzle(blockIdx.x, gridDim.x);
    const int tensor = (int)(wg % 3);              // interleave tensors per XCD
    const int rem = (int)(wg / 3);                 // 0..1023
    const int bh = rem >> 4, to = (rem >> 1) & 7, half = rem & 1;
    const int h0 = half ? 6 : 0;

    const u16* in = tensor == 0 ? qin : (tensor == 1 ? kin : vin);
    const float* cw = tensor == 0 ? cwq : (tensor == 1 ? cwk : cwv);
    const size_t inbase = (size_t)bh * N_ * 96;

    // stage 3 planes x 8 h-rows x 14 tokens x 96ch: 4032 16B chunks
    #pragma unroll
    for (int it = 0; it < 8; ++it) {
        if (it == 7 && wv >= 7) break;             // wave-uniform tail guard
        const int chunk = it * 512 + tid;
        const int plane = chunk / 1344;            // 1344 chunks per plane
        const int remc  = chunk - plane * 1344;
        const int hrow  = remc / 168;              // 168 chunks per h-row
        const int rem2  = remc - hrow * 168;
        const int tokw  = (rem2 * 16) / 192;
        const int choff = ((rem2 * 16) - tokw * 192) >> 1;
        int t = to - 1 + plane; if (t < 0) t = 0; if (t > 7) t = 7;
        const int token = 1 + t * 196 + (h0 + hrow) * 14 + tokw;
        GLOAD_LDS16(in + inbase + (size_t)token * 96 + choff,
                    smem + (size_t)(it * 512 + wv * 64) * 8);
    }
    for (int i = tid; i < 96 * 27; i += 512) {
        const int tap = i / 96, ch = i - tap * 96;
        wsm2[i] = cw[ch * 27 + tap];
    }
    __syncthreads();

    const int l = lane < 48 ? lane : 47;

    if (tensor == 0) {
        const f32x2 gamv = *(const f32x2*)&gq[2 * l];
        const f32x2 betv = *(const f32x2*)&bq[2 * l];
        if (wv < 7)
            pool_row<1, 0, 0, 14>(smem, wsm2, gamv, betv, qout, QPAD,
                                  bh, to, half * 7 + wv, h0, SCALE_);
        else if (to == 0 && half == 0)
            pool_cls<0>(in, inbase, gamv, betv, qout, QPAD, bh, SCALE_);
    } else if (tensor == 1) {
        const f32x2 gamv = *(const f32x2*)&gk[2 * l];
        const f32x2 betv = *(const f32x2*)&bk[2 * l];
        const int ho = half * 4 + (wv >> 1);
        if (ho < 7) {
            if ((wv & 1) == 0)
                pool_row<2, 1, 0, 4>(smem, wsm2, gamv, betv, kout, KPAD, bh, to, ho, h0, 1.f);
            else
                pool_row<2, 1, 4, 3>(smem, wsm2, gamv, betv, kout, KPAD, bh, to, ho, h0, 1.f);
        } else if (to == 0 && half == 1 && wv == 7)
            pool_cls<1>(in, inbase, gamv, betv, kout, KPAD, bh, 1.f);
    } else {
        const f32x2 gamv = *(const f32x2*)&gv[2 * l];
        const f32x2 betv = *(const f32x2*)&bv[2 * l];
        const int ho = half * 4 + (wv >> 1);
        if (ho < 7) {
            if ((wv & 1) == 0)
                pool_row<2, 2, 0, 4>(smem, wsm2, gamv, betv, vtout, KPAD, bh, to, ho, h0, 1.f);
            else
                pool_row<2, 2, 4, 3>(smem, wsm2, gamv, betv, vtout, KPAD, bh, to, ho, h0, 1.f);
        } else if (to == 0 && half == 1 && wv == 7)
            pool_cls<2>(in, inbase, gamv, betv, vtout, KPAD, bh, 1.f);
    }
}

// ---------------------------------------------------------------------------
// MFMA attention v2 -> bf16 [M_][768]. 32 q-rows/wave (2 subtiles), K reg
// double-buffer prefetch, VT loads hoisted before softmax. Q pre-scaled.
// ---------------------------------------------------------------------------
__global__ __launch_bounds__(256)
void attn_mfma_kernel(const u16* __restrict__ Q, const u16* __restrict__ K,
                      const u16* __restrict__ VT, u16* __restrict__ Out)
{
    __shared__ alignas(16) u16 plds[4][2][512];   // per-wave, per-subtile P tile
    const int tid  = threadIdx.x;
    const int w    = tid >> 6, lane = tid & 63;
    const int c    = lane & 15, g = lane >> 4;

    const unsigned wg = xcd_swizzle(blockIdx.x, gridDim.x);
    const int bh = (int)(wg / 13);
    const int b  = bh >> 3, hh = bh & 7;
    const int q0 = (int)(wg % 13) * 128 + w * 32;

    const size_t qbase = (size_t)bh * QPAD * 96;
    const size_t kbase = (size_t)bh * KPAD * 96;

    short8v qa[2][3];
    #pragma unroll
    for (int s2 = 0; s2 < 2; ++s2)
        #pragma unroll
        for (int kf = 0; kf < 3; ++kf)
            qa[s2][kf] = *(const short8v*)
                &Q[qbase + (size_t)(q0 + s2 * 16 + c) * 96 + kf * 32 + g * 8];

    f32x4 oacc[2][6];
    #pragma unroll
    for (int s2 = 0; s2 < 2; ++s2)
        #pragma unroll
        for (int t = 0; t < 6; ++t) oacc[s2][t] = (f32x4){0.f, 0.f, 0.f, 0.f};
    float lsum[2][4] = {{0.f,0.f,0.f,0.f},{0.f,0.f,0.f,0.f}};

    short8v kb[2][6];
#define LOADK(IDX, PR) do {                                                     \
    _Pragma("unroll")                                                           \
    for (int h = 0; h < 2; ++h)                                                 \
        _Pragma("unroll")                                                       \
        for (int kf = 0; kf < 3; ++kf)                                          \
            kb[IDX][h * 3 + kf] = *(const short8v*)                             \
                &K[kbase + (size_t)((PR) * 32 + h * 16 + c) * 96 + kf * 32 + g * 8]; \
    } while (0)

    LOADK(0, 0);

    #pragma unroll
    for (int pr = 0; pr < 13; ++pr) {
        const int cur = pr & 1, nxt = cur ^ 1;

        short8v vt[6];
        #pragma unroll
        for (int t = 0; t < 6; ++t)
            vt[t] = *(const short8v*)
                &VT[kbase + (size_t)(t * 16 + c) * KPAD + pr * 32 + g * 8];

        f32x4 sacc[2][2];
        __builtin_amdgcn_s_setprio(1);
        #pragma unroll
        for (int s2 = 0; s2 < 2; ++s2)
            #pragma unroll
            for (int h = 0; h < 2; ++h) {
                f32x4 sa = (f32x4){0.f, 0.f, 0.f, 0.f};
                sa = __builtin_amdgcn_mfma_f32_16x16x32_bf16(qa[s2][0], kb[cur][h*3+0], sa, 0, 0, 0);
                sa = __builtin_amdgcn_mfma_f32_16x16x32_bf16(qa[s2][1], kb[cur][h*3+1], sa, 0, 0, 0);
                sa = __builtin_amdgcn_mfma_f32_16x16x32_bf16(qa[s2][2], kb[cur][h*3+2], sa, 0, 0, 0);
                sacc[s2][h] = sa;
            }
        __builtin_amdgcn_s_setprio(0);

        if (pr < 12) LOADK(nxt, pr + 1);

        #pragma unroll
        for (int s2 = 0; s2 < 2; ++s2)
            #pragma unroll
            for (int h = 0; h < 2; ++h) {
                const int jcol = pr * 32 + h * 16 + c;
                #pragma unroll
                for (int r = 0; r < 4; ++r) {
                    float s = sacc[s2][h][r];
                    if (jcol >= NKV_) s = -1e30f;
                    const float p = __expf(s);
                    lsum[s2][r] += p;
                    const int q    = g * 4 + r;
                    const int j    = h * 16 + c;
                    const int dstL = q | ((j >> 3) << 4);
                    plds[w][s2][dstL * 8 + (j & 7)] = f2bf(p);
                }
            }
        asm volatile("s_waitcnt lgkmcnt(0)" ::: "memory");
        __builtin_amdgcn_sched_barrier(0);
        const short8v pa0 = *(const short8v*)&plds[w][0][lane * 8];
        const short8v pa1 = *(const short8v*)&plds[w][1][lane * 8];

        __builtin_amdgcn_s_setprio(1);
        #pragma unroll
        for (int t = 0; t < 6; ++t)
            oacc[0][t] = __builtin_amdgcn_mfma_f32_16x16x32_bf16(pa0, vt[t], oacc[0][t], 0, 0, 0);
        #pragma unroll
        for (int t = 0; t < 6; ++t)
            oacc[1][t] = __builtin_amdgcn_mfma_f32_16x16x32_bf16(pa1, vt[t], oacc[1][t], 0, 0, 0);
        __builtin_amdgcn_s_setprio(0);
    }
#undef LOADK

    float linv[2][4];
    #pragma unroll
    for (int s2 = 0; s2 < 2; ++s2)
        #pragma unroll
        for (int r = 0; r < 4; ++r) {
            float s = lsum[s2][r];
            s += __shfl_xor(s, 1, 64);
            s += __shfl_xor(s, 2, 64);
            s += __shfl_xor(s, 4, 64);
            s += __shfl_xor(s, 8, 64);
            linv[s2][r] = 1.f / s;
        }

    #pragma unroll
    for (int s2 = 0; s2 < 2; ++s2)
        #pragma unroll
        for (int t = 0; t < 6; ++t)
            #pragma unroll
            for (int r = 0; r < 4; ++r) {
                const int row = q0 + s2 * 16 + g * 4 + r;
                if (row < N_)
                    Out[((size_t)(b * N_ + row)) * 768 + hh * 96 + t * 16 + c] =
                        f2bf(oacc[s2][t][r] * linv[s2][r]);
            }
}

// ---------------------------------------------------------------------------
extern "C" void kernel_launch(void* const* d_in, const int* in_sizes, int n_in,
                              void* d_out, int out_size, void* d_ws, size_t ws_size,
                              hipStream_t stream)
{
    const float* x     = (const float*)d_in[0];
    const float* Wqkv  = (const float*)d_in[1];
    const float* bqkv  = (const float*)d_in[2];
    const float* Wproj = (const float*)d_in[3];
    const float* bproj = (const float*)d_in[4];
    const float* cwq   = (const float*)d_in[5];
    const float* cwk   = (const float*)d_in[6];
    const float* cwv   = (const float*)d_in[7];
    const float* lnqg  = (const float*)d_in[8];
    const float* lnqb  = (const float*)d_in[9];
    const float* lnkg  = (const float*)d_in[10];
    const float* lnkb  = (const float*)d_in[11];
    const float* lnvg  = (const float*)d_in[12];
    const float* lnvb  = (const float*)d_in[13];

    u16* ws = (u16*)d_ws;
    u16* qkv_raw = ws;                       // 3 x [B][NH][N][D] bf16
    u16* q16 = qkv_raw + 3 * QKV1;           // [64][QPAD][96]
    u16* k16 = q16 + (size_t)64 * QPAD * 96; // [64][KPAD][96]
    u16* vt16 = k16 + (size_t)64 * KPAD * 96;// [64][96][KPAD] (transposed)
    u16* x16    = vt16 + (size_t)64 * KPAD * 96;  // [12552][768]
    u16* Wqkvt  = x16 + (size_t)M_ * 768;         // [2304][768]
    u16* Wprojt = Wqkvt + (size_t)2304 * 768;     // [768][768]
    u16* attn16 = qkv_raw;                   // alias: raw dead after pooling
    float* out = (float*)d_out;

    // 0) converts / transposes / VT pad zero
    cvt_f32_to_bf16<<<(M_ * 768 / 4 + 255) / 256, 256, 0, stream>>>(x, x16, M_ * 768 / 4);
    transpose_cvt<<<dim3(2304 / 32, 768 / 32), 256, 0, stream>>>(Wqkv, Wqkvt, 2304);
    transpose_cvt<<<dim3(768 / 32, 768 / 32), 256, 0, stream>>>(Wproj, Wprojt, 768);
    zero_pad_vt<<<(64 * 96 * (KPAD - NKV_) + 255) / 256, 256, 0, stream>>>(vt16);

    // 1) qkv GEMM (8-wave pipelined MFMA) with bf16 scatter into q/k/v
    gemm_bf16_kernel<2304, true><<<18 * 99, 512, 0, stream>>>(x16, Wqkvt, bqkv, qkv_raw);

    // 2) fused pool + LN v4: tensor = wg % 3 (XCD work balance)
    pool_ln_fused_kernel<<<3072, 512, POOL2_LDS_B, stream>>>(
        qkv_raw, qkv_raw + QKV1, qkv_raw + 2 * QKV1,
        cwq, cwk, cwv, lnqg, lnqb, lnkg, lnkb, lnvg, lnvb,
        q16, k16, vt16);

    // 3) MFMA attention v2 -> bf16 [M_][768]
    attn_mfma_kernel<<<13 * 64, 256, 0, stream>>>(q16, k16, vt16, attn16);

    // 4) output projection (8-wave pipelined MFMA) -> fp32 d_out
    gemm_bf16_kernel<768, false><<<6 * 99, 512, 0, stream>>>(attn16, Wprojt, bproj, out);
}

// Round 14
// 206.253 us; speedup vs baseline: 1.3989x; 1.0850x over previous
//
#include <hip/hip_runtime.h>
#include <hip/hip_bf16.h>
#include <math.h>

#define B_   8
#define NH_  8
#define D_   96
#define C_   768
#define N_   1569          // 8*14*14 + 1
#define NKV_ 393           // 8*7*7 + 1
#define M_   (B_*N_)       // 12552
#define QKV1 ((size_t)B_*NH_*N_*D_)    // 9,639,936 elems per tensor
#define QPAD 1664          // padded q rows per slab (13 tiles of 128)
#define KPAD 416           // padded kv rows per slab (13 tiles of 32)
#define SCALE_ 0.10206207261596575f    // 96^-0.5

using short8v = __attribute__((ext_vector_type(8))) short;
using f32x4   = __attribute__((ext_vector_type(4))) float;
using f32x2   = __attribute__((ext_vector_type(2))) float;
typedef unsigned short u16;

#define GLOAD_LDS16(g, l) __builtin_amdgcn_global_load_lds( \
    (const __attribute__((address_space(1))) void*)(g),     \
    (__attribute__((address_space(3))) void*)(l), 16, 0, 0)

static __device__ __forceinline__ u16 f2bf(float f) {
    __hip_bfloat16 b = __float2bfloat16(f);
    return *(u16*)&b;
}

// bijective XCD swizzle (m204): consecutive swizzled ids land on one XCD
static __device__ __forceinline__ unsigned xcd_swizzle(unsigned orig, unsigned nwg) {
    const unsigned qq = nwg >> 3, rr = nwg & 7;
    const unsigned xcd = orig & 7, loc = orig >> 3;
    return (xcd < rr ? xcd * (qq + 1) : rr * (qq + 1) + (xcd - rr) * qq) + loc;
}

// ---------------------------------------------------------------------------
// fp32 -> bf16 flat convert (n4 float4 chunks)
// ---------------------------------------------------------------------------
__global__ __launch_bounds__(256)
void cvt_f32_to_bf16(const float* __restrict__ in, u16* __restrict__ out, int n4)
{
    const int i = blockIdx.x * 256 + threadIdx.x;
    if (i < n4) {
        const float4 v = ((const float4*)in)[i];
        ushort4 o;
        o.x = f2bf(v.x); o.y = f2bf(v.y); o.z = f2bf(v.z); o.w = f2bf(v.w);
        ((ushort4*)out)[i] = o;
    }
}

// ---------------------------------------------------------------------------
// W [768][ncols] fp32  ->  Wt [ncols][768] bf16   (32x32 LDS tiles)
// ---------------------------------------------------------------------------
__global__ __launch_bounds__(256)
void transpose_cvt(const float* __restrict__ W, u16* __restrict__ Wt, int ncols)
{
    __shared__ float tile[32][33];
    const int tx = threadIdx.x & 31, ty = threadIdx.x >> 5;   // 32 x 8
    const int n0 = blockIdx.x * 32, k0 = blockIdx.y * 32;
    #pragma unroll
    for (int i = 0; i < 4; ++i)
        tile[ty + i * 8][tx] = W[(size_t)(k0 + ty + i * 8) * ncols + n0 + tx];
    __syncthreads();
    #pragma unroll
    for (int i = 0; i < 4; ++i)
        Wt[(size_t)(n0 + ty + i * 8) * 768 + k0 + tx] = f2bf(tile[tx][ty + i * 8]);
}

// ---------------------------------------------------------------------------
// conv weights [96][27] fp32 -> [27][96] fp32, 3 tensors
// ---------------------------------------------------------------------------
__global__ __launch_bounds__(256)
void transpose_w(const float* __restrict__ cwq, const float* __restrict__ cwk,
                 const float* __restrict__ cwv, float* __restrict__ outT)
{
    const int i = blockIdx.x * 256 + threadIdx.x;
    if (i < 3 * 27 * 96) {
        const int tsr = i / 2592;
        const int r = i - tsr * 2592;
        const int tap = r / 96, ch = r - tap * 96;
        const float* src = tsr == 0 ? cwq : (tsr == 1 ? cwk : cwv);
        outT[i] = src[ch * 27 + tap];
    }
}

// ---------------------------------------------------------------------------
// zero V^T pad columns (j in [NKV_, KPAD)) — required finite for PV MFMA
// ---------------------------------------------------------------------------
__global__ __launch_bounds__(256)
void zero_pad_vt(u16* __restrict__ vt)
{
    const int i = blockIdx.x * 256 + threadIdx.x;
    const int total = 64 * 96 * (KPAD - NKV_);
    if (i < total) {
        const int j = i % (KPAD - NKV_);
        const int rest = i / (KPAD - NKV_);     // slab*96 + d
        vt[(size_t)rest * KPAD + NKV_ + j] = 0;
    }
}

// ---------------------------------------------------------------------------
// bf16 MFMA GEMM, counted-vmcnt pipeline (T3+T4) + LDS XOR swizzle (T2).
// 512 threads / 8 waves (2x4), 64x32 per wave. T5 setprio around MFMA.
// ---------------------------------------------------------------------------
template<int NC, bool SCATTER>
__global__ __launch_bounds__(512)
void gemm_bf16_kernel(const u16* __restrict__ A, const u16* __restrict__ Bt,
                      const float* __restrict__ bias, void* __restrict__ outp)
{
    constexpr int NXT = NC / 128;
    __shared__ alignas(16) u16 As[2][128 * 64];
    __shared__ alignas(16) u16 Bs[2][128 * 64];

    const int tid  = threadIdx.x;
    const int w    = tid >> 6, lane = tid & 63;
    const int c    = lane & 15, g = lane >> 4;
    const int wm   = w >> 2, wn = w & 3;      // 2 x 4 wave grid
    const int lrow = lane >> 3, lcol = lane & 7;

    const unsigned wg = xcd_swizzle(blockIdx.x, gridDim.x);
    const int m0 = (int)(wg / NXT) * 128;
    const int n0 = (int)(wg % NXT) * 128;

    f32x4 acc[4][2];
    #pragma unroll
    for (int i = 0; i < 4; ++i)
        #pragma unroll
        for (int j = 0; j < 2; ++j) acc[i][j] = (f32x4){0.f, 0.f, 0.f, 0.f};

#define STAGE(BUF, K0) do {                                                      \
    _Pragma("unroll")                                                            \
    for (int t = 0; t < 2; ++t) {                                                \
        const int r = t * 64 + w * 8;                                            \
        const int row = r + lrow;                                                \
        const int scol = (lcol ^ (row & 7)) * 8;                                 \
        int m = m0 + row; if (m >= M_) m = M_ - 1;                               \
        GLOAD_LDS16(&A[(size_t)m * 768 + (K0) + scol], &As[BUF][r * 64]);        \
        GLOAD_LDS16(&Bt[(size_t)(n0 + row) * 768 + (K0) + scol],                 \
                    &Bs[BUF][r * 64]);                                           \
    } } while (0)

    const int xora = (g ^ (c & 7)) * 8;          // kk=0: logical col16 = g
    const int xorb = ((4 + g) ^ (c & 7)) * 8;    // kk=1: logical col16 = 4+g

#define KSTEP(BUF, LAST, PREF, KNEXT) do {                                       \
    if (LAST) asm volatile("s_waitcnt vmcnt(0)" ::: "memory");                   \
    else      asm volatile("s_waitcnt vmcnt(4)" ::: "memory");                   \
    __builtin_amdgcn_s_barrier();                                                \
    short8v a0[4], a1[4], b0[2], b1[2];                                          \
    _Pragma("unroll")                                                            \
    for (int i = 0; i < 4; ++i) {                                                \
        const int ra = (wm * 64 + i * 16 + c) * 64;                              \
        a0[i] = *(const short8v*)&As[BUF][ra + xora];                            \
        a1[i] = *(const short8v*)&As[BUF][ra + xorb];                            \
    }                                                                            \
    _Pragma("unroll")                                                            \
    for (int j = 0; j < 2; ++j) {                                                \
        const int rb = (wn * 32 + j * 16 + c) * 64;                              \
        b0[j] = *(const short8v*)&Bs[BUF][rb + xora];                            \
        b1[j] = *(const short8v*)&Bs[BUF][rb + xorb];                            \
    }                                                                            \
    asm volatile("s_waitcnt lgkmcnt(0)" ::: "memory");                           \
    __builtin_amdgcn_sched_barrier(0);                                           \
    __builtin_amdgcn_s_barrier();                                                \
    if (PREF) STAGE(BUF, KNEXT);                                                 \
    __builtin_amdgcn_s_setprio(1);                                               \
    _Pragma("unroll")                                                            \
    for (int i = 0; i < 4; ++i)                                                  \
        _Pragma("unroll")                                                        \
        for (int j = 0; j < 2; ++j)                                              \
            acc[i][j] = __builtin_amdgcn_mfma_f32_16x16x32_bf16(                 \
                a0[i], b0[j], acc[i][j], 0, 0, 0);                               \
    _Pragma("unroll")                                                            \
    for (int i = 0; i < 4; ++i)                                                  \
        _Pragma("unroll")                                                        \
        for (int j = 0; j < 2; ++j)                                              \
            acc[i][j] = __builtin_amdgcn_mfma_f32_16x16x32_bf16(                 \
                a1[i], b1[j], acc[i][j], 0, 0, 0);                               \
    __builtin_amdgcn_s_setprio(0);                                               \
    } while (0)

    STAGE(0, 0);
    STAGE(1, 64);
    #pragma unroll
    for (int tt = 0; tt < 5; ++tt) {
        KSTEP(0, false, true, (2 * tt + 2) * 64);
        KSTEP(1, false, true, (2 * tt + 3) * 64);
    }
    KSTEP(0, false, false, 0);
    KSTEP(1, true,  false, 0);
#undef STAGE
#undef KSTEP

    #pragma unroll
    for (int i = 0; i < 4; ++i) {
        const int mrow = m0 + wm * 64 + i * 16 + g * 4;
        #pragma unroll
        for (int j = 0; j < 2; ++j) {
            const int ncol = n0 + wn * 32 + j * 16 + c;
            const float bv = bias[ncol];
            if constexpr (SCATTER) {
                u16* out = (u16*)outp;
                const int s   = ncol / C_;          // 0=q,1=k,2=v
                const int rem = ncol - s * C_;
                const int hh  = rem / D_;
                const int dd  = rem - hh * D_;
                #pragma unroll
                for (int r = 0; r < 4; ++r) {
                    const int m = mrow + r;
                    if (m < M_) {
                        const int bb2 = m / N_;
                        const int n = m - bb2 * N_;
                        out[(size_t)s * QKV1 +
                            ((size_t)(bb2 * NH_ + hh) * N_ + n) * D_ + dd] = f2bf(acc[i][j][r] + bv);
                    }
                }
            } else {
                float* out = (float*)outp;
                #pragma unroll
                for (int r = 0; r < 4; ++r) {
                    const int m = mrow + r;
                    if (m < M_) out[(size_t)m * NC + ncol] = acc[i][j][r] + bv;
                }
            }
        }
    }
}

// ---------------------------------------------------------------------------
// Pool+LN v5: 16-lane groups, 6 channels/lane, no LDS, direct global reads.
// One group = 7 output tokens of one (bh,to,ho[,chunk]). 4-level shfl LN.
// WMODE 0: out[bh][tok][96]; WMODE 2: v^T out[bh][96][KPAD].
// ---------------------------------------------------------------------------
static __device__ __forceinline__ void loadx6(const u16* __restrict__ rowp,
                                              int iw, f32x2 x[3])
{
    if (iw < 0 || iw >= 14) {      // compile-time after unroll
        x[0] = x[1] = x[2] = (f32x2){0.f, 0.f};
        return;
    }
    const unsigned* p = (const unsigned*)(rowp + (size_t)iw * 96);
    #pragma unroll
    for (int j = 0; j < 3; ++j) {
        const unsigned u = p[j];
        x[j][0] = __uint_as_float(u << 16);
        x[j][1] = __uint_as_float(u & 0xffff0000u);
    }
}

template<int STRIDE, int OHW, int WMODE, int WO0>
static __device__ __forceinline__
void pool_task(const u16* __restrict__ in, const float* __restrict__ cwT,
               const float* __restrict__ g, const float* __restrict__ bta,
               u16* __restrict__ out, int tokstride, int bh, int to, int ho,
               float oscale)
{
    const int sl = threadIdx.x & 15;
    const u16* base = in + (size_t)bh * N_ * 96 + 6 * sl;

    f32x2 acc[7][3];
    #pragma unroll
    for (int i = 0; i < 7; ++i)
        #pragma unroll
        for (int p = 0; p < 3; ++p) acc[i][p] = (f32x2){0.f, 0.f};

    #pragma unroll
    for (int dt = 0; dt < 3; ++dt) {
        const int t = to - 1 + dt;
        if (t < 0 || t > 7) continue;
        #pragma unroll
        for (int dh = 0; dh < 3; ++dh) {
            const int h = ho * STRIDE - 1 + dh;
            if (h < 0 || h >= 14) continue;
            const int tapb = dt * 9 + dh * 3;
            f32x2 wt[3][3];
            #pragma unroll
            for (int dw = 0; dw < 3; ++dw)
                #pragma unroll
                for (int p = 0; p < 3; ++p)
                    wt[dw][p] = *(const f32x2*)&cwT[(tapb + dw) * 96 + 6 * sl + 2 * p];
            const u16* rowp = base + (size_t)(1 + t * 196 + h * 14) * 96;

            if constexpr (STRIDE == 1) {
                f32x2 xm[3], x0[3], xp[3];
                loadx6(rowp, WO0 - 1, xm);
                loadx6(rowp, WO0, x0);
                #pragma unroll
                for (int wo = 0; wo < 7; ++wo) {
                    loadx6(rowp, WO0 + wo + 1, xp);
                    #pragma unroll
                    for (int p = 0; p < 3; ++p) {
                        acc[wo][p] = __builtin_elementwise_fma(wt[0][p], xm[p], acc[wo][p]);
                        acc[wo][p] = __builtin_elementwise_fma(wt[1][p], x0[p], acc[wo][p]);
                        acc[wo][p] = __builtin_elementwise_fma(wt[2][p], xp[p], acc[wo][p]);
                        xm[p] = x0[p]; x0[p] = xp[p];
                    }
                }
            } else {
                #pragma unroll
                for (int wo = 0; wo < 7; ++wo) {
                    #pragma unroll
                    for (int dw = 0; dw < 3; ++dw) {
                        f32x2 xa[3];
                        loadx6(rowp, 2 * wo - 1 + dw, xa);
                        #pragma unroll
                        for (int p = 0; p < 3; ++p)
                            acc[wo][p] = __builtin_elementwise_fma(wt[dw][p], xa[p], acc[wo][p]);
                    }
                }
            }
        }
    }

    f32x2 gg[3], bb[3];
    #pragma unroll
    for (int p = 0; p < 3; ++p) {
        gg[p] = *(const f32x2*)&g[6 * sl + 2 * p] * oscale;
        bb[p] = *(const f32x2*)&bta[6 * sl + 2 * p] * oscale;
    }

    #pragma unroll
    for (int wo = 0; wo < 7; ++wo) {
        float s = acc[wo][0][0] + acc[wo][0][1] + acc[wo][1][0] + acc[wo][1][1]
                + acc[wo][2][0] + acc[wo][2][1];
        float sq = acc[wo][0][0] * acc[wo][0][0];
        sq = fmaf(acc[wo][0][1], acc[wo][0][1], sq);
        sq = fmaf(acc[wo][1][0], acc[wo][1][0], sq);
        sq = fmaf(acc[wo][1][1], acc[wo][1][1], sq);
        sq = fmaf(acc[wo][2][0], acc[wo][2][0], sq);
        sq = fmaf(acc[wo][2][1], acc[wo][2][1], sq);
        #pragma unroll
        for (int off = 1; off < 16; off <<= 1) {
            s  += __shfl_xor(s, off, 64);
            sq += __shfl_xor(sq, off, 64);
        }
        const float mu = s * (1.f / 96.f);
        const float rstd = rsqrtf(sq * (1.f / 96.f) - mu * mu + 1e-5f);
        const f32x2 muv = (f32x2){mu, mu};
        const int tok = 1 + (to * OHW + ho) * OHW + WO0 + wo;
        u16 yb[6];
        #pragma unroll
        for (int p = 0; p < 3; ++p) {
            const f32x2 y = (acc[wo][p] - muv) * rstd * gg[p] + bb[p];
            yb[2 * p] = f2bf(y[0]); yb[2 * p + 1] = f2bf(y[1]);
        }
        if constexpr (WMODE == 2) {
            #pragma unroll
            for (int j = 0; j < 6; ++j)
                out[((size_t)bh * 96 + 6 * sl + j) * KPAD + tok] = yb[j];
        } else {
            unsigned* op = (unsigned*)&out[((size_t)bh * tokstride + tok) * 96 + 6 * sl];
            #pragma unroll
            for (int p = 0; p < 3; ++p)
                op[p] = (unsigned)yb[2 * p] | ((unsigned)yb[2 * p + 1] << 16);
        }
    }
}

template<int WMODE>
static __device__ __forceinline__
void pool_cls_v5(const u16* __restrict__ in, const float* __restrict__ g,
                 const float* __restrict__ bta, u16* __restrict__ out,
                 int tokstride, int bh, float oscale)
{
    const int sl = threadIdx.x & 15;
    const unsigned* p = (const unsigned*)(in + (size_t)bh * N_ * 96 + 6 * sl);
    f32x2 v[3];
    #pragma unroll
    for (int j = 0; j < 3; ++j) {
        const unsigned u = p[j];
        v[j][0] = __uint_as_float(u << 16);
        v[j][1] = __uint_as_float(u & 0xffff0000u);
    }
    float s = v[0][0] + v[0][1] + v[1][0] + v[1][1] + v[2][0] + v[2][1];
    float sq = v[0][0]*v[0][0] + v[0][1]*v[0][1] + v[1][0]*v[1][0]
             + v[1][1]*v[1][1] + v[2][0]*v[2][0] + v[2][1]*v[2][1];
    #pragma unroll
    for (int off = 1; off < 16; off <<= 1) {
        s  += __shfl_xor(s, off, 64);
        sq += __shfl_xor(sq, off, 64);
    }
    const float mu = s * (1.f / 96.f);
    const float rstd = rsqrtf(sq * (1.f / 96.f) - mu * mu + 1e-5f);
    u16 yb[6];
    #pragma unroll
    for (int p2 = 0; p2 < 3; ++p2) {
        const f32x2 gg = *(const f32x2*)&g[6 * sl + 2 * p2] * oscale;
        const f32x2 bb = *(const f32x2*)&bta[6 * sl + 2 * p2] * oscale;
        const f32x2 y = (v[p2] - (f32x2){mu, mu}) * rstd * gg + bb;
        yb[2 * p2] = f2bf(y[0]); yb[2 * p2 + 1] = f2bf(y[1]);
    }
    if constexpr (WMODE == 2) {
        #pragma unroll
        for (int j = 0; j < 6; ++j)
            out[((size_t)bh * 96 + 6 * sl + j) * KPAD] = yb[j];
    } else {
        unsigned* op = (unsigned*)&out[(size_t)bh * tokstride * 96 + 6 * sl];
        #pragma unroll
        for (int p2 = 0; p2 < 3; ++p2)
            op[p2] = (unsigned)yb[2 * p2] | ((unsigned)yb[2 * p2 + 1] << 16);
    }
}

// task ids: q chunk0 [0,7168), q chunk1 [7168,14336), k [14336,17920),
// v [17920,21504), cls [21504,21696)
#define NTASKS 21696
__global__ __launch_bounds__(256)
void pool_ln_v5_kernel(const u16* __restrict__ qin, const u16* __restrict__ kin,
                       const u16* __restrict__ vin, const float* __restrict__ cwT,
                       const float* __restrict__ gq, const float* __restrict__ bq,
                       const float* __restrict__ gk, const float* __restrict__ bk,
                       const float* __restrict__ gv, const float* __restrict__ bv,
                       u16* __restrict__ qout, u16* __restrict__ kout,
                       u16* __restrict__ vtout)
{
    const unsigned wg = xcd_swizzle(blockIdx.x, gridDim.x);
    const int gid = (int)(wg * 16 + (threadIdx.x >> 4));
    if (gid >= NTASKS) return;

    if (gid < 14336) {                       // q
        const int chunk = gid / 7168;
        const int r = gid - chunk * 7168;
        const int ho = r % 14;
        const int to = (r / 14) & 7;
        const int bh = r / 112;
        if (chunk == 0)
            pool_task<1, 14, 0, 0>(qin, cwT, gq, bq, qout, QPAD, bh, to, ho, SCALE_);
        else
            pool_task<1, 14, 0, 7>(qin, cwT, gq, bq, qout, QPAD, bh, to, ho, SCALE_);
    } else if (gid < 17920) {                // k
        const int r = gid - 14336;
        const int ho = r % 7;
        const int to = (r / 7) & 7;
        const int bh = r / 56;
        pool_task<2, 7, 0, 0>(kin, cwT + 2592, gk, bk, kout, KPAD, bh, to, ho, 1.f);
    } else if (gid < 21504) {                // v (transposed out)
        const int r = gid - 17920;
        const int ho = r % 7;
        const int to = (r / 7) & 7;
        const int bh = r / 56;
        pool_task<2, 7, 2, 0>(vin, cwT + 5184, gv, bv, vtout, KPAD, bh, to, ho, 1.f);
    } else {                                 // cls
        const int r = gid - 21504;
        const int tsr = r >> 6, bh = r & 63;
        if (tsr == 0)      pool_cls_v5<0>(qin, gq, bq, qout, QPAD, bh, SCALE_);
        else if (tsr == 1) pool_cls_v5<0>(kin, gk, bk, kout, KPAD, bh, 1.f);
        else               pool_cls_v5<2>(vin, gv, bv, vtout, KPAD, bh, 1.f);
    }
}

// ---------------------------------------------------------------------------
// MFMA attention v2 -> bf16 [M_][768]. 32 q-rows/wave (2 subtiles), K reg
// double-buffer prefetch, VT loads hoisted before softmax. Q pre-scaled.
// ---------------------------------------------------------------------------
__global__ __launch_bounds__(256)
void attn_mfma_kernel(const u16* __restrict__ Q, const u16* __restrict__ K,
                      const u16* __restrict__ VT, u16* __restrict__ Out)
{
    __shared__ alignas(16) u16 plds[4][2][512];   // per-wave, per-subtile P tile
    const int tid  = threadIdx.x;
    const int w    = tid >> 6, lane = tid & 63;
    const int c    = lane & 15, g = lane >> 4;

    const unsigned wg = xcd_swizzle(blockIdx.x, gridDim.x);
    const int bh = (int)(wg / 13);
    const int b  = bh >> 3, hh = bh & 7;
    const int q0 = (int)(wg % 13) * 128 + w * 32;

    const size_t qbase = (size_t)bh * QPAD * 96;
    const size_t kbase = (size_t)bh * KPAD * 96;

    short8v qa[2][3];
    #pragma unroll
    for (int s2 = 0; s2 < 2; ++s2)
        #pragma unroll
        for (int kf = 0; kf < 3; ++kf)
            qa[s2][kf] = *(const short8v*)
                &Q[qbase + (size_t)(q0 + s2 * 16 + c) * 96 + kf * 32 + g * 8];

    f32x4 oacc[2][6];
    #pragma unroll
    for (int s2 = 0; s2 < 2; ++s2)
        #pragma unroll
        for (int t = 0; t < 6; ++t) oacc[s2][t] = (f32x4){0.f, 0.f, 0.f, 0.f};
    float lsum[2][4] = {{0.f,0.f,0.f,0.f},{0.f,0.f,0.f,0.f}};

    short8v kb[2][6];
#define LOADK(IDX, PR) do {                                                     \
    _Pragma("unroll")                                                           \
    for (int h = 0; h < 2; ++h)                                                 \
        _Pragma("unroll")                                                       \
        for (int kf = 0; kf < 3; ++kf)                                          \
            kb[IDX][h * 3 + kf] = *(const short8v*)                             \
                &K[kbase + (size_t)((PR) * 32 + h * 16 + c) * 96 + kf * 32 + g * 8]; \
    } while (0)

    LOADK(0, 0);

    #pragma unroll
    for (int pr = 0; pr < 13; ++pr) {
        const int cur = pr & 1, nxt = cur ^ 1;

        short8v vt[6];
        #pragma unroll
        for (int t = 0; t < 6; ++t)
            vt[t] = *(const short8v*)
                &VT[kbase + (size_t)(t * 16 + c) * KPAD + pr * 32 + g * 8];

        f32x4 sacc[2][2];
        __builtin_amdgcn_s_setprio(1);
        #pragma unroll
        for (int s2 = 0; s2 < 2; ++s2)
            #pragma unroll
            for (int h = 0; h < 2; ++h) {
                f32x4 sa = (f32x4){0.f, 0.f, 0.f, 0.f};
                sa = __builtin_amdgcn_mfma_f32_16x16x32_bf16(qa[s2][0], kb[cur][h*3+0], sa, 0, 0, 0);
                sa = __builtin_amdgcn_mfma_f32_16x16x32_bf16(qa[s2][1], kb[cur][h*3+1], sa, 0, 0, 0);
                sa = __builtin_amdgcn_mfma_f32_16x16x32_bf16(qa[s2][2], kb[cur][h*3+2], sa, 0, 0, 0);
                sacc[s2][h] = sa;
            }
        __builtin_amdgcn_s_setprio(0);

        if (pr < 12) LOADK(nxt, pr + 1);

        #pragma unroll
        for (int s2 = 0; s2 < 2; ++s2)
            #pragma unroll
            for (int h = 0; h < 2; ++h) {
                const int jcol = pr * 32 + h * 16 + c;
                #pragma unroll
                for (int r = 0; r < 4; ++r) {
                    float s = sacc[s2][h][r];
                    if (jcol >= NKV_) s = -1e30f;
                    const float p = __expf(s);
                    lsum[s2][r] += p;
                    const int q    = g * 4 + r;
                    const int j    = h * 16 + c;
                    const int dstL = q | ((j >> 3) << 4);
                    plds[w][s2][dstL * 8 + (j & 7)] = f2bf(p);
                }
            }
        asm volatile("s_waitcnt lgkmcnt(0)" ::: "memory");
        __builtin_amdgcn_sched_barrier(0);
        const short8v pa0 = *(const short8v*)&plds[w][0][lane * 8];
        const short8v pa1 = *(const short8v*)&plds[w][1][lane * 8];

        __builtin_amdgcn_s_setprio(1);
        #pragma unroll
        for (int t = 0; t < 6; ++t)
            oacc[0][t] = __builtin_amdgcn_mfma_f32_16x16x32_bf16(pa0, vt[t], oacc[0][t], 0, 0, 0);
        #pragma unroll
        for (int t = 0; t < 6; ++t)
            oacc[1][t] = __builtin_amdgcn_mfma_f32_16x16x32_bf16(pa1, vt[t], oacc[1][t], 0, 0, 0);
        __builtin_amdgcn_s_setprio(0);
    }
#undef LOADK

    float linv[2][4];
    #pragma unroll
    for (int s2 = 0; s2 < 2; ++s2)
        #pragma unroll
        for (int r = 0; r < 4; ++r) {
            float s = lsum[s2][r];
            s += __shfl_xor(s, 1, 64);
            s += __shfl_xor(s, 2, 64);
            s += __shfl_xor(s, 4, 64);
            s += __shfl_xor(s, 8, 64);
            linv[s2][r] = 1.f / s;
        }

    #pragma unroll
    for (int s2 = 0; s2 < 2; ++s2)
        #pragma unroll
        for (int t = 0; t < 6; ++t)
            #pragma unroll
            for (int r = 0; r < 4; ++r) {
                const int row = q0 + s2 * 16 + g * 4 + r;
                if (row < N_)
                    Out[((size_t)(b * N_ + row)) * 768 + hh * 96 + t * 16 + c] =
                        f2bf(oacc[s2][t][r] * linv[s2][r]);
            }
}

// ---------------------------------------------------------------------------
extern "C" void kernel_launch(void* const* d_in, const int* in_sizes, int n_in,
                              void* d_out, int out_size, void* d_ws, size_t ws_size,
                              hipStream_t stream)
{
    const float* x     = (const float*)d_in[0];
    const float* Wqkv  = (const float*)d_in[1];
    const float* bqkv  = (const float*)d_in[2];
    const float* Wproj = (const float*)d_in[3];
    const float* bproj = (const float*)d_in[4];
    const float* cwq   = (const float*)d_in[5];
    const float* cwk   = (const float*)d_in[6];
    const float* cwv   = (const float*)d_in[7];
    const float* lnqg  = (const float*)d_in[8];
    const float* lnqb  = (const float*)d_in[9];
    const float* lnkg  = (const float*)d_in[10];
    const float* lnkb  = (const float*)d_in[11];
    const float* lnvg  = (const float*)d_in[12];
    const float* lnvb  = (const float*)d_in[13];

    u16* ws = (u16*)d_ws;
    u16* qkv_raw = ws;                       // 3 x [B][NH][N][D] bf16
    u16* q16 = qkv_raw + 3 * QKV1;           // [64][QPAD][96]
    u16* k16 = q16 + (size_t)64 * QPAD * 96; // [64][KPAD][96]
    u16* vt16 = k16 + (size_t)64 * KPAD * 96;// [64][96][KPAD] (transposed)
    u16* x16    = vt16 + (size_t)64 * KPAD * 96;  // [12552][768]
    u16* Wqkvt  = x16 + (size_t)M_ * 768;         // [2304][768]
    u16* Wprojt = Wqkvt + (size_t)2304 * 768;     // [768][768]
    float* cwT  = (float*)(Wprojt + (size_t)768 * 768);  // 3 x [27][96] f32
    u16* attn16 = qkv_raw;                   // alias: raw dead after pooling
    float* out = (float*)d_out;

    // 0) converts / transposes / VT pad zero
    cvt_f32_to_bf16<<<(M_ * 768 / 4 + 255) / 256, 256, 0, stream>>>(x, x16, M_ * 768 / 4);
    transpose_cvt<<<dim3(2304 / 32, 768 / 32), 256, 0, stream>>>(Wqkv, Wqkvt, 2304);
    transpose_cvt<<<dim3(768 / 32, 768 / 32), 256, 0, stream>>>(Wproj, Wprojt, 768);
    transpose_w<<<(3 * 27 * 96 + 255) / 256, 256, 0, stream>>>(cwq, cwk, cwv, cwT);
    zero_pad_vt<<<(64 * 96 * (KPAD - NKV_) + 255) / 256, 256, 0, stream>>>(vt16);

    // 1) qkv GEMM (8-wave pipelined MFMA) with bf16 scatter into q/k/v
    gemm_bf16_kernel<2304, true><<<18 * 99, 512, 0, stream>>>(x16, Wqkvt, bqkv, qkv_raw);

    // 2) pool + LN v5: 16-lane groups, no LDS, task-per-group
    pool_ln_v5_kernel<<<(NTASKS + 15) / 16, 256, 0, stream>>>(
        qkv_raw, qkv_raw + QKV1, qkv_raw + 2 * QKV1, cwT,
        lnqg, lnqb, lnkg, lnkb, lnvg, lnvb, q16, k16, vt16);

    // 3) MFMA attention v2 -> bf16 [M_][768]
    attn_mfma_kernel<<<13 * 64, 256, 0, stream>>>(q16, k16, vt16, attn16);

    // 4) output projection (8-wave pipelined MFMA) -> fp32 d_out
    gemm_bf16_kernel<768, false><<<6 * 99, 512, 0, stream>>>(attn16, Wprojt, bproj, out);
}

// Round 15
// 199.201 us; speedup vs baseline: 1.4484x; 1.0354x over previous
//
#include <hip/hip_runtime.h>
#include <hip/hip_bf16.h>
#include <math.h>

#define B_   8
#define NH_  8
#define D_   96
#define C_   768
#define N_   1569          // 8*14*14 + 1
#define NKV_ 393           // 8*7*7 + 1
#define M_   (B_*N_)       // 12552
#define QKV1 ((size_t)B_*NH_*N_*D_)    // 9,639,936 elems per tensor
#define QPAD 1664          // padded q rows per slab (13 tiles of 128)
#define KPAD 416           // padded kv rows per slab (13 tiles of 32)
#define SCALE_ 0.10206207261596575f    // 96^-0.5

using short8v = __attribute__((ext_vector_type(8))) short;
using f32x4   = __attribute__((ext_vector_type(4))) float;
using f32x2   = __attribute__((ext_vector_type(2))) float;
typedef unsigned short u16;

#define GLOAD_LDS16(g, l) __builtin_amdgcn_global_load_lds( \
    (const __attribute__((address_space(1))) void*)(g),     \
    (__attribute__((address_space(3))) void*)(l), 16, 0, 0)

static __device__ __forceinline__ u16 f2bf(float f) {
    __hip_bfloat16 b = __float2bfloat16(f);
    return *(u16*)&b;
}

// bijective XCD swizzle (m204): consecutive swizzled ids land on one XCD
static __device__ __forceinline__ unsigned xcd_swizzle(unsigned orig, unsigned nwg) {
    const unsigned qq = nwg >> 3, rr = nwg & 7;
    const unsigned xcd = orig & 7, loc = orig >> 3;
    return (xcd < rr ? xcd * (qq + 1) : rr * (qq + 1) + (xcd - rr) * qq) + loc;
}

// ---------------------------------------------------------------------------
// Merged prep kernel: block-range dispatch over 5 jobs.
//  [0, 9414): x fp32->bf16 (one float4/thread)
//  [9414, 11142): Wqkv transpose+cvt (32x32 tiles, 72 x 24)
//  [11142, 11718): Wproj transpose+cvt (24 x 24)
//  [11718, 11749): conv weights [96][27] -> [27][96] x3
//  [11749, 12301): zero V^T pad columns
// ---------------------------------------------------------------------------
#define PREP_CVT_B   9414
#define PREP_WQ_B    1728
#define PREP_WP_B    576
#define PREP_WT_B    31
#define PREP_ZP_B    552
#define PREP_BLOCKS  (PREP_CVT_B + PREP_WQ_B + PREP_WP_B + PREP_WT_B + PREP_ZP_B)

static __device__ __forceinline__
void tile_transpose(const float* __restrict__ W, u16* __restrict__ Wt,
                    int ncols, int n0, int k0, float* tile /*[32][33]*/)
{
    const int tx = threadIdx.x & 31, ty = threadIdx.x >> 5;   // 32 x 8
    #pragma unroll
    for (int i = 0; i < 4; ++i)
        tile[(ty + i * 8) * 33 + tx] = W[(size_t)(k0 + ty + i * 8) * ncols + n0 + tx];
    __syncthreads();
    #pragma unroll
    for (int i = 0; i < 4; ++i)
        Wt[(size_t)(n0 + ty + i * 8) * 768 + k0 + tx] = f2bf(tile[tx * 33 + ty + i * 8]);
}

__global__ __launch_bounds__(256)
void prep_kernel(const float* __restrict__ x, const float* __restrict__ Wqkv,
                 const float* __restrict__ Wproj,
                 const float* __restrict__ cwq, const float* __restrict__ cwk,
                 const float* __restrict__ cwv,
                 u16* __restrict__ x16, u16* __restrict__ Wqkvt,
                 u16* __restrict__ Wprojt, float* __restrict__ cwT,
                 u16* __restrict__ vt16)
{
    __shared__ float tile[32 * 33];
    const int bid = blockIdx.x;
    const int tid = threadIdx.x;

    if (bid < PREP_CVT_B) {
        const int i = bid * 256 + tid;
        const int n4 = M_ * 768 / 4;
        if (i < n4) {
            const float4 v = ((const float4*)x)[i];
            ushort4 o;
            o.x = f2bf(v.x); o.y = f2bf(v.y); o.z = f2bf(v.z); o.w = f2bf(v.w);
            ((ushort4*)x16)[i] = o;
        }
    } else if (bid < PREP_CVT_B + PREP_WQ_B) {
        const int b2 = bid - PREP_CVT_B;
        tile_transpose(Wqkv, Wqkvt, 2304, (b2 % 72) * 32, (b2 / 72) * 32, tile);
    } else if (bid < PREP_CVT_B + PREP_WQ_B + PREP_WP_B) {
        const int b2 = bid - PREP_CVT_B - PREP_WQ_B;
        tile_transpose(Wproj, Wprojt, 768, (b2 % 24) * 32, (b2 / 24) * 32, tile);
    } else if (bid < PREP_CVT_B + PREP_WQ_B + PREP_WP_B + PREP_WT_B) {
        const int i = (bid - PREP_CVT_B - PREP_WQ_B - PREP_WP_B) * 256 + tid;
        if (i < 3 * 27 * 96) {
            const int tsr = i / 2592;
            const int r = i - tsr * 2592;
            const int tap = r / 96, ch = r - tap * 96;
            const float* src = tsr == 0 ? cwq : (tsr == 1 ? cwk : cwv);
            cwT[i] = src[ch * 27 + tap];
        }
    } else {
        const int i = (bid - PREP_CVT_B - PREP_WQ_B - PREP_WP_B - PREP_WT_B) * 256 + tid;
        const int total = 64 * 96 * (KPAD - NKV_);
        if (i < total) {
            const int j = i % (KPAD - NKV_);
            const int rest = i / (KPAD - NKV_);     // slab*96 + d
            vt16[(size_t)rest * KPAD + NKV_ + j] = 0;
        }
    }
}

// ---------------------------------------------------------------------------
// bf16 MFMA GEMM, counted-vmcnt pipeline (T3+T4) + LDS XOR swizzle (T2).
// 512 threads / 8 waves (2x4), 64x32 per wave. T5 setprio around MFMA.
// ---------------------------------------------------------------------------
template<int NC, bool SCATTER>
__global__ __launch_bounds__(512)
void gemm_bf16_kernel(const u16* __restrict__ A, const u16* __restrict__ Bt,
                      const float* __restrict__ bias, void* __restrict__ outp)
{
    constexpr int NXT = NC / 128;
    __shared__ alignas(16) u16 As[2][128 * 64];
    __shared__ alignas(16) u16 Bs[2][128 * 64];

    const int tid  = threadIdx.x;
    const int w    = tid >> 6, lane = tid & 63;
    const int c    = lane & 15, g = lane >> 4;
    const int wm   = w >> 2, wn = w & 3;      // 2 x 4 wave grid
    const int lrow = lane >> 3, lcol = lane & 7;

    const unsigned wg = xcd_swizzle(blockIdx.x, gridDim.x);
    const int m0 = (int)(wg / NXT) * 128;
    const int n0 = (int)(wg % NXT) * 128;

    f32x4 acc[4][2];
    #pragma unroll
    for (int i = 0; i < 4; ++i)
        #pragma unroll
        for (int j = 0; j < 2; ++j) acc[i][j] = (f32x4){0.f, 0.f, 0.f, 0.f};

#define STAGE(BUF, K0) do {                                                      \
    _Pragma("unroll")                                                            \
    for (int t = 0; t < 2; ++t) {                                                \
        const int r = t * 64 + w * 8;                                            \
        const int row = r + lrow;                                                \
        const int scol = (lcol ^ (row & 7)) * 8;                                 \
        int m = m0 + row; if (m >= M_) m = M_ - 1;                               \
        GLOAD_LDS16(&A[(size_t)m * 768 + (K0) + scol], &As[BUF][r * 64]);        \
        GLOAD_LDS16(&Bt[(size_t)(n0 + row) * 768 + (K0) + scol],                 \
                    &Bs[BUF][r * 64]);                                           \
    } } while (0)

    const int xora = (g ^ (c & 7)) * 8;          // kk=0: logical col16 = g
    const int xorb = ((4 + g) ^ (c & 7)) * 8;    // kk=1: logical col16 = 4+g

#define KSTEP(BUF, LAST, PREF, KNEXT) do {                                       \
    if (LAST) asm volatile("s_waitcnt vmcnt(0)" ::: "memory");                   \
    else      asm volatile("s_waitcnt vmcnt(4)" ::: "memory");                   \
    __builtin_amdgcn_s_barrier();                                                \
    short8v a0[4], a1[4], b0[2], b1[2];                                          \
    _Pragma("unroll")                                                            \
    for (int i = 0; i < 4; ++i) {                                                \
        const int ra = (wm * 64 + i * 16 + c) * 64;                              \
        a0[i] = *(const short8v*)&As[BUF][ra + xora];                            \
        a1[i] = *(const short8v*)&As[BUF][ra + xorb];                            \
    }                                                                            \
    _Pragma("unroll")                                                            \
    for (int j = 0; j < 2; ++j) {                                                \
        const int rb = (wn * 32 + j * 16 + c) * 64;                              \
        b0[j] = *(const short8v*)&Bs[BUF][rb + xora];                            \
        b1[j] = *(const short8v*)&Bs[BUF][rb + xorb];                            \
    }                                                                            \
    asm volatile("s_waitcnt lgkmcnt(0)" ::: "memory");                           \
    __builtin_amdgcn_sched_barrier(0);                                           \
    __builtin_amdgcn_s_barrier();                                                \
    if (PREF) STAGE(BUF, KNEXT);                                                 \
    __builtin_amdgcn_s_setprio(1);                                               \
    _Pragma("unroll")                                                            \
    for (int i = 0; i < 4; ++i)                                                  \
        _Pragma("unroll")                                                        \
        for (int j = 0; j < 2; ++j)                                              \
            acc[i][j] = __builtin_amdgcn_mfma_f32_16x16x32_bf16(                 \
                a0[i], b0[j], acc[i][j], 0, 0, 0);                               \
    _Pragma("unroll")                                                            \
    for (int i = 0; i < 4; ++i)                                                  \
        _Pragma("unroll")                                                        \
        for (int j = 0; j < 2; ++j)                                              \
            acc[i][j] = __builtin_amdgcn_mfma_f32_16x16x32_bf16(                 \
                a1[i], b1[j], acc[i][j], 0, 0, 0);                               \
    __builtin_amdgcn_s_setprio(0);                                               \
    } while (0)

    STAGE(0, 0);
    STAGE(1, 64);
    #pragma unroll
    for (int tt = 0; tt < 5; ++tt) {
        KSTEP(0, false, true, (2 * tt + 2) * 64);
        KSTEP(1, false, true, (2 * tt + 3) * 64);
    }
    KSTEP(0, false, false, 0);
    KSTEP(1, true,  false, 0);
#undef STAGE
#undef KSTEP

    #pragma unroll
    for (int i = 0; i < 4; ++i) {
        const int mrow = m0 + wm * 64 + i * 16 + g * 4;
        #pragma unroll
        for (int j = 0; j < 2; ++j) {
            const int ncol = n0 + wn * 32 + j * 16 + c;
            const float bv = bias[ncol];
            if constexpr (SCATTER) {
                u16* out = (u16*)outp;
                const int s   = ncol / C_;          // 0=q,1=k,2=v
                const int rem = ncol - s * C_;
                const int hh  = rem / D_;
                const int dd  = rem - hh * D_;
                #pragma unroll
                for (int r = 0; r < 4; ++r) {
                    const int m = mrow + r;
                    if (m < M_) {
                        const int bb2 = m / N_;
                        const int n = m - bb2 * N_;
                        out[(size_t)s * QKV1 +
                            ((size_t)(bb2 * NH_ + hh) * N_ + n) * D_ + dd] = f2bf(acc[i][j][r] + bv);
                    }
                }
            } else {
                float* out = (float*)outp;
                #pragma unroll
                for (int r = 0; r < 4; ++r) {
                    const int m = mrow + r;
                    if (m < M_) out[(size_t)m * NC + ncol] = acc[i][j][r] + bv;
                }
            }
        }
    }
}

// ---------------------------------------------------------------------------
// Pool+LN v5: 16-lane groups, 6 channels/lane, no LDS, direct global reads.
// ---------------------------------------------------------------------------
static __device__ __forceinline__ void loadx6(const u16* __restrict__ rowp,
                                              int iw, f32x2 x[3])
{
    if (iw < 0 || iw >= 14) {      // compile-time after unroll
        x[0] = x[1] = x[2] = (f32x2){0.f, 0.f};
        return;
    }
    const unsigned* p = (const unsigned*)(rowp + (size_t)iw * 96);
    #pragma unroll
    for (int j = 0; j < 3; ++j) {
        const unsigned u = p[j];
        x[j][0] = __uint_as_float(u << 16);
        x[j][1] = __uint_as_float(u & 0xffff0000u);
    }
}

template<int STRIDE, int OHW, int WMODE, int WO0>
static __device__ __forceinline__
void pool_task(const u16* __restrict__ in, const float* __restrict__ cwT,
               const float* __restrict__ g, const float* __restrict__ bta,
               u16* __restrict__ out, int tokstride, int bh, int to, int ho,
               float oscale)
{
    const int sl = threadIdx.x & 15;
    const u16* base = in + (size_t)bh * N_ * 96 + 6 * sl;

    f32x2 acc[7][3];
    #pragma unroll
    for (int i = 0; i < 7; ++i)
        #pragma unroll
        for (int p = 0; p < 3; ++p) acc[i][p] = (f32x2){0.f, 0.f};

    #pragma unroll
    for (int dt = 0; dt < 3; ++dt) {
        const int t = to - 1 + dt;
        if (t < 0 || t > 7) continue;
        #pragma unroll
        for (int dh = 0; dh < 3; ++dh) {
            const int h = ho * STRIDE - 1 + dh;
            if (h < 0 || h >= 14) continue;
            const int tapb = dt * 9 + dh * 3;
            f32x2 wt[3][3];
            #pragma unroll
            for (int dw = 0; dw < 3; ++dw)
                #pragma unroll
                for (int p = 0; p < 3; ++p)
                    wt[dw][p] = *(const f32x2*)&cwT[(tapb + dw) * 96 + 6 * sl + 2 * p];
            const u16* rowp = base + (size_t)(1 + t * 196 + h * 14) * 96;

            if constexpr (STRIDE == 1) {
                f32x2 xm[3], x0[3], xp[3];
                loadx6(rowp, WO0 - 1, xm);
                loadx6(rowp, WO0, x0);
                #pragma unroll
                for (int wo = 0; wo < 7; ++wo) {
                    loadx6(rowp, WO0 + wo + 1, xp);
                    #pragma unroll
                    for (int p = 0; p < 3; ++p) {
                        acc[wo][p] = __builtin_elementwise_fma(wt[0][p], xm[p], acc[wo][p]);
                        acc[wo][p] = __builtin_elementwise_fma(wt[1][p], x0[p], acc[wo][p]);
                        acc[wo][p] = __builtin_elementwise_fma(wt[2][p], xp[p], acc[wo][p]);
                        xm[p] = x0[p]; x0[p] = xp[p];
                    }
                }
            } else {
                #pragma unroll
                for (int wo = 0; wo < 7; ++wo) {
                    #pragma unroll
                    for (int dw = 0; dw < 3; ++dw) {
                        f32x2 xa[3];
                        loadx6(rowp, 2 * wo - 1 + dw, xa);
                        #pragma unroll
                        for (int p = 0; p < 3; ++p)
                            acc[wo][p] = __builtin_elementwise_fma(wt[dw][p], xa[p], acc[wo][p]);
                    }
                }
            }
        }
    }

    f32x2 gg[3], bb[3];
    #pragma unroll
    for (int p = 0; p < 3; ++p) {
        gg[p] = *(const f32x2*)&g[6 * sl + 2 * p] * oscale;
        bb[p] = *(const f32x2*)&bta[6 * sl + 2 * p] * oscale;
    }

    #pragma unroll
    for (int wo = 0; wo < 7; ++wo) {
        float s = acc[wo][0][0] + acc[wo][0][1] + acc[wo][1][0] + acc[wo][1][1]
                + acc[wo][2][0] + acc[wo][2][1];
        float sq = acc[wo][0][0] * acc[wo][0][0];
        sq = fmaf(acc[wo][0][1], acc[wo][0][1], sq);
        sq = fmaf(acc[wo][1][0], acc[wo][1][0], sq);
        sq = fmaf(acc[wo][1][1], acc[wo][1][1], sq);
        sq = fmaf(acc[wo][2][0], acc[wo][2][0], sq);
        sq = fmaf(acc[wo][2][1], acc[wo][2][1], sq);
        #pragma unroll
        for (int off = 1; off < 16; off <<= 1) {
            s  += __shfl_xor(s, off, 64);
            sq += __shfl_xor(sq, off, 64);
        }
        const float mu = s * (1.f / 96.f);
        const float rstd = rsqrtf(sq * (1.f / 96.f) - mu * mu + 1e-5f);
        const f32x2 muv = (f32x2){mu, mu};
        const int tok = 1 + (to * OHW + ho) * OHW + WO0 + wo;
        u16 yb[6];
        #pragma unroll
        for (int p = 0; p < 3; ++p) {
            const f32x2 y = (acc[wo][p] - muv) * rstd * gg[p] + bb[p];
            yb[2 * p] = f2bf(y[0]); yb[2 * p + 1] = f2bf(y[1]);
        }
        if constexpr (WMODE == 2) {
            #pragma unroll
            for (int j = 0; j < 6; ++j)
                out[((size_t)bh * 96 + 6 * sl + j) * KPAD + tok] = yb[j];
        } else {
            unsigned* op = (unsigned*)&out[((size_t)bh * tokstride + tok) * 96 + 6 * sl];
            #pragma unroll
            for (int p = 0; p < 3; ++p)
                op[p] = (unsigned)yb[2 * p] | ((unsigned)yb[2 * p + 1] << 16);
        }
    }
}

template<int WMODE>
static __device__ __forceinline__
void pool_cls_v5(const u16* __restrict__ in, const float* __restrict__ g,
                 const float* __restrict__ bta, u16* __restrict__ out,
                 int tokstride, int bh, float oscale)
{
    const int sl = threadIdx.x & 15;
    const unsigned* p = (const unsigned*)(in + (size_t)bh * N_ * 96 + 6 * sl);
    f32x2 v[3];
    #pragma unroll
    for (int j = 0; j < 3; ++j) {
        const unsigned u = p[j];
        v[j][0] = __uint_as_float(u << 16);
        v[j][1] = __uint_as_float(u & 0xffff0000u);
    }
    float s = v[0][0] + v[0][1] + v[1][0] + v[1][1] + v[2][0] + v[2][1];
    float sq = v[0][0]*v[0][0] + v[0][1]*v[0][1] + v[1][0]*v[1][0]
             + v[1][1]*v[1][1] + v[2][0]*v[2][0] + v[2][1]*v[2][1];
    #pragma unroll
    for (int off = 1; off < 16; off <<= 1) {
        s  += __shfl_xor(s, off, 64);
        sq += __shfl_xor(sq, off, 64);
    }
    const float mu = s * (1.f / 96.f);
    const float rstd = rsqrtf(sq * (1.f / 96.f) - mu * mu + 1e-5f);
    u16 yb[6];
    #pragma unroll
    for (int p2 = 0; p2 < 3; ++p2) {
        const f32x2 gg = *(const f32x2*)&g[6 * sl + 2 * p2] * oscale;
        const f32x2 bb = *(const f32x2*)&bta[6 * sl + 2 * p2] * oscale;
        const f32x2 y = (v[p2] - (f32x2){mu, mu}) * rstd * gg + bb;
        yb[2 * p2] = f2bf(y[0]); yb[2 * p2 + 1] = f2bf(y[1]);
    }
    if constexpr (WMODE == 2) {
        #pragma unroll
        for (int j = 0; j < 6; ++j)
            out[((size_t)bh * 96 + 6 * sl + j) * KPAD] = yb[j];
    } else {
        unsigned* op = (unsigned*)&out[(size_t)bh * tokstride * 96 + 6 * sl];
        #pragma unroll
        for (int p2 = 0; p2 < 3; ++p2)
            op[p2] = (unsigned)yb[2 * p2] | ((unsigned)yb[2 * p2 + 1] << 16);
    }
}

// task ids: q chunk0 [0,7168), q chunk1 [7168,14336), k [14336,17920),
// v [17920,21504), cls [21504,21696)
#define NTASKS 21696
__global__ __launch_bounds__(256)
void pool_ln_v5_kernel(const u16* __restrict__ qin, const u16* __restrict__ kin,
                       const u16* __restrict__ vin, const float* __restrict__ cwT,
                       const float* __restrict__ gq, const float* __restrict__ bq,
                       const float* __restrict__ gk, const float* __restrict__ bk,
                       const float* __restrict__ gv, const float* __restrict__ bv,
                       u16* __restrict__ qout, u16* __restrict__ kout,
                       u16* __restrict__ vtout)
{
    const unsigned wg = xcd_swizzle(blockIdx.x, gridDim.x);
    const int gid = (int)(wg * 16 + (threadIdx.x >> 4));
    if (gid >= NTASKS) return;

    if (gid < 14336) {                       // q
        const int chunk = gid / 7168;
        const int r = gid - chunk * 7168;
        const int ho = r % 14;
        const int to = (r / 14) & 7;
        const int bh = r / 112;
        if (chunk == 0)
            pool_task<1, 14, 0, 0>(qin, cwT, gq, bq, qout, QPAD, bh, to, ho, SCALE_);
        else
            pool_task<1, 14, 0, 7>(qin, cwT, gq, bq, qout, QPAD, bh, to, ho, SCALE_);
    } else if (gid < 17920) {                // k
        const int r = gid - 14336;
        const int ho = r % 7;
        const int to = (r / 7) & 7;
        const int bh = r / 56;
        pool_task<2, 7, 0, 0>(kin, cwT + 2592, gk, bk, kout, KPAD, bh, to, ho, 1.f);
    } else if (gid < 21504) {                // v (transposed out)
        const int r = gid - 17920;
        const int ho = r % 7;
        const int to = (r / 7) & 7;
        const int bh = r / 56;
        pool_task<2, 7, 2, 0>(vin, cwT + 5184, gv, bv, vtout, KPAD, bh, to, ho, 1.f);
    } else {                                 // cls
        const int r = gid - 21504;
        const int tsr = r >> 6, bh = r & 63;
        if (tsr == 0)      pool_cls_v5<0>(qin, gq, bq, qout, QPAD, bh, SCALE_);
        else if (tsr == 1) pool_cls_v5<0>(kin, gk, bk, kout, KPAD, bh, 1.f);
        else               pool_cls_v5<2>(vin, gv, bv, vtout, KPAD, bh, 1.f);
    }
}

// ---------------------------------------------------------------------------
// MFMA attention v3 -> bf16 [M_][768]. 32 q-rows/wave, K reg double-buffer,
// VT hoisted; per-subtile exp/PV interleave (PV0 MFMA overlaps exp1 VALU).
// ---------------------------------------------------------------------------
__global__ __launch_bounds__(256)
void attn_mfma_kernel(const u16* __restrict__ Q, const u16* __restrict__ K,
                      const u16* __restrict__ VT, u16* __restrict__ Out)
{
    __shared__ alignas(16) u16 plds[4][2][512];   // per-wave, per-subtile P tile
    const int tid  = threadIdx.x;
    const int w    = tid >> 6, lane = tid & 63;
    const int c    = lane & 15, g = lane >> 4;

    const unsigned wg = xcd_swizzle(blockIdx.x, gridDim.x);
    const int bh = (int)(wg / 13);
    const int b  = bh >> 3, hh = bh & 7;
    const int q0 = (int)(wg % 13) * 128 + w * 32;

    const size_t qbase = (size_t)bh * QPAD * 96;
    const size_t kbase = (size_t)bh * KPAD * 96;

    short8v qa[2][3];
    #pragma unroll
    for (int s2 = 0; s2 < 2; ++s2)
        #pragma unroll
        for (int kf = 0; kf < 3; ++kf)
            qa[s2][kf] = *(const short8v*)
                &Q[qbase + (size_t)(q0 + s2 * 16 + c) * 96 + kf * 32 + g * 8];

    f32x4 oacc[2][6];
    #pragma unroll
    for (int s2 = 0; s2 < 2; ++s2)
        #pragma unroll
        for (int t = 0; t < 6; ++t) oacc[s2][t] = (f32x4){0.f, 0.f, 0.f, 0.f};
    float lsum[2][4] = {{0.f,0.f,0.f,0.f},{0.f,0.f,0.f,0.f}};

    short8v kb[2][6];
#define LOADK(IDX, PR) do {                                                     \
    _Pragma("unroll")                                                           \
    for (int h = 0; h < 2; ++h)                                                 \
        _Pragma("unroll")                                                       \
        for (int kf = 0; kf < 3; ++kf)                                          \
            kb[IDX][h * 3 + kf] = *(const short8v*)                             \
                &K[kbase + (size_t)((PR) * 32 + h * 16 + c) * 96 + kf * 32 + g * 8]; \
    } while (0)

    LOADK(0, 0);

    #pragma unroll
    for (int pr = 0; pr < 13; ++pr) {
        const int cur = pr & 1, nxt = cur ^ 1;

        short8v vt[6];
        #pragma unroll
        for (int t = 0; t < 6; ++t)
            vt[t] = *(const short8v*)
                &VT[kbase + (size_t)(t * 16 + c) * KPAD + pr * 32 + g * 8];

        f32x4 sacc[2][2];
        __builtin_amdgcn_s_setprio(1);
        #pragma unroll
        for (int s2 = 0; s2 < 2; ++s2)
            #pragma unroll
            for (int h = 0; h < 2; ++h) {
                f32x4 sa = (f32x4){0.f, 0.f, 0.f, 0.f};
                sa = __builtin_amdgcn_mfma_f32_16x16x32_bf16(qa[s2][0], kb[cur][h*3+0], sa, 0, 0, 0);
                sa = __builtin_amdgcn_mfma_f32_16x16x32_bf16(qa[s2][1], kb[cur][h*3+1], sa, 0, 0, 0);
                sa = __builtin_amdgcn_mfma_f32_16x16x32_bf16(qa[s2][2], kb[cur][h*3+2], sa, 0, 0, 0);
                sacc[s2][h] = sa;
            }
        __builtin_amdgcn_s_setprio(0);

        if (pr < 12) LOADK(nxt, pr + 1);

        // subtile 0: exp -> LDS -> PV0 (its MFMA overlaps subtile 1's exp VALU)
        #pragma unroll
        for (int h = 0; h < 2; ++h) {
            const int jcol = pr * 32 + h * 16 + c;
            #pragma unroll
            for (int r = 0; r < 4; ++r) {
                float s = sacc[0][h][r];
                if (jcol >= NKV_) s = -1e30f;
                const float p = __expf(s);
                lsum[0][r] += p;
                const int q    = g * 4 + r;
                const int j    = h * 16 + c;
                const int dstL = q | ((j >> 3) << 4);
                plds[w][0][dstL * 8 + (j & 7)] = f2bf(p);
            }
        }
        asm volatile("s_waitcnt lgkmcnt(0)" ::: "memory");
        __builtin_amdgcn_sched_barrier(0);
        {
            const short8v pa0 = *(const short8v*)&plds[w][0][lane * 8];
            __builtin_amdgcn_s_setprio(1);
            #pragma unroll
            for (int t = 0; t < 6; ++t)
                oacc[0][t] = __builtin_amdgcn_mfma_f32_16x16x32_bf16(pa0, vt[t], oacc[0][t], 0, 0, 0);
            __builtin_amdgcn_s_setprio(0);
        }

        // subtile 1
        #pragma unroll
        for (int h = 0; h < 2; ++h) {
            const int jcol = pr * 32 + h * 16 + c;
            #pragma unroll
            for (int r = 0; r < 4; ++r) {
                float s = sacc[1][h][r];
                if (jcol >= NKV_) s = -1e30f;
                const float p = __expf(s);
                lsum[1][r] += p;
                const int q    = g * 4 + r;
                const int j    = h * 16 + c;
                const int dstL = q | ((j >> 3) << 4);
                plds[w][1][dstL * 8 + (j & 7)] = f2bf(p);
            }
        }
        asm volatile("s_waitcnt lgkmcnt(0)" ::: "memory");
        __builtin_amdgcn_sched_barrier(0);
        {
            const short8v pa1 = *(const short8v*)&plds[w][1][lane * 8];
            __builtin_amdgcn_s_setprio(1);
            #pragma unroll
            for (int t = 0; t < 6; ++t)
                oacc[1][t] = __builtin_amdgcn_mfma_f32_16x16x32_bf16(pa1, vt[t], oacc[1][t], 0, 0, 0);
            __builtin_amdgcn_s_setprio(0);
        }
    }
#undef LOADK

    float linv[2][4];
    #pragma unroll
    for (int s2 = 0; s2 < 2; ++s2)
        #pragma unroll
        for (int r = 0; r < 4; ++r) {
            float s = lsum[s2][r];
            s += __shfl_xor(s, 1, 64);
            s += __shfl_xor(s, 2, 64);
            s += __shfl_xor(s, 4, 64);
            s += __shfl_xor(s, 8, 64);
            linv[s2][r] = 1.f / s;
        }

    #pragma unroll
    for (int s2 = 0; s2 < 2; ++s2)
        #pragma unroll
        for (int t = 0; t < 6; ++t)
            #pragma unroll
            for (int r = 0; r < 4; ++r) {
                const int row = q0 + s2 * 16 + g * 4 + r;
                if (row < N_)
                    Out[((size_t)(b * N_ + row)) * 768 + hh * 96 + t * 16 + c] =
                        f2bf(oacc[s2][t][r] * linv[s2][r]);
            }
}

// ---------------------------------------------------------------------------
extern "C" void kernel_launch(void* const* d_in, const int* in_sizes, int n_in,
                              void* d_out, int out_size, void* d_ws, size_t ws_size,
                              hipStream_t stream)
{
    const float* x     = (const float*)d_in[0];
    const float* Wqkv  = (const float*)d_in[1];
    const float* bqkv  = (const float*)d_in[2];
    const float* Wproj = (const float*)d_in[3];
    const float* bproj = (const float*)d_in[4];
    const float* cwq   = (const float*)d_in[5];
    const float* cwk   = (const float*)d_in[6];
    const float* cwv   = (const float*)d_in[7];
    const float* lnqg  = (const float*)d_in[8];
    const float* lnqb  = (const float*)d_in[9];
    const float* lnkg  = (const float*)d_in[10];
    const float* lnkb  = (const float*)d_in[11];
    const float* lnvg  = (const float*)d_in[12];
    const float* lnvb  = (const float*)d_in[13];

    u16* ws = (u16*)d_ws;
    u16* qkv_raw = ws;                       // 3 x [B][NH][N][D] bf16
    u16* q16 = qkv_raw + 3 * QKV1;           // [64][QPAD][96]
    u16* k16 = q16 + (size_t)64 * QPAD * 96; // [64][KPAD][96]
    u16* vt16 = k16 + (size_t)64 * KPAD * 96;// [64][96][KPAD] (transposed)
    u16* x16    = vt16 + (size_t)64 * KPAD * 96;  // [12552][768]
    u16* Wqkvt  = x16 + (size_t)M_ * 768;         // [2304][768]
    u16* Wprojt = Wqkvt + (size_t)2304 * 768;     // [768][768]
    float* cwT  = (float*)(Wprojt + (size_t)768 * 768);  // 3 x [27][96] f32
    u16* attn16 = qkv_raw;                   // alias: raw dead after pooling
    float* out = (float*)d_out;

    // 0) merged prep: cvt x, transpose weights, transpose conv w, vt pad
    prep_kernel<<<PREP_BLOCKS, 256, 0, stream>>>(
        x, Wqkv, Wproj, cwq, cwk, cwv, x16, Wqkvt, Wprojt, cwT, vt16);

    // 1) qkv GEMM (8-wave pipelined MFMA) with bf16 scatter into q/k/v
    gemm_bf16_kernel<2304, true><<<18 * 99, 512, 0, stream>>>(x16, Wqkvt, bqkv, qkv_raw);

    // 2) pool + LN v5: 16-lane groups, no LDS, task-per-group
    pool_ln_v5_kernel<<<(NTASKS + 15) / 16, 256, 0, stream>>>(
        qkv_raw, qkv_raw + QKV1, qkv_raw + 2 * QKV1, cwT,
        lnqg, lnqb, lnkg, lnkb, lnvg, lnvb, q16, k16, vt16);

    // 3) MFMA attention v3 -> bf16 [M_][768]
    attn_mfma_kernel<<<13 * 64, 256, 0, stream>>>(q16, k16, vt16, attn16);

    // 4) output projection (8-wave pipelined MFMA) -> fp32 d_out
    gemm_bf16_kernel<768, false><<<6 * 99, 512, 0, stream>>>(attn16, Wprojt, bproj, out);
}

// Round 16
// 190.038 us; speedup vs baseline: 1.5182x; 1.0482x over previous
//
#include <hip/hip_runtime.h>
#include <hip/hip_bf16.h>
#include <math.h>

#define B_   8
#define NH_  8
#define D_   96
#define C_   768
#define N_   1569          // 8*14*14 + 1
#define NKV_ 393           // 8*7*7 + 1
#define M_   (B_*N_)       // 12552
#define QKV1 ((size_t)B_*NH_*N_*D_)    // 9,639,936 elems per tensor
#define QPAD 1664          // padded q rows per slab (13 tiles of 128)
#define KPAD 416           // padded kv rows per slab (13 tiles of 32)
#define SCALE_ 0.10206207261596575f    // 96^-0.5

using short8v = __attribute__((ext_vector_type(8))) short;
using f32x4   = __attribute__((ext_vector_type(4))) float;
using f32x2   = __attribute__((ext_vector_type(2))) float;
typedef unsigned short u16;

#define GLOAD_LDS16(g, l) __builtin_amdgcn_global_load_lds( \
    (const __attribute__((address_space(1))) void*)(g),     \
    (__attribute__((address_space(3))) void*)(l), 16, 0, 0)

static __device__ __forceinline__ u16 f2bf(float f) {
    __hip_bfloat16 b = __float2bfloat16(f);
    return *(u16*)&b;
}

// bijective XCD swizzle (m204): consecutive swizzled ids land on one XCD
static __device__ __forceinline__ unsigned xcd_swizzle(unsigned orig, unsigned nwg) {
    const unsigned qq = nwg >> 3, rr = nwg & 7;
    const unsigned xcd = orig & 7, loc = orig >> 3;
    return (xcd < rr ? xcd * (qq + 1) : rr * (qq + 1) + (xcd - rr) * qq) + loc;
}

// ---------------------------------------------------------------------------
// Merged prep kernel: block-range dispatch over 5 jobs.
// ---------------------------------------------------------------------------
#define PREP_CVT_B   9414
#define PREP_WQ_B    1728
#define PREP_WP_B    576
#define PREP_WT_B    31
#define PREP_ZP_B    552
#define PREP_BLOCKS  (PREP_CVT_B + PREP_WQ_B + PREP_WP_B + PREP_WT_B + PREP_ZP_B)

static __device__ __forceinline__
void tile_transpose(const float* __restrict__ W, u16* __restrict__ Wt,
                    int ncols, int n0, int k0, float* tile /*[32][33]*/)
{
    const int tx = threadIdx.x & 31, ty = threadIdx.x >> 5;   // 32 x 8
    #pragma unroll
    for (int i = 0; i < 4; ++i)
        tile[(ty + i * 8) * 33 + tx] = W[(size_t)(k0 + ty + i * 8) * ncols + n0 + tx];
    __syncthreads();
    #pragma unroll
    for (int i = 0; i < 4; ++i)
        Wt[(size_t)(n0 + ty + i * 8) * 768 + k0 + tx] = f2bf(tile[tx * 33 + ty + i * 8]);
}

__global__ __launch_bounds__(256)
void prep_kernel(const float* __restrict__ x, const float* __restrict__ Wqkv,
                 const float* __restrict__ Wproj,
                 const float* __restrict__ cwq, const float* __restrict__ cwk,
                 const float* __restrict__ cwv,
                 u16* __restrict__ x16, u16* __restrict__ Wqkvt,
                 u16* __restrict__ Wprojt, float* __restrict__ cwT,
                 u16* __restrict__ vt16)
{
    __shared__ float tile[32 * 33];
    const int bid = blockIdx.x;
    const int tid = threadIdx.x;

    if (bid < PREP_CVT_B) {
        const int i = bid * 256 + tid;
        const int n4 = M_ * 768 / 4;
        if (i < n4) {
            const float4 v = ((const float4*)x)[i];
            ushort4 o;
            o.x = f2bf(v.x); o.y = f2bf(v.y); o.z = f2bf(v.z); o.w = f2bf(v.w);
            ((ushort4*)x16)[i] = o;
        }
    } else if (bid < PREP_CVT_B + PREP_WQ_B) {
        const int b2 = bid - PREP_CVT_B;
        tile_transpose(Wqkv, Wqkvt, 2304, (b2 % 72) * 32, (b2 / 72) * 32, tile);
    } else if (bid < PREP_CVT_B + PREP_WQ_B + PREP_WP_B) {
        const int b2 = bid - PREP_CVT_B - PREP_WQ_B;
        tile_transpose(Wproj, Wprojt, 768, (b2 % 24) * 32, (b2 / 24) * 32, tile);
    } else if (bid < PREP_CVT_B + PREP_WQ_B + PREP_WP_B + PREP_WT_B) {
        const int i = (bid - PREP_CVT_B - PREP_WQ_B - PREP_WP_B) * 256 + tid;
        if (i < 3 * 27 * 96) {
            const int tsr = i / 2592;
            const int r = i - tsr * 2592;
            const int tap = r / 96, ch = r - tap * 96;
            const float* src = tsr == 0 ? cwq : (tsr == 1 ? cwk : cwv);
            cwT[i] = src[ch * 27 + tap];
        }
    } else {
        const int i = (bid - PREP_CVT_B - PREP_WQ_B - PREP_WP_B - PREP_WT_B) * 256 + tid;
        const int total = 64 * 96 * (KPAD - NKV_);
        if (i < total) {
            const int j = i % (KPAD - NKV_);
            const int rest = i / (KPAD - NKV_);     // slab*96 + d
            vt16[(size_t)rest * KPAD + NKV_ + j] = 0;
        }
    }
}

// ---------------------------------------------------------------------------
// bf16 MFMA GEMM v2: BM=128, BN=256, BK=64; 8 waves (2m x 4n), 64x64/wave.
// Single-buffered LDS (48KB -> 2 blocks/CU, 4 waves/SIMD). T2 XOR swizzle.
// Per K-step: vmcnt(0)+bar -> kk0 frags -> MFMA kk0 -> kk1 frags -> bar ->
// STAGE(t+1) (flies under kk1 MFMAs + co-resident block). T5 setprio.
// ---------------------------------------------------------------------------
template<int NC, bool SCATTER>
__global__ __launch_bounds__(512, 4)
void gemm_bf16_kernel(const u16* __restrict__ A, const u16* __restrict__ Bt,
                      const float* __restrict__ bias, void* __restrict__ outp)
{
    constexpr int NXT = NC / 256;
    __shared__ alignas(16) u16 As[128 * 64];
    __shared__ alignas(16) u16 Bs[256 * 64];

    const int tid  = threadIdx.x;
    const int w    = tid >> 6, lane = tid & 63;
    const int c    = lane & 15, g = lane >> 4;
    const int wm   = w >> 2, wn = w & 3;      // 2m x 4n wave grid, 64x64 each
    const int lrow = lane >> 3, lcol = lane & 7;

    const unsigned wg = xcd_swizzle(blockIdx.x, gridDim.x);
    const int m0 = (int)(wg / NXT) * 128;
    const int n0 = (int)(wg % NXT) * 256;

    f32x4 acc[4][4];
    #pragma unroll
    for (int i = 0; i < 4; ++i)
        #pragma unroll
        for (int j = 0; j < 4; ++j) acc[i][j] = (f32x4){0.f, 0.f, 0.f, 0.f};

#define STAGE(K0) do {                                                           \
    _Pragma("unroll")                                                            \
    for (int it2 = 0; it2 < 2; ++it2) {                                          \
        const int rb = it2 * 64 + w * 8;                                         \
        const int row = rb + lrow;                                               \
        const int scol = (lcol ^ (row & 7)) * 8;                                 \
        int m = m0 + row; if (m >= M_) m = M_ - 1;                               \
        GLOAD_LDS16(&A[(size_t)m * 768 + (K0) + scol], &As[rb * 64]);            \
    }                                                                            \
    _Pragma("unroll")                                                            \
    for (int it2 = 0; it2 < 4; ++it2) {                                          \
        const int rb = it2 * 64 + w * 8;                                         \
        const int row = rb + lrow;                                               \
        const int scol = (lcol ^ (row & 7)) * 8;                                 \
        GLOAD_LDS16(&Bt[(size_t)(n0 + row) * 768 + (K0) + scol], &Bs[rb * 64]);  \
    } } while (0)

    const int xora = (g ^ (c & 7)) * 8;          // kk=0: logical col16 = g
    const int xorb = ((4 + g) ^ (c & 7)) * 8;    // kk=1: logical col16 = 4+g

#define KSTEP(T) do {                                                            \
    asm volatile("s_waitcnt vmcnt(0)" ::: "memory");                             \
    __builtin_amdgcn_s_barrier();                                                \
    {                                                                            \
        short8v a0[4], b0[4];                                                    \
        _Pragma("unroll")                                                        \
        for (int i = 0; i < 4; ++i)                                              \
            a0[i] = *(const short8v*)&As[(wm * 64 + i * 16 + c) * 64 + xora];    \
        _Pragma("unroll")                                                        \
        for (int j = 0; j < 4; ++j)                                              \
            b0[j] = *(const short8v*)&Bs[(wn * 64 + j * 16 + c) * 64 + xora];    \
        asm volatile("s_waitcnt lgkmcnt(0)" ::: "memory");                       \
        __builtin_amdgcn_sched_barrier(0);                                       \
        __builtin_amdgcn_s_setprio(1);                                           \
        _Pragma("unroll")                                                        \
        for (int i = 0; i < 4; ++i)                                              \
            _Pragma("unroll")                                                    \
            for (int j = 0; j < 4; ++j)                                          \
                acc[i][j] = __builtin_amdgcn_mfma_f32_16x16x32_bf16(             \
                    a0[i], b0[j], acc[i][j], 0, 0, 0);                           \
        __builtin_amdgcn_s_setprio(0);                                           \
    }                                                                            \
    {                                                                            \
        short8v a1[4], b1[4];                                                    \
        _Pragma("unroll")                                                        \
        for (int i = 0; i < 4; ++i)                                              \
            a1[i] = *(const short8v*)&As[(wm * 64 + i * 16 + c) * 64 + xorb];    \
        _Pragma("unroll")                                                        \
        for (int j = 0; j < 4; ++j)                                              \
            b1[j] = *(const short8v*)&Bs[(wn * 64 + j * 16 + c) * 64 + xorb];    \
        asm volatile("s_waitcnt lgkmcnt(0)" ::: "memory");                       \
        __builtin_amdgcn_sched_barrier(0);                                       \
        __builtin_amdgcn_s_barrier();                                            \
        if ((T) + 1 < 12) STAGE(((T) + 1) * 64);                                 \
        __builtin_amdgcn_s_setprio(1);                                           \
        _Pragma("unroll")                                                        \
        for (int i = 0; i < 4; ++i)                                              \
            _Pragma("unroll")                                                    \
            for (int j = 0; j < 4; ++j)                                          \
                acc[i][j] = __builtin_amdgcn_mfma_f32_16x16x32_bf16(             \
                    a1[i], b1[j], acc[i][j], 0, 0, 0);                           \
        __builtin_amdgcn_s_setprio(0);                                           \
    } } while (0)

    STAGE(0);
    #pragma unroll
    for (int t = 0; t < 12; ++t) KSTEP(t);
#undef STAGE
#undef KSTEP

    #pragma unroll
    for (int i = 0; i < 4; ++i) {
        const int mrow = m0 + wm * 64 + i * 16 + g * 4;
        #pragma unroll
        for (int j = 0; j < 4; ++j) {
            const int ncol = n0 + wn * 64 + j * 16 + c;
            const float bv = bias[ncol];
            if constexpr (SCATTER) {
                u16* out = (u16*)outp;
                const int s   = ncol / C_;          // 0=q,1=k,2=v
                const int rem = ncol - s * C_;
                const int hh  = rem / D_;
                const int dd  = rem - hh * D_;
                #pragma unroll
                for (int r = 0; r < 4; ++r) {
                    const int m = mrow + r;
                    if (m < M_) {
                        const int bb2 = m / N_;
                        const int n = m - bb2 * N_;
                        out[(size_t)s * QKV1 +
                            ((size_t)(bb2 * NH_ + hh) * N_ + n) * D_ + dd] = f2bf(acc[i][j][r] + bv);
                    }
                }
            } else {
                float* out = (float*)outp;
                #pragma unroll
                for (int r = 0; r < 4; ++r) {
                    const int m = mrow + r;
                    if (m < M_) out[(size_t)m * NC + ncol] = acc[i][j][r] + bv;
                }
            }
        }
    }
}

// ---------------------------------------------------------------------------
// Pool+LN v5: 16-lane groups, 6 channels/lane, no LDS, direct global reads.
// ---------------------------------------------------------------------------
static __device__ __forceinline__ void loadx6(const u16* __restrict__ rowp,
                                              int iw, f32x2 x[3])
{
    if (iw < 0 || iw >= 14) {      // compile-time after unroll
        x[0] = x[1] = x[2] = (f32x2){0.f, 0.f};
        return;
    }
    const unsigned* p = (const unsigned*)(rowp + (size_t)iw * 96);
    #pragma unroll
    for (int j = 0; j < 3; ++j) {
        const unsigned u = p[j];
        x[j][0] = __uint_as_float(u << 16);
        x[j][1] = __uint_as_float(u & 0xffff0000u);
    }
}

template<int STRIDE, int OHW, int WMODE, int WO0>
static __device__ __forceinline__
void pool_task(const u16* __restrict__ in, const float* __restrict__ cwT,
               const float* __restrict__ g, const float* __restrict__ bta,
               u16* __restrict__ out, int tokstride, int bh, int to, int ho,
               float oscale)
{
    const int sl = threadIdx.x & 15;
    const u16* base = in + (size_t)bh * N_ * 96 + 6 * sl;

    f32x2 acc[7][3];
    #pragma unroll
    for (int i = 0; i < 7; ++i)
        #pragma unroll
        for (int p = 0; p < 3; ++p) acc[i][p] = (f32x2){0.f, 0.f};

    #pragma unroll
    for (int dt = 0; dt < 3; ++dt) {
        const int t = to - 1 + dt;
        if (t < 0 || t > 7) continue;
        #pragma unroll
        for (int dh = 0; dh < 3; ++dh) {
            const int h = ho * STRIDE - 1 + dh;
            if (h < 0 || h >= 14) continue;
            const int tapb = dt * 9 + dh * 3;
            f32x2 wt[3][3];
            #pragma unroll
            for (int dw = 0; dw < 3; ++dw)
                #pragma unroll
                for (int p = 0; p < 3; ++p)
                    wt[dw][p] = *(const f32x2*)&cwT[(tapb + dw) * 96 + 6 * sl + 2 * p];
            const u16* rowp = base + (size_t)(1 + t * 196 + h * 14) * 96;

            if constexpr (STRIDE == 1) {
                f32x2 xm[3], x0[3], xp[3];
                loadx6(rowp, WO0 - 1, xm);
                loadx6(rowp, WO0, x0);
                #pragma unroll
                for (int wo = 0; wo < 7; ++wo) {
                    loadx6(rowp, WO0 + wo + 1, xp);
                    #pragma unroll
                    for (int p = 0; p < 3; ++p) {
                        acc[wo][p] = __builtin_elementwise_fma(wt[0][p], xm[p], acc[wo][p]);
                        acc[wo][p] = __builtin_elementwise_fma(wt[1][p], x0[p], acc[wo][p]);
                        acc[wo][p] = __builtin_elementwise_fma(wt[2][p], xp[p], acc[wo][p]);
                        xm[p] = x0[p]; x0[p] = xp[p];
                    }
                }
            } else {
                #pragma unroll
                for (int wo = 0; wo < 7; ++wo) {
                    #pragma unroll
                    for (int dw = 0; dw < 3; ++dw) {
                        f32x2 xa[3];
                        loadx6(rowp, 2 * wo - 1 + dw, xa);
                        #pragma unroll
                        for (int p = 0; p < 3; ++p)
                            acc[wo][p] = __builtin_elementwise_fma(wt[dw][p], xa[p], acc[wo][p]);
                    }
                }
            }
        }
    }

    f32x2 gg[3], bb[3];
    #pragma unroll
    for (int p = 0; p < 3; ++p) {
        gg[p] = *(const f32x2*)&g[6 * sl + 2 * p] * oscale;
        bb[p] = *(const f32x2*)&bta[6 * sl + 2 * p] * oscale;
    }

    #pragma unroll
    for (int wo = 0; wo < 7; ++wo) {
        float s = acc[wo][0][0] + acc[wo][0][1] + acc[wo][1][0] + acc[wo][1][1]
                + acc[wo][2][0] + acc[wo][2][1];
        float sq = acc[wo][0][0] * acc[wo][0][0];
        sq = fmaf(acc[wo][0][1], acc[wo][0][1], sq);
        sq = fmaf(acc[wo][1][0], acc[wo][1][0], sq);
        sq = fmaf(acc[wo][1][1], acc[wo][1][1], sq);
        sq = fmaf(acc[wo][2][0], acc[wo][2][0], sq);
        sq = fmaf(acc[wo][2][1], acc[wo][2][1], sq);
        #pragma unroll
        for (int off = 1; off < 16; off <<= 1) {
            s  += __shfl_xor(s, off, 64);
            sq += __shfl_xor(sq, off, 64);
        }
        const float mu = s * (1.f / 96.f);
        const float rstd = rsqrtf(sq * (1.f / 96.f) - mu * mu + 1e-5f);
        const f32x2 muv = (f32x2){mu, mu};
        const int tok = 1 + (to * OHW + ho) * OHW + WO0 + wo;
        u16 yb[6];
        #pragma unroll
        for (int p = 0; p < 3; ++p) {
            const f32x2 y = (acc[wo][p] - muv) * rstd * gg[p] + bb[p];
            yb[2 * p] = f2bf(y[0]); yb[2 * p + 1] = f2bf(y[1]);
        }
        if constexpr (WMODE == 2) {
            #pragma unroll
            for (int j = 0; j < 6; ++j)
                out[((size_t)bh * 96 + 6 * sl + j) * KPAD + tok] = yb[j];
        } else {
            unsigned* op = (unsigned*)&out[((size_t)bh * tokstride + tok) * 96 + 6 * sl];
            #pragma unroll
            for (int p = 0; p < 3; ++p)
                op[p] = (unsigned)yb[2 * p] | ((unsigned)yb[2 * p + 1] << 16);
        }
    }
}

template<int WMODE>
static __device__ __forceinline__
void pool_cls_v5(const u16* __restrict__ in, const float* __restrict__ g,
                 const float* __restrict__ bta, u16* __restrict__ out,
                 int tokstride, int bh, float oscale)
{
    const int sl = threadIdx.x & 15;
    const unsigned* p = (const unsigned*)(in + (size_t)bh * N_ * 96 + 6 * sl);
    f32x2 v[3];
    #pragma unroll
    for (int j = 0; j < 3; ++j) {
        const unsigned u = p[j];
        v[j][0] = __uint_as_float(u << 16);
        v[j][1] = __uint_as_float(u & 0xffff0000u);
    }
    float s = v[0][0] + v[0][1] + v[1][0] + v[1][1] + v[2][0] + v[2][1];
    float sq = v[0][0]*v[0][0] + v[0][1]*v[0][1] + v[1][0]*v[1][0]
             + v[1][1]*v[1][1] + v[2][0]*v[2][0] + v[2][1]*v[2][1];
    #pragma unroll
    for (int off = 1; off < 16; off <<= 1) {
        s  += __shfl_xor(s, off, 64);
        sq += __shfl_xor(sq, off, 64);
    }
    const float mu = s * (1.f / 96.f);
    const float rstd = rsqrtf(sq * (1.f / 96.f) - mu * mu + 1e-5f);
    u16 yb[6];
    #pragma unroll
    for (int p2 = 0; p2 < 3; ++p2) {
        const f32x2 gg = *(const f32x2*)&g[6 * sl + 2 * p2] * oscale;
        const f32x2 bb = *(const f32x2*)&bta[6 * sl + 2 * p2] * oscale;
        const f32x2 y = (v[p2] - (f32x2){mu, mu}) * rstd * gg + bb;
        yb[2 * p2] = f2bf(y[0]); yb[2 * p2 + 1] = f2bf(y[1]);
    }
    if constexpr (WMODE == 2) {
        #pragma unroll
        for (int j = 0; j < 6; ++j)
            out[((size_t)bh * 96 + 6 * sl + j) * KPAD] = yb[j];
    } else {
        unsigned* op = (unsigned*)&out[(size_t)bh * tokstride * 96 + 6 * sl];
        #pragma unroll
        for (int p2 = 0; p2 < 3; ++p2)
            op[p2] = (unsigned)yb[2 * p2] | ((unsigned)yb[2 * p2 + 1] << 16);
    }
}

// task ids: q chunk0 [0,7168), q chunk1 [7168,14336), k [14336,17920),
// v [17920,21504), cls [21504,21696)
#define NTASKS 21696
__global__ __launch_bounds__(256)
void pool_ln_v5_kernel(const u16* __restrict__ qin, const u16* __restrict__ kin,
                       const u16* __restrict__ vin, const float* __restrict__ cwT,
                       const float* __restrict__ gq, const float* __restrict__ bq,
                       const float* __restrict__ gk, const float* __restrict__ bk,
                       const float* __restrict__ gv, const float* __restrict__ bv,
                       u16* __restrict__ qout, u16* __restrict__ kout,
                       u16* __restrict__ vtout)
{
    const unsigned wg = xcd_swizzle(blockIdx.x, gridDim.x);
    const int gid = (int)(wg * 16 + (threadIdx.x >> 4));
    if (gid >= NTASKS) return;

    if (gid < 14336) {                       // q
        const int chunk = gid / 7168;
        const int r = gid - chunk * 7168;
        const int ho = r % 14;
        const int to = (r / 14) & 7;
        const int bh = r / 112;
        if (chunk == 0)
            pool_task<1, 14, 0, 0>(qin, cwT, gq, bq, qout, QPAD, bh, to, ho, SCALE_);
        else
            pool_task<1, 14, 0, 7>(qin, cwT, gq, bq, qout, QPAD, bh, to, ho, SCALE_);
    } else if (gid < 17920) {                // k
        const int r = gid - 14336;
        const int ho = r % 7;
        const int to = (r / 7) & 7;
        const int bh = r / 56;
        pool_task<2, 7, 0, 0>(kin, cwT + 2592, gk, bk, kout, KPAD, bh, to, ho, 1.f);
    } else if (gid < 21504) {                // v (transposed out)
        const int r = gid - 17920;
        const int ho = r % 7;
        const int to = (r / 7) & 7;
        const int bh = r / 56;
        pool_task<2, 7, 2, 0>(vin, cwT + 5184, gv, bv, vtout, KPAD, bh, to, ho, 1.f);
    } else {                                 // cls
        const int r = gid - 21504;
        const int tsr = r >> 6, bh = r & 63;
        if (tsr == 0)      pool_cls_v5<0>(qin, gq, bq, qout, QPAD, bh, SCALE_);
        else if (tsr == 1) pool_cls_v5<0>(kin, gk, bk, kout, KPAD, bh, 1.f);
        else               pool_cls_v5<2>(vin, gv, bv, vtout, KPAD, bh, 1.f);
    }
}

// ---------------------------------------------------------------------------
// MFMA attention v3 -> bf16 [M_][768]. 32 q-rows/wave, K reg double-buffer,
// VT hoisted; per-subtile exp/PV interleave (PV0 MFMA overlaps exp1 VALU).
// ---------------------------------------------------------------------------
__global__ __launch_bounds__(256)
void attn_mfma_kernel(const u16* __restrict__ Q, const u16* __restrict__ K,
                      const u16* __restrict__ VT, u16* __restrict__ Out)
{
    __shared__ alignas(16) u16 plds[4][2][512];   // per-wave, per-subtile P tile
    const int tid  = threadIdx.x;
    const int w    = tid >> 6, lane = tid & 63;
    const int c    = lane & 15, g = lane >> 4;

    const unsigned wg = xcd_swizzle(blockIdx.x, gridDim.x);
    const int bh = (int)(wg / 13);
    const int b  = bh >> 3, hh = bh & 7;
    const int q0 = (int)(wg % 13) * 128 + w * 32;

    const size_t qbase = (size_t)bh * QPAD * 96;
    const size_t kbase = (size_t)bh * KPAD * 96;

    short8v qa[2][3];
    #pragma unroll
    for (int s2 = 0; s2 < 2; ++s2)
        #pragma unroll
        for (int kf = 0; kf < 3; ++kf)
            qa[s2][kf] = *(const short8v*)
                &Q[qbase + (size_t)(q0 + s2 * 16 + c) * 96 + kf * 32 + g * 8];

    f32x4 oacc[2][6];
    #pragma unroll
    for (int s2 = 0; s2 < 2; ++s2)
        #pragma unroll
        for (int t = 0; t < 6; ++t) oacc[s2][t] = (f32x4){0.f, 0.f, 0.f, 0.f};
    float lsum[2][4] = {{0.f,0.f,0.f,0.f},{0.f,0.f,0.f,0.f}};

    short8v kb[2][6];
#define LOADK(IDX, PR) do {                                                     \
    _Pragma("unroll")                                                           \
    for (int h = 0; h < 2; ++h)                                                 \
        _Pragma("unroll")                                                       \
        for (int kf = 0; kf < 3; ++kf)                                          \
            kb[IDX][h * 3 + kf] = *(const short8v*)                             \
                &K[kbase + (size_t)((PR) * 32 + h * 16 + c) * 96 + kf * 32 + g * 8]; \
    } while (0)

    LOADK(0, 0);

    #pragma unroll
    for (int pr = 0; pr < 13; ++pr) {
        const int cur = pr & 1, nxt = cur ^ 1;

        short8v vt[6];
        #pragma unroll
        for (int t = 0; t < 6; ++t)
            vt[t] = *(const short8v*)
                &VT[kbase + (size_t)(t * 16 + c) * KPAD + pr * 32 + g * 8];

        f32x4 sacc[2][2];
        __builtin_amdgcn_s_setprio(1);
        #pragma unroll
        for (int s2 = 0; s2 < 2; ++s2)
            #pragma unroll
            for (int h = 0; h < 2; ++h) {
                f32x4 sa = (f32x4){0.f, 0.f, 0.f, 0.f};
                sa = __builtin_amdgcn_mfma_f32_16x16x32_bf16(qa[s2][0], kb[cur][h*3+0], sa, 0, 0, 0);
                sa = __builtin_amdgcn_mfma_f32_16x16x32_bf16(qa[s2][1], kb[cur][h*3+1], sa, 0, 0, 0);
                sa = __builtin_amdgcn_mfma_f32_16x16x32_bf16(qa[s2][2], kb[cur][h*3+2], sa, 0, 0, 0);
                sacc[s2][h] = sa;
            }
        __builtin_amdgcn_s_setprio(0);

        if (pr < 12) LOADK(nxt, pr + 1);

        // subtile 0: exp -> LDS -> PV0 (its MFMA overlaps subtile 1's exp VALU)
        #pragma unroll
        for (int h = 0; h < 2; ++h) {
            const int jcol = pr * 32 + h * 16 + c;
            #pragma unroll
            for (int r = 0; r < 4; ++r) {
                float s = sacc[0][h][r];
                if (jcol >= NKV_) s = -1e30f;
                const float p = __expf(s);
                lsum[0][r] += p;
                const int q    = g * 4 + r;
                const int j    = h * 16 + c;
                const int dstL = q | ((j >> 3) << 4);
                plds[w][0][dstL * 8 + (j & 7)] = f2bf(p);
            }
        }
        asm volatile("s_waitcnt lgkmcnt(0)" ::: "memory");
        __builtin_amdgcn_sched_barrier(0);
        {
            const short8v pa0 = *(const short8v*)&plds[w][0][lane * 8];
            __builtin_amdgcn_s_setprio(1);
            #pragma unroll
            for (int t = 0; t < 6; ++t)
                oacc[0][t] = __builtin_amdgcn_mfma_f32_16x16x32_bf16(pa0, vt[t], oacc[0][t], 0, 0, 0);
            __builtin_amdgcn_s_setprio(0);
        }

        // subtile 1
        #pragma unroll
        for (int h = 0; h < 2; ++h) {
            const int jcol = pr * 32 + h * 16 + c;
            #pragma unroll
            for (int r = 0; r < 4; ++r) {
                float s = sacc[1][h][r];
                if (jcol >= NKV_) s = -1e30f;
                const float p = __expf(s);
                lsum[1][r] += p;
                const int q    = g * 4 + r;
                const int j    = h * 16 + c;
                const int dstL = q | ((j >> 3) << 4);
                plds[w][1][dstL * 8 + (j & 7)] = f2bf(p);
            }
        }
        asm volatile("s_waitcnt lgkmcnt(0)" ::: "memory");
        __builtin_amdgcn_sched_barrier(0);
        {
            const short8v pa1 = *(const short8v*)&plds[w][1][lane * 8];
            __builtin_amdgcn_s_setprio(1);
            #pragma unroll
            for (int t = 0; t < 6; ++t)
                oacc[1][t] = __builtin_amdgcn_mfma_f32_16x16x32_bf16(pa1, vt[t], oacc[1][t], 0, 0, 0);
            __builtin_amdgcn_s_setprio(0);
        }
    }
#undef LOADK

    float linv[2][4];
    #pragma unroll
    for (int s2 = 0; s2 < 2; ++s2)
        #pragma unroll
        for (int r = 0; r < 4; ++r) {
            float s = lsum[s2][r];
            s += __shfl_xor(s, 1, 64);
            s += __shfl_xor(s, 2, 64);
            s += __shfl_xor(s, 4, 64);
            s += __shfl_xor(s, 8, 64);
            linv[s2][r] = 1.f / s;
        }

    #pragma unroll
    for (int s2 = 0; s2 < 2; ++s2)
        #pragma unroll
        for (int t = 0; t < 6; ++t)
            #pragma unroll
            for (int r = 0; r < 4; ++r) {
                const int row = q0 + s2 * 16 + g * 4 + r;
                if (row < N_)
                    Out[((size_t)(b * N_ + row)) * 768 + hh * 96 + t * 16 + c] =
                        f2bf(oacc[s2][t][r] * linv[s2][r]);
            }
}

// ---------------------------------------------------------------------------
extern "C" void kernel_launch(void* const* d_in, const int* in_sizes, int n_in,
                              void* d_out, int out_size, void* d_ws, size_t ws_size,
                              hipStream_t stream)
{
    const float* x     = (const float*)d_in[0];
    const float* Wqkv  = (const float*)d_in[1];
    const float* bqkv  = (const float*)d_in[2];
    const float* Wproj = (const float*)d_in[3];
    const float* bproj = (const float*)d_in[4];
    const float* cwq   = (const float*)d_in[5];
    const float* cwk   = (const float*)d_in[6];
    const float* cwv   = (const float*)d_in[7];
    const float* lnqg  = (const float*)d_in[8];
    const float* lnqb  = (const float*)d_in[9];
    const float* lnkg  = (const float*)d_in[10];
    const float* lnkb  = (const float*)d_in[11];
    const float* lnvg  = (const float*)d_in[12];
    const float* lnvb  = (const float*)d_in[13];

    u16* ws = (u16*)d_ws;
    u16* qkv_raw = ws;                       // 3 x [B][NH][N][D] bf16
    u16* q16 = qkv_raw + 3 * QKV1;           // [64][QPAD][96]
    u16* k16 = q16 + (size_t)64 * QPAD * 96; // [64][KPAD][96]
    u16* vt16 = k16 + (size_t)64 * KPAD * 96;// [64][96][KPAD] (transposed)
    u16* x16    = vt16 + (size_t)64 * KPAD * 96;  // [12552][768]
    u16* Wqkvt  = x16 + (size_t)M_ * 768;         // [2304][768]
    u16* Wprojt = Wqkvt + (size_t)2304 * 768;     // [768][768]
    float* cwT  = (float*)(Wprojt + (size_t)768 * 768);  // 3 x [27][96] f32
    u16* attn16 = qkv_raw;                   // alias: raw dead after pooling
    float* out = (float*)d_out;

    // 0) merged prep: cvt x, transpose weights, transpose conv w, vt pad
    prep_kernel<<<PREP_BLOCKS, 256, 0, stream>>>(
        x, Wqkv, Wproj, cwq, cwk, cwv, x16, Wqkvt, Wprojt, cwT, vt16);

    // 1) qkv GEMM (128x256, 64x64 waves) with bf16 scatter into q/k/v
    gemm_bf16_kernel<2304, true><<<99 * 9, 512, 0, stream>>>(x16, Wqkvt, bqkv, qkv_raw);

    // 2) pool + LN v5: 16-lane groups, no LDS, task-per-group
    pool_ln_v5_kernel<<<(NTASKS + 15) / 16, 256, 0, stream>>>(
        qkv_raw, qkv_raw + QKV1, qkv_raw + 2 * QKV1, cwT,
        lnqg, lnqb, lnkg, lnkb, lnvg, lnvb, q16, k16, vt16);

    // 3) MFMA attention v3 -> bf16 [M_][768]
    attn_mfma_kernel<<<13 * 64, 256, 0, stream>>>(q16, k16, vt16, attn16);

    // 4) output projection -> fp32 d_out
    gemm_bf16_kernel<768, false><<<99 * 3, 512, 0, stream>>>(attn16, Wprojt, bproj, out);
}